// Round 1
// baseline (1203.224 us; speedup 1.0000x reference)
//
#include <hip/hip_runtime.h>
#include <hip/hip_bf16.h>
#include <math.h>

#define DIM   768
#define HID   128
#define H2    256
#define NENT  128
#define SPAN  16
#define NCLS  5

// ws layout (float elements)
#define POOL_OFF 0
#define POOL_SZ  (3*NENT*H2)             // 98304
#define HEP_OFF  (POOL_OFF + POOL_SZ)
#define HEP_SZ   (NENT*NENT*H2)          // 4194304  [k][i][c]
#define TEP_OFF  (HEP_OFF + HEP_SZ)      // [k][j][b]
#define TMP_OFF  (TEP_OFF + HEP_SZ)      // [k][a][b] 8388608

__device__ __forceinline__ float sigmoidf_(float x) { return 1.0f / (1.0f + __expf(-x)); }

// ---------------- pool: LSTM single-step + max over span ----------------
// grid: 384 = 3 types * 128 ents; block 256 = (dir 2) x (j 128)
__global__ __launch_bounds__(256)
void pool_kernel(const float* __restrict__ enc,
                 const int* __restrict__ idx_h, const int* __restrict__ idx_t, const int* __restrict__ idx_e,
                 const float* __restrict__ Whf, const float* __restrict__ bhf,
                 const float* __restrict__ Whb, const float* __restrict__ bhb,
                 const float* __restrict__ Wtf, const float* __restrict__ btf,
                 const float* __restrict__ Wtb, const float* __restrict__ btb,
                 const float* __restrict__ Wef, const float* __restrict__ bef,
                 const float* __restrict__ Web, const float* __restrict__ beb,
                 float* __restrict__ pool)
{
    __shared__ __align__(16) float toks[SPAN][DIM];   // 48 KB
    const int tid  = threadIdx.x;
    const int type = blockIdx.x >> 7;
    const int ent  = blockIdx.x & 127;
    const int* idx = (type == 0) ? idx_h : (type == 1) ? idx_t : idx_e;

    for (int t = tid; t < SPAN * (DIM / 4); t += 256) {
        int l  = t / (DIM / 4);
        int c4 = t % (DIM / 4);
        int row = idx[ent * SPAN + l];
        float4 v = ((const float4*)(enc + row * DIM))[c4];
        ((float4*)(&toks[l][0]))[c4] = v;
    }
    __syncthreads();

    const int dir = tid >> 7;
    const int j   = tid & 127;
    const float *W, *B;
    if (type == 0)      { W = dir ? Whb : Whf; B = dir ? bhb : bhf; }
    else if (type == 1) { W = dir ? Wtb : Wtf; B = dir ? btb : btf; }
    else                { W = dir ? Web : Wef; B = dir ? beb : bef; }

    // gate rows: i=[0,128) g=[256,384) o=[384,512)   (f unused: c0=0)
    const float4* Wi = (const float4*)(W + (0 * HID + j) * DIM);
    const float4* Wg = (const float4*)(W + (2 * HID + j) * DIM);
    const float4* Wo = (const float4*)(W + (3 * HID + j) * DIM);

    float ai[SPAN], ag[SPAN], ao[SPAN];
    #pragma unroll
    for (int l = 0; l < SPAN; ++l) { ai[l] = 0.f; ag[l] = 0.f; ao[l] = 0.f; }

    for (int c4 = 0; c4 < DIM / 4; ++c4) {
        float4 wi = Wi[c4], wg = Wg[c4], wo = Wo[c4];
        #pragma unroll
        for (int l = 0; l < SPAN; ++l) {
            float4 x = ((const float4*)(&toks[l][0]))[c4];  // broadcast across lanes
            ai[l] += x.x * wi.x + x.y * wi.y + x.z * wi.z + x.w * wi.w;
            ag[l] += x.x * wg.x + x.y * wg.y + x.z * wg.z + x.w * wg.w;
            ao[l] += x.x * wo.x + x.y * wo.y + x.z * wo.z + x.w * wo.w;
        }
    }
    float bi = B[j], bg = B[2 * HID + j], bo = B[3 * HID + j];
    float hmax = -1e30f;
    #pragma unroll
    for (int l = 0; l < SPAN; ++l) {
        float iv = sigmoidf_(ai[l] + bi);
        float gv = tanhf(ag[l] + bg);
        float ov = sigmoidf_(ao[l] + bo);
        float h  = ov * tanhf(iv * gv);
        hmax = fmaxf(hmax, h);
    }
    pool[(type * NENT + ent) * H2 + dir * HID + j] = hmax;
}

// ---------------- gemm1 (NT): tmp[k][ab] = sum_c Ee[k][c] * T[ab][c] ----------------
// M=128 (k, full), N tile 128 of ab (grid 512), K=256
__global__ __launch_bounds__(256)
void gemm1_kernel(const float* __restrict__ Ee,   // [128][256]
                  const float* __restrict__ T,    // [65536][256]
                  float* __restrict__ tmp)        // [128][65536]
{
    __shared__ float As[128][33];
    __shared__ float Bs[128][33];
    const int tid = threadIdx.x;
    const int ab0 = blockIdx.x * 128;
    const int tx = tid & 15, ty = tid >> 4;

    float acc[8][8];
    #pragma unroll
    for (int m = 0; m < 8; ++m)
        #pragma unroll
        for (int n = 0; n < 8; ++n) acc[m][n] = 0.f;

    for (int kt = 0; kt < H2 / 32; ++kt) {
        const int c0 = kt * 32;
        #pragma unroll
        for (int q = 0; q < 4; ++q) {
            int fid = tid + q * 256;          // 0..1023 : 128 rows x 8 float4
            int r = fid >> 3, c4 = fid & 7;
            float4 v = ((const float4*)(Ee + r * H2 + c0))[c4];
            As[r][c4 * 4 + 0] = v.x; As[r][c4 * 4 + 1] = v.y;
            As[r][c4 * 4 + 2] = v.z; As[r][c4 * 4 + 3] = v.w;
            float4 w = ((const float4*)(T + (size_t)(ab0 + r) * H2 + c0))[c4];
            Bs[r][c4 * 4 + 0] = w.x; Bs[r][c4 * 4 + 1] = w.y;
            Bs[r][c4 * 4 + 2] = w.z; Bs[r][c4 * 4 + 3] = w.w;
        }
        __syncthreads();
        for (int kk = 0; kk < 32; ++kk) {
            float a[8], b[8];
            #pragma unroll
            for (int m = 0; m < 8; ++m) a[m] = As[ty + 16 * m][kk];
            #pragma unroll
            for (int n = 0; n < 8; ++n) b[n] = Bs[tx + 16 * n][kk];
            #pragma unroll
            for (int m = 0; m < 8; ++m)
                #pragma unroll
                for (int n = 0; n < 8; ++n) acc[m][n] += a[m] * b[n];
        }
        __syncthreads();
    }
    #pragma unroll
    for (int m = 0; m < 8; ++m) {
        int k = ty + 16 * m;
        #pragma unroll
        for (int n = 0; n < 8; ++n) {
            int ab = ab0 + tx + 16 * n;
            tmp[(size_t)k * 65536 + ab] = acc[m][n];
        }
    }
}

// ---------------- gemm2 (NN): out[k][i][b] = sum_a Hx[i][a] * tmp[k][a][b] ----------------
// grid 256 = k(128) x ntile(2); per-k GEMM M=128,N=128,K=256
__global__ __launch_bounds__(256)
void gemm2_kernel(const float* __restrict__ Hx,   // [128][256]
                  const float* __restrict__ tmp,  // [128][256][256]
                  float* __restrict__ outp)       // [128][128][256]
{
    __shared__ float As[128][33];
    __shared__ float Bs[32][132];
    const int tid = threadIdx.x;
    const int k   = blockIdx.x >> 1;
    const int nb0 = (blockIdx.x & 1) * 128;
    const float* B = tmp + (size_t)k * H2 * H2;
    const int tx = tid & 15, ty = tid >> 4;

    float acc[8][8];
    #pragma unroll
    for (int m = 0; m < 8; ++m)
        #pragma unroll
        for (int n = 0; n < 8; ++n) acc[m][n] = 0.f;

    for (int kt = 0; kt < 8; ++kt) {
        const int c0 = kt * 32;
        #pragma unroll
        for (int q = 0; q < 4; ++q) {
            int fid = tid + q * 256;
            int r = fid >> 3, c4 = fid & 7;
            float4 v = ((const float4*)(Hx + r * H2 + c0))[c4];
            As[r][c4 * 4 + 0] = v.x; As[r][c4 * 4 + 1] = v.y;
            As[r][c4 * 4 + 2] = v.z; As[r][c4 * 4 + 3] = v.w;
        }
        #pragma unroll
        for (int q = 0; q < 4; ++q) {
            int fid = tid + q * 256;           // 32 rows x 32 float4
            int r = fid >> 5, c4 = fid & 31;
            float4 v = ((const float4*)(B + (c0 + r) * H2 + nb0))[c4];
            ((float4*)&Bs[r][c4 * 4])[0] = v;  // row stride 132 floats = 528 B (16B-mult)
        }
        __syncthreads();
        for (int kk = 0; kk < 32; ++kk) {
            float a[8], b[8];
            #pragma unroll
            for (int m = 0; m < 8; ++m) a[m] = As[ty + 16 * m][kk];
            #pragma unroll
            for (int n = 0; n < 8; ++n) b[n] = Bs[kk][tx + 16 * n];
            #pragma unroll
            for (int m = 0; m < 8; ++m)
                #pragma unroll
                for (int n = 0; n < 8; ++n) acc[m][n] += a[m] * b[n];
        }
        __syncthreads();
    }
    #pragma unroll
    for (int m = 0; m < 8; ++m) {
        int i = ty + 16 * m;
        #pragma unroll
        for (int n = 0; n < 8; ++n)
            outp[(size_t)k * (NENT * H2) + i * H2 + nb0 + tx + 16 * n] = acc[m][n];
    }
}

// ---------------- step3: per (k, i-tile16): v = hep*Tcls; pred = tep*v ----------------
// grid 1024 = k(128) x it(8)
__global__ __launch_bounds__(256)
void step3_kernel(const float* __restrict__ hep,  // [k][i][c]
                  const float* __restrict__ tep,  // [k][j][b]
                  const float* __restrict__ Tcls, // [256][5][256]
                  float* __restrict__ out)        // [i][j][k][m]
{
    __shared__ __align__(16) float Hs[16][H2];         // 16 KB
    __shared__ __align__(16) float Vs[16][NCLS][H2];   // 80 KB
    __shared__ __align__(16) float Es[128][36];        // 18 KB
    const int tid = threadIdx.x;
    const int k  = blockIdx.x >> 3;
    const int it = blockIdx.x & 7;
    const int i0 = it * 16;

    #pragma unroll
    for (int q = 0; q < 4; ++q) {
        int fid = tid + q * 256;               // 16 rows x 64 float4
        int r = fid >> 6, c4 = fid & 63;
        ((float4*)&Hs[r][0])[c4] = ((const float4*)(hep + ((size_t)k * NENT + i0 + r) * H2))[c4];
    }
    __syncthreads();

    // phase1: Vs[i][m][b=tid] = sum_c Hs[i][c] * Tcls[b][m][c]
    {
        const int b = tid;
        #pragma unroll 1
        for (int m = 0; m < NCLS; ++m) {
            float acc[16];
            #pragma unroll
            for (int i = 0; i < 16; ++i) acc[i] = 0.f;
            const float4* trow = (const float4*)(Tcls + (size_t)(b * NCLS + m) * H2);
            for (int c4 = 0; c4 < H2 / 4; ++c4) {
                float4 tc = trow[c4];
                #pragma unroll
                for (int i = 0; i < 16; ++i) {
                    float4 h = ((const float4*)&Hs[i][0])[c4];
                    acc[i] += h.x * tc.x + h.y * tc.y + h.z * tc.z + h.w * tc.w;
                }
            }
            #pragma unroll
            for (int i = 0; i < 16; ++i) Vs[i][m][b] = acc[i];
        }
    }
    __syncthreads();

    // phase2: pred[i][j][m] = sum_b tep[k][j][b] * Vs[i][m][b]
    const int j  = tid & 127;
    const int ig = tid >> 7;
    float acc[8][NCLS];
    #pragma unroll
    for (int ii = 0; ii < 8; ++ii)
        #pragma unroll
        for (int m = 0; m < NCLS; ++m) acc[ii][m] = 0.f;

    for (int bt = 0; bt < 8; ++bt) {
        const int b0 = bt * 32;
        #pragma unroll
        for (int q = 0; q < 4; ++q) {
            int fid = tid + q * 256;           // 128 rows x 8 float4
            int r = fid >> 3, c4 = fid & 7;
            float4 v = ((const float4*)(tep + ((size_t)k * NENT + r) * H2 + b0))[c4];
            ((float4*)&Es[r][c4 * 4])[0] = v;  // stride 36 floats = 144 B (16B-mult)
        }
        __syncthreads();
        #pragma unroll
        for (int b4 = 0; b4 < 8; ++b4) {
            float4 tj = ((const float4*)&Es[j][b4 * 4])[0];
            #pragma unroll
            for (int ii = 0; ii < 8; ++ii) {
                #pragma unroll
                for (int m = 0; m < NCLS; ++m) {
                    float4 v4 = ((const float4*)&Vs[ig * 8 + ii][m][b0 + b4 * 4])[0];
                    acc[ii][m] += tj.x * v4.x + tj.y * v4.y + tj.z * v4.z + tj.w * v4.w;
                }
            }
        }
        __syncthreads();
    }

    #pragma unroll
    for (int ii = 0; ii < 8; ++ii) {
        int i = i0 + ig * 8 + ii;
        size_t base = ((size_t)(i * NENT + j) * NENT + k) * NCLS;
        #pragma unroll
        for (int m = 0; m < NCLS; ++m) out[base + m] = acc[ii][m];
    }
}

extern "C" void kernel_launch(void* const* d_in, const int* in_sizes, int n_in,
                              void* d_out, int out_size, void* d_ws, size_t ws_size,
                              hipStream_t stream)
{
    (void)in_sizes; (void)n_in; (void)out_size; (void)ws_size;
    const float* enc  = (const float*)d_in[0];
    const int*   hidx = (const int*)d_in[1];
    const int*   tidx = (const int*)d_in[2];
    const int*   eidx = (const int*)d_in[3];
    const float* Whf = (const float*)d_in[4];
    const float* bhf = (const float*)d_in[5];
    const float* Whb = (const float*)d_in[6];
    const float* bhb = (const float*)d_in[7];
    const float* Wtf = (const float*)d_in[8];
    const float* btf = (const float*)d_in[9];
    const float* Wtb = (const float*)d_in[10];
    const float* btb = (const float*)d_in[11];
    const float* Wef = (const float*)d_in[12];
    const float* bef = (const float*)d_in[13];
    const float* Web = (const float*)d_in[14];
    const float* beb = (const float*)d_in[15];
    const float* T_he  = (const float*)d_in[16];
    const float* T_te  = (const float*)d_in[17];
    const float* T_cls = (const float*)d_in[18];

    float* out  = (float*)d_out;
    float* ws   = (float*)d_ws;
    float* pool = ws + POOL_OFF;   // [3][128][256]
    float* hep  = ws + HEP_OFF;    // [k][i][c]
    float* tep  = ws + TEP_OFF;    // [k][j][b]
    float* tmp  = ws + TMP_OFF;    // [k][a][b]

    pool_kernel<<<384, 256, 0, stream>>>(enc, hidx, tidx, eidx,
        Whf, bhf, Whb, bhb, Wtf, btf, Wtb, btb, Wef, bef, Web, beb, pool);

    gemm1_kernel<<<512, 256, 0, stream>>>(pool + 2 * NENT * H2, T_he, tmp);
    gemm2_kernel<<<256, 256, 0, stream>>>(pool + 0 * NENT * H2, tmp, hep);

    gemm1_kernel<<<512, 256, 0, stream>>>(pool + 2 * NENT * H2, T_te, tmp);
    gemm2_kernel<<<256, 256, 0, stream>>>(pool + 1 * NENT * H2, tmp, tep);

    step3_kernel<<<1024, 256, 0, stream>>>(hep, tep, T_cls, out);
}

// Round 2
// 592.327 us; speedup vs baseline: 2.0314x; 2.0314x over previous
//
#include <hip/hip_runtime.h>
#include <hip/hip_bf16.h>
#include <math.h>

#define DIM   768
#define HID   128
#define H2    256
#define NENT  128
#define SPAN  16
#define NCLS  5

// ---- ws layout (bytes) ----
// pool  fp32 [3][128][256]            @ 0         (393,216 B)
// hepB  bf16 [k][i][c] 128*128*256    @ 393216    (8,388,608 B)
// tepB  bf16 [k][j][b]                @ 8781824   (8,388,608 B)
// TclsB bf16 [m][c][b] 5*256*256      @ 17170432  (655,360 B)
// tmp   fp32 [k][a][b] 128*256*256    @ 17825792  (33,554,432 B)   (dead before step3)
// predT fp32 [k*5+m][i][j]            @ 17825792  (41,943,040 B)   overlaps tmp
// total = 59,768,832 B  (proven ws >= 67.5 MB from round 1)
#define HEPB_OFF   393216
#define TEPB_OFF   (HEPB_OFF + 8388608)
#define TCLSB_OFF  (TEPB_OFF + 8388608)
#define TMP_OFF    (TCLSB_OFF + 655360)
#define PREDT_OFF  TMP_OFF

typedef __attribute__((ext_vector_type(8))) short bf16x8;
typedef __attribute__((ext_vector_type(4))) float f32x4;

__device__ __forceinline__ float sigmoidf_(float x) { return 1.0f / (1.0f + __expf(-x)); }

__device__ __forceinline__ unsigned short f2bf(float x) {
    __hip_bfloat16 h = __float2bfloat16(x);
    return *reinterpret_cast<unsigned short*>(&h);
}

// ---------------- pool: LSTM single-step + max over span ----------------
__global__ __launch_bounds__(256)
void pool_kernel(const float* __restrict__ enc,
                 const int* __restrict__ idx_h, const int* __restrict__ idx_t, const int* __restrict__ idx_e,
                 const float* __restrict__ Whf, const float* __restrict__ bhf,
                 const float* __restrict__ Whb, const float* __restrict__ bhb,
                 const float* __restrict__ Wtf, const float* __restrict__ btf,
                 const float* __restrict__ Wtb, const float* __restrict__ btb,
                 const float* __restrict__ Wef, const float* __restrict__ bef,
                 const float* __restrict__ Web, const float* __restrict__ beb,
                 float* __restrict__ pool)
{
    __shared__ __align__(16) float toks[SPAN][DIM];
    const int tid  = threadIdx.x;
    const int type = blockIdx.x >> 7;
    const int ent  = blockIdx.x & 127;
    const int* idx = (type == 0) ? idx_h : (type == 1) ? idx_t : idx_e;

    for (int t = tid; t < SPAN * (DIM / 4); t += 256) {
        int l  = t / (DIM / 4);
        int c4 = t % (DIM / 4);
        int row = idx[ent * SPAN + l];
        float4 v = ((const float4*)(enc + row * DIM))[c4];
        ((float4*)(&toks[l][0]))[c4] = v;
    }
    __syncthreads();

    const int dir = tid >> 7;
    const int j   = tid & 127;
    const float *W, *B;
    if (type == 0)      { W = dir ? Whb : Whf; B = dir ? bhb : bhf; }
    else if (type == 1) { W = dir ? Wtb : Wtf; B = dir ? btb : btf; }
    else                { W = dir ? Web : Wef; B = dir ? beb : bef; }

    const float4* Wi = (const float4*)(W + (0 * HID + j) * DIM);
    const float4* Wg = (const float4*)(W + (2 * HID + j) * DIM);
    const float4* Wo = (const float4*)(W + (3 * HID + j) * DIM);

    float ai[SPAN], ag[SPAN], ao[SPAN];
    #pragma unroll
    for (int l = 0; l < SPAN; ++l) { ai[l] = 0.f; ag[l] = 0.f; ao[l] = 0.f; }

    for (int c4 = 0; c4 < DIM / 4; ++c4) {
        float4 wi = Wi[c4], wg = Wg[c4], wo = Wo[c4];
        #pragma unroll
        for (int l = 0; l < SPAN; ++l) {
            float4 x = ((const float4*)(&toks[l][0]))[c4];
            ai[l] += x.x * wi.x + x.y * wi.y + x.z * wi.z + x.w * wi.w;
            ag[l] += x.x * wg.x + x.y * wg.y + x.z * wg.z + x.w * wg.w;
            ao[l] += x.x * wo.x + x.y * wo.y + x.z * wo.z + x.w * wo.w;
        }
    }
    float bi = B[j], bg = B[2 * HID + j], bo = B[3 * HID + j];
    float hmax = -1e30f;
    #pragma unroll
    for (int l = 0; l < SPAN; ++l) {
        float iv = sigmoidf_(ai[l] + bi);
        float gv = tanhf(ag[l] + bg);
        float ov = sigmoidf_(ao[l] + bo);
        float h  = ov * tanhf(iv * gv);
        hmax = fmaxf(hmax, h);
    }
    pool[(type * NENT + ent) * H2 + dir * HID + j] = hmax;
}

// ---------------- convert T_cls[b][m][c] -> bf16 TclsB[m][c][b] ----------------
__global__ __launch_bounds__(256)
void conv_tcls(const float* __restrict__ T, unsigned short* __restrict__ TB)
{
    int idx = blockIdx.x * 256 + threadIdx.x;        // 327680 total, coalesced read
    int b = idx / (NCLS * H2);
    int r = idx % (NCLS * H2);
    int m = r >> 8, c = r & 255;
    TB[((m << 8) + c) * H2 + b] = f2bf(T[idx]);
}

// ---------------- gemm1 (NT, fp32): tmp[k][ab] = sum_c Ee[k][c] * T[ab][c] ----------------
__global__ __launch_bounds__(256)
void gemm1_kernel(const float* __restrict__ Ee,   // [128][256]
                  const float* __restrict__ T,    // [65536][256]
                  float* __restrict__ tmp)        // [128][65536]
{
    __shared__ float As[128][33];
    __shared__ float Bs[128][33];
    const int tid = threadIdx.x;
    const int ab0 = blockIdx.x * 128;
    const int tx = tid & 15, ty = tid >> 4;

    float acc[8][8];
    #pragma unroll
    for (int m = 0; m < 8; ++m)
        #pragma unroll
        for (int n = 0; n < 8; ++n) acc[m][n] = 0.f;

    for (int kt = 0; kt < H2 / 32; ++kt) {
        const int c0 = kt * 32;
        #pragma unroll
        for (int q = 0; q < 4; ++q) {
            int fid = tid + q * 256;
            int r = fid >> 3, c4 = fid & 7;
            float4 v = ((const float4*)(Ee + r * H2 + c0))[c4];
            As[r][c4 * 4 + 0] = v.x; As[r][c4 * 4 + 1] = v.y;
            As[r][c4 * 4 + 2] = v.z; As[r][c4 * 4 + 3] = v.w;
            float4 w = ((const float4*)(T + (size_t)(ab0 + r) * H2 + c0))[c4];
            Bs[r][c4 * 4 + 0] = w.x; Bs[r][c4 * 4 + 1] = w.y;
            Bs[r][c4 * 4 + 2] = w.z; Bs[r][c4 * 4 + 3] = w.w;
        }
        __syncthreads();
        for (int kk = 0; kk < 32; ++kk) {
            float a[8], b[8];
            #pragma unroll
            for (int m = 0; m < 8; ++m) a[m] = As[ty + 16 * m][kk];
            #pragma unroll
            for (int n = 0; n < 8; ++n) b[n] = Bs[tx + 16 * n][kk];
            #pragma unroll
            for (int m = 0; m < 8; ++m)
                #pragma unroll
                for (int n = 0; n < 8; ++n) acc[m][n] += a[m] * b[n];
        }
        __syncthreads();
    }
    #pragma unroll
    for (int m = 0; m < 8; ++m) {
        int k = ty + 16 * m;
        #pragma unroll
        for (int n = 0; n < 8; ++n) {
            int ab = ab0 + tx + 16 * n;
            tmp[(size_t)k * 65536 + ab] = acc[m][n];
        }
    }
}

// ---------------- gemm2 (NN, fp32 -> bf16 store): out[k][i][b] = sum_a Hx[i][a]*tmp[k][a][b] ----
__global__ __launch_bounds__(256)
void gemm2_kernel(const float* __restrict__ Hx,   // [128][256]
                  const float* __restrict__ tmp,  // [128][256][256]
                  unsigned short* __restrict__ outp) // bf16 [128][128][256]
{
    __shared__ float As[128][33];
    __shared__ float Bs[32][132];
    const int tid = threadIdx.x;
    const int k   = blockIdx.x >> 1;
    const int nb0 = (blockIdx.x & 1) * 128;
    const float* B = tmp + (size_t)k * H2 * H2;
    const int tx = tid & 15, ty = tid >> 4;

    float acc[8][8];
    #pragma unroll
    for (int m = 0; m < 8; ++m)
        #pragma unroll
        for (int n = 0; n < 8; ++n) acc[m][n] = 0.f;

    for (int kt = 0; kt < 8; ++kt) {
        const int c0 = kt * 32;
        #pragma unroll
        for (int q = 0; q < 4; ++q) {
            int fid = tid + q * 256;
            int r = fid >> 3, c4 = fid & 7;
            float4 v = ((const float4*)(Hx + r * H2 + c0))[c4];
            As[r][c4 * 4 + 0] = v.x; As[r][c4 * 4 + 1] = v.y;
            As[r][c4 * 4 + 2] = v.z; As[r][c4 * 4 + 3] = v.w;
        }
        #pragma unroll
        for (int q = 0; q < 4; ++q) {
            int fid = tid + q * 256;
            int r = fid >> 5, c4 = fid & 31;
            float4 v = ((const float4*)(B + (c0 + r) * H2 + nb0))[c4];
            ((float4*)&Bs[r][c4 * 4])[0] = v;
        }
        __syncthreads();
        for (int kk = 0; kk < 32; ++kk) {
            float a[8], b[8];
            #pragma unroll
            for (int m = 0; m < 8; ++m) a[m] = As[ty + 16 * m][kk];
            #pragma unroll
            for (int n = 0; n < 8; ++n) b[n] = Bs[kk][tx + 16 * n];
            #pragma unroll
            for (int m = 0; m < 8; ++m)
                #pragma unroll
                for (int n = 0; n < 8; ++n) acc[m][n] += a[m] * b[n];
        }
        __syncthreads();
    }
    #pragma unroll
    for (int m = 0; m < 8; ++m) {
        int i = ty + 16 * m;
        #pragma unroll
        for (int n = 0; n < 8; ++n)
            outp[(size_t)k * (NENT * H2) + i * H2 + nb0 + tx + 16 * n] = f2bf(acc[m][n]);
    }
}

// ---------------- step3 MFMA: per (k,m): W = tep_k @ Tcls_m ; P = hep_k @ W^T ----------------
// grid 640 = k*5+m ; 512 threads = 8 waves ; LDS: W bf16 [128][256] swizzled (64 KB)
__global__ __launch_bounds__(512)
void step3_mfma(const unsigned short* __restrict__ hepB,  // [k][i][c]
                const unsigned short* __restrict__ tepB,  // [k][j][b]
                const unsigned short* __restrict__ TclsB, // [m][c][b]
                float* __restrict__ predT)                // [k*5+m][i][j]
{
    __shared__ unsigned short W[128 * 256];   // [j][c] bf16, byte ^= (j&7)<<4
    const int bid = blockIdx.x;
    const int k = bid / 5, m = bid % 5;
    const int tid = threadIdx.x;
    const int w  = tid >> 6;
    const int l  = tid & 63;
    const int lr = l & 15;     // row/col within 16-tile
    const int lg = l >> 4;     // k-slice group

    // ---- G1: W[j][c] = sum_b tepB[k][j][b] * TclsB[m][c][b]
    {
        const int jb = (w & 3) * 32;          // 2 j-tiles
        const int cb = (w >> 2) * 128;        // 8 c-tiles
        f32x4 acc[2][8];
        #pragma unroll
        for (int a = 0; a < 2; ++a)
            #pragma unroll
            for (int b = 0; b < 8; ++b) acc[a][b] = (f32x4){0.f, 0.f, 0.f, 0.f};

        const unsigned short* tk = tepB  + (size_t)k * (NENT * H2);
        const unsigned short* tc = TclsB + (size_t)m * (H2 * H2);
        for (int ks = 0; ks < 8; ++ks) {
            bf16x8 a0 = *(const bf16x8*)(tk + (jb +      lr) * H2 + ks * 32 + lg * 8);
            bf16x8 a1 = *(const bf16x8*)(tk + (jb + 16 + lr) * H2 + ks * 32 + lg * 8);
            #pragma unroll
            for (int ct = 0; ct < 8; ++ct) {
                bf16x8 bb = *(const bf16x8*)(tc + (cb + ct * 16 + lr) * H2 + ks * 32 + lg * 8);
                acc[0][ct] = __builtin_amdgcn_mfma_f32_16x16x32_bf16(a0, bb, acc[0][ct], 0, 0, 0);
                acc[1][ct] = __builtin_amdgcn_mfma_f32_16x16x32_bf16(a1, bb, acc[1][ct], 0, 0, 0);
            }
        }
        #pragma unroll
        for (int jt = 0; jt < 2; ++jt)
            #pragma unroll
            for (int ct = 0; ct < 8; ++ct)
                #pragma unroll
                for (int r = 0; r < 4; ++r) {
                    int j = jb + jt * 16 + lg * 4 + r;
                    int c = cb + ct * 16 + lr;
                    int byteoff = (((j << 8) + c) << 1) ^ ((j & 7) << 4);
                    *(unsigned short*)((char*)W + byteoff) = f2bf(acc[jt][ct][r]);
                }
    }
    __syncthreads();

    // ---- G2: P[i][j] = sum_c hepB[k][i][c] * W[j][c]
    {
        const int ib = (w & 3) * 32;          // 2 i-tiles
        const int jb = (w >> 2) * 64;         // 4 j-tiles
        f32x4 acc[2][4];
        #pragma unroll
        for (int a = 0; a < 2; ++a)
            #pragma unroll
            for (int b = 0; b < 4; ++b) acc[a][b] = (f32x4){0.f, 0.f, 0.f, 0.f};

        const unsigned short* hk = hepB + (size_t)k * (NENT * H2);
        for (int ks = 0; ks < 8; ++ks) {
            bf16x8 a0 = *(const bf16x8*)(hk + (ib +      lr) * H2 + ks * 32 + lg * 8);
            bf16x8 a1 = *(const bf16x8*)(hk + (ib + 16 + lr) * H2 + ks * 32 + lg * 8);
            #pragma unroll
            for (int jt = 0; jt < 4; ++jt) {
                int j = jb + jt * 16 + lr;
                int byteoff = ((((j << 8) + ks * 32 + lg * 8)) << 1) ^ ((j & 7) << 4);
                bf16x8 bb = *(const bf16x8*)((const char*)W + byteoff);
                acc[0][jt] = __builtin_amdgcn_mfma_f32_16x16x32_bf16(a0, bb, acc[0][jt], 0, 0, 0);
                acc[1][jt] = __builtin_amdgcn_mfma_f32_16x16x32_bf16(a1, bb, acc[1][jt], 0, 0, 0);
            }
        }
        float* po = predT + (size_t)bid * (NENT * NENT);
        #pragma unroll
        for (int it = 0; it < 2; ++it)
            #pragma unroll
            for (int jt = 0; jt < 4; ++jt)
                #pragma unroll
                for (int r = 0; r < 4; ++r) {
                    int i = ib + it * 16 + lg * 4 + r;
                    int j = jb + jt * 16 + lr;
                    po[i * NENT + j] = acc[it][jt][r];
                }
    }
}

// ---------------- transpose: predT[km][ij] -> out[ij][km] ----------------
// grid 2048 = 512 ij-tiles(32) x 4 km-chunks(160)
__global__ __launch_bounds__(256)
void transpose_out(const float* __restrict__ predT, float* __restrict__ out)
{
    __shared__ float Ls[160][33];
    const int bid = blockIdx.x;
    const int ij0 = (bid >> 2) * 32;
    const int km0 = (bid & 3) * 160;
    const int t = threadIdx.x;

    #pragma unroll
    for (int q = 0; q < 20; ++q) {
        int r = (t >> 5) + q * 8;          // local km 0..159
        int c = t & 31;                    // local ij
        Ls[r][c] = predT[(size_t)(km0 + r) * 16384 + ij0 + c];
    }
    __syncthreads();
    for (int idx = t; idx < 32 * 160; idx += 256) {
        int r = idx / 160, c = idx % 160;  // r: local ij, c: local km
        out[(size_t)(ij0 + r) * 640 + km0 + c] = Ls[c][r];
    }
}

extern "C" void kernel_launch(void* const* d_in, const int* in_sizes, int n_in,
                              void* d_out, int out_size, void* d_ws, size_t ws_size,
                              hipStream_t stream)
{
    (void)in_sizes; (void)n_in; (void)out_size; (void)ws_size;
    const float* enc  = (const float*)d_in[0];
    const int*   hidx = (const int*)d_in[1];
    const int*   tidx = (const int*)d_in[2];
    const int*   eidx = (const int*)d_in[3];
    const float* Whf = (const float*)d_in[4];
    const float* bhf = (const float*)d_in[5];
    const float* Whb = (const float*)d_in[6];
    const float* bhb = (const float*)d_in[7];
    const float* Wtf = (const float*)d_in[8];
    const float* btf = (const float*)d_in[9];
    const float* Wtb = (const float*)d_in[10];
    const float* btb = (const float*)d_in[11];
    const float* Wef = (const float*)d_in[12];
    const float* bef = (const float*)d_in[13];
    const float* Web = (const float*)d_in[14];
    const float* beb = (const float*)d_in[15];
    const float* T_he  = (const float*)d_in[16];
    const float* T_te  = (const float*)d_in[17];
    const float* T_cls = (const float*)d_in[18];

    float* out  = (float*)d_out;
    char*  ws   = (char*)d_ws;
    float*          pool  = (float*)ws;
    unsigned short* hepB  = (unsigned short*)(ws + HEPB_OFF);
    unsigned short* tepB  = (unsigned short*)(ws + TEPB_OFF);
    unsigned short* TclsB = (unsigned short*)(ws + TCLSB_OFF);
    float*          tmp   = (float*)(ws + TMP_OFF);
    float*          predT = (float*)(ws + PREDT_OFF);

    pool_kernel<<<384, 256, 0, stream>>>(enc, hidx, tidx, eidx,
        Whf, bhf, Whb, bhb, Wtf, btf, Wtb, btb, Wef, bef, Web, beb, pool);

    conv_tcls<<<1280, 256, 0, stream>>>(T_cls, TclsB);

    gemm1_kernel<<<512, 256, 0, stream>>>(pool + 2 * NENT * H2, T_he, tmp);
    gemm2_kernel<<<256, 256, 0, stream>>>(pool + 0 * NENT * H2, tmp, hepB);

    gemm1_kernel<<<512, 256, 0, stream>>>(pool + 2 * NENT * H2, T_te, tmp);
    gemm2_kernel<<<256, 256, 0, stream>>>(pool + 1 * NENT * H2, tmp, tepB);

    step3_mfma<<<640, 512, 0, stream>>>(hepB, tepB, TclsB, predT);

    transpose_out<<<2048, 256, 0, stream>>>(predT, out);
}

// Round 3
// 307.176 us; speedup vs baseline: 3.9171x; 1.9283x over previous
//
#include <hip/hip_runtime.h>
#include <hip/hip_bf16.h>
#include <math.h>

#define DIM   768
#define HID   128
#define H2    256
#define NENT  128
#define SPAN  16
#define NCLS  5

// ---- ws layout (bytes) ----
// poolB bf16 [3][128][256]              @ 0          (196,608)
// hepB  bf16 [k][i][c]                  @ 196608     (8,388,608)
// tepB  bf16 [k][j][b]                  @ 8585216    (8,388,608)
// TclsB bf16 [m][c][b]                  @ 16973824   (655,360)
// WB    bf16 [3][2][384][768]           @ 17629184   (3,538,944)
// tmpT  bf16 [k][b][a] 128*256*256      @ 21168128   (16,777,216)  dead before step3
// predT fp32 [k*5+m][i][j]              @ 21168128   (41,943,040)  overlaps tmpT
// end = 63,111,168 B  (ws >= 67.5 MB proven in round 1)
#define POOLB_OFF 0
#define HEPB_OFF  196608
#define TEPB_OFF  (HEPB_OFF + 8388608)
#define TCLSB_OFF (TEPB_OFF + 8388608)
#define WB_OFF    (TCLSB_OFF + 655360)
#define TMPT_OFF  (WB_OFF + 3538944)
#define PREDT_OFF TMPT_OFF

typedef __attribute__((ext_vector_type(8))) short bf16x8;
typedef __attribute__((ext_vector_type(4))) float f32x4;

__device__ __forceinline__ float sigmoidf_(float x) { return 1.0f / (1.0f + __expf(-x)); }

__device__ __forceinline__ unsigned short f2bf(float x) {
    __hip_bfloat16 h = __float2bfloat16(x);
    return *reinterpret_cast<unsigned short*>(&h);
}

// ---------------- weight convert: 6 x fp32[512][768] -> bf16 WB[t2][384][768] (i,g,o rows) ----
__global__ __launch_bounds__(256)
void wconv(const float* __restrict__ Whf, const float* __restrict__ Whb,
           const float* __restrict__ Wtf, const float* __restrict__ Wtb,
           const float* __restrict__ Wef, const float* __restrict__ Web,
           unsigned short* __restrict__ WB)
{
    int gid = blockIdx.x * 256 + threadIdx.x;        // < 442368
    int t2  = gid / 73728;                           // type*2+dir
    int rem = gid % 73728;
    int n   = rem / 192;                             // gate*128 + j
    int c4  = rem % 192;
    int gate = n >> 7, j = n & 127;
    int srow = (gate == 0) ? j : (gate == 1) ? 256 + j : 384 + j;
    const float* W = (t2 == 0) ? Whf : (t2 == 1) ? Whb : (t2 == 2) ? Wtf :
                     (t2 == 3) ? Wtb : (t2 == 4) ? Wef : Web;
    float4 v = ((const float4*)(W + srow * DIM))[c4];
    unsigned short* d = WB + ((size_t)(t2 * 384 + n)) * DIM + c4 * 4;
    d[0] = f2bf(v.x); d[1] = f2bf(v.y); d[2] = f2bf(v.z); d[3] = f2bf(v.w);
}

// ---------------- convert T_cls[b][m][c] -> bf16 TclsB[m][c][b] ----------------
__global__ __launch_bounds__(256)
void conv_tcls(const float* __restrict__ T, unsigned short* __restrict__ TB)
{
    int idx = blockIdx.x * 256 + threadIdx.x;        // 327680 total
    int b = idx / (NCLS * H2);
    int r = idx % (NCLS * H2);
    int m = r >> 8, c = r & 255;
    TB[((m << 8) + c) * H2 + b] = f2bf(T[idx]);
}

// ---------------- pool via MFMA: gates GEMM + LSTM nonlinearity + span max ----------------
// grid 384 = type(3) x ent(128); block 128 = 2 waves (dir)
__global__ __launch_bounds__(128, 2)
void pool_mfma(const float* __restrict__ enc,
               const int* __restrict__ idx_h, const int* __restrict__ idx_t, const int* __restrict__ idx_e,
               const unsigned short* __restrict__ WB,   // [3][2][384][768]
               const float* __restrict__ bhf, const float* __restrict__ bhb,
               const float* __restrict__ btf, const float* __restrict__ btb,
               const float* __restrict__ bef, const float* __restrict__ beb,
               unsigned short* __restrict__ poolB)      // [3][128][256]
{
    __shared__ unsigned short toks[SPAN * 776];         // padded: 2-way-free banks
    const int tid  = threadIdx.x;
    const int type = blockIdx.x >> 7;
    const int ent  = blockIdx.x & 127;
    const int* idx = (type == 0) ? idx_h : (type == 1) ? idx_t : idx_e;

    // stage 16 gathered rows, fp32 -> bf16
    #pragma unroll
    for (int q = 0; q < 24; ++q) {
        int fid = tid + q * 128;                // 0..3071 : 16 rows x 192 float4
        int r = fid / 192, c4 = fid % 192;
        int row = idx[ent * SPAN + r];
        float4 v = ((const float4*)(enc + (size_t)row * DIM))[c4];
        unsigned short h4[4] = { f2bf(v.x), f2bf(v.y), f2bf(v.z), f2bf(v.w) };
        *(uint2*)(&toks[r * 776 + c4 * 4]) = *(uint2*)h4;
    }
    __syncthreads();

    const int w  = tid >> 6;                    // dir
    const int l  = tid & 63;
    const int lr = l & 15, lg = l >> 4;

    const unsigned short* Wb = WB + (size_t)(type * 2 + w) * 384 * DIM;
    const float* Bv = (type == 0) ? (w ? bhb : bhf)
                    : (type == 1) ? (w ? btb : btf)
                                  : (w ? beb : bef);

    f32x4 acc[3][8];
    #pragma unroll
    for (int g = 0; g < 3; ++g)
        #pragma unroll
        for (int jt = 0; jt < 8; ++jt) acc[g][jt] = (f32x4){0.f, 0.f, 0.f, 0.f};

    #pragma unroll 1
    for (int ks = 0; ks < 24; ++ks) {
        bf16x8 a = *(const bf16x8*)(&toks[lr * 776 + ks * 32 + lg * 8]);
        #pragma unroll
        for (int jt = 0; jt < 8; ++jt) {
            #pragma unroll
            for (int g = 0; g < 3; ++g) {
                bf16x8 bb = *(const bf16x8*)(Wb + (size_t)(g * 128 + jt * 16 + lr) * DIM + ks * 32 + lg * 8);
                acc[g][jt] = __builtin_amdgcn_mfma_f32_16x16x32_bf16(a, bb, acc[g][jt], 0, 0, 0);
            }
        }
    }

    #pragma unroll
    for (int jt = 0; jt < 8; ++jt) {
        int j = jt * 16 + lr;
        float bi = Bv[j], bg = Bv[2 * HID + j], bo = Bv[3 * HID + j];
        float vmax = -1e30f;
        #pragma unroll
        for (int r = 0; r < 4; ++r) {
            float iv = sigmoidf_(acc[0][jt][r] + bi);
            float gv = tanhf(acc[1][jt][r] + bg);
            float ov = sigmoidf_(acc[2][jt][r] + bo);
            float h  = ov * tanhf(iv * gv);
            vmax = fmaxf(vmax, h);
        }
        vmax = fmaxf(vmax, __shfl_xor(vmax, 16, 64));
        vmax = fmaxf(vmax, __shfl_xor(vmax, 32, 64));
        if (lg == 0)
            poolB[(size_t)(type * NENT + ent) * H2 + w * HID + j] = f2bf(vmax);
    }
}

// ---------------- gemm1 MFMA: tmpT[k][b][a] = sum_c Ee[k][c] * T[a][b][c] ----------------
// grid 256 (one b per block); block 512 = 8 waves; wave tile 64k x 64a
__global__ __launch_bounds__(512, 2)
void gemm1_mfma(const unsigned short* __restrict__ EeB, // [128][256] bf16
                const float* __restrict__ T,            // [a][b][c] fp32
                unsigned short* __restrict__ tmpT)      // [k][b][a] bf16
{
    const int tid = threadIdx.x;
    const int w = tid >> 6, l = tid & 63;
    const int lr = l & 15, lg = l >> 4;
    const int b   = blockIdx.x;
    const int mb  = (w & 1) * 64;
    const int nbw = (w >> 1) * 64;

    f32x4 acc[4][4];
    #pragma unroll
    for (int mt = 0; mt < 4; ++mt)
        #pragma unroll
        for (int nt = 0; nt < 4; ++nt) acc[mt][nt] = (f32x4){0.f, 0.f, 0.f, 0.f};

    #pragma unroll 1
    for (int ks = 0; ks < 8; ++ks) {
        bf16x8 af[4];
        #pragma unroll
        for (int mt = 0; mt < 4; ++mt)
            af[mt] = *(const bf16x8*)(EeB + (mb + mt * 16 + lr) * H2 + ks * 32 + lg * 8);
        #pragma unroll
        for (int nt = 0; nt < 4; ++nt) {
            int a_ = nbw + nt * 16 + lr;
            const float* tr = T + ((size_t)a_ * 256 + b) * 256 + ks * 32 + lg * 8;
            float4 v0 = ((const float4*)tr)[0];
            float4 v1 = ((const float4*)tr)[1];
            bf16x8 bf;
            unsigned short* bp = (unsigned short*)&bf;
            bp[0] = f2bf(v0.x); bp[1] = f2bf(v0.y); bp[2] = f2bf(v0.z); bp[3] = f2bf(v0.w);
            bp[4] = f2bf(v1.x); bp[5] = f2bf(v1.y); bp[6] = f2bf(v1.z); bp[7] = f2bf(v1.w);
            #pragma unroll
            for (int mt = 0; mt < 4; ++mt)
                acc[mt][nt] = __builtin_amdgcn_mfma_f32_16x16x32_bf16(af[mt], bf, acc[mt][nt], 0, 0, 0);
        }
    }
    #pragma unroll
    for (int mt = 0; mt < 4; ++mt)
        #pragma unroll
        for (int nt = 0; nt < 4; ++nt)
            #pragma unroll
            for (int r = 0; r < 4; ++r) {
                int k  = mb + mt * 16 + lg * 4 + r;
                int a_ = nbw + nt * 16 + lr;
                tmpT[(size_t)k * 65536 + b * 256 + a_] = f2bf(acc[mt][nt][r]);
            }
}

// ---------------- gemm2 MFMA (NT): out[k][i][b] = sum_a Hx[i][a] * tmpT[k][b][a] ----------
// grid 256 = k(128) x bhalf(2); block 256 = 4 waves; wave tile 64i x 64b
__global__ __launch_bounds__(256, 2)
void gemm2_mfma(const unsigned short* __restrict__ HxB, // [128][256] bf16
                const unsigned short* __restrict__ tmpT,// [k][b][a] bf16
                unsigned short* __restrict__ outB)      // [k][i][b] bf16
{
    const int tid = threadIdx.x;
    const int w = tid >> 6, l = tid & 63;
    const int lr = l & 15, lg = l >> 4;
    const int k   = blockIdx.x >> 1;
    const int nb0 = (blockIdx.x & 1) * 128;
    const int ib  = (w & 1) * 64;
    const int bb  = (w >> 1) * 64;
    const unsigned short* Bp = tmpT + (size_t)k * 65536;

    f32x4 acc[4][4];
    #pragma unroll
    for (int mt = 0; mt < 4; ++mt)
        #pragma unroll
        for (int nt = 0; nt < 4; ++nt) acc[mt][nt] = (f32x4){0.f, 0.f, 0.f, 0.f};

    #pragma unroll 1
    for (int ks = 0; ks < 8; ++ks) {
        bf16x8 af[4], bf[4];
        #pragma unroll
        for (int mt = 0; mt < 4; ++mt)
            af[mt] = *(const bf16x8*)(HxB + (ib + mt * 16 + lr) * H2 + ks * 32 + lg * 8);
        #pragma unroll
        for (int nt = 0; nt < 4; ++nt)
            bf[nt] = *(const bf16x8*)(Bp + (nb0 + bb + nt * 16 + lr) * H2 + ks * 32 + lg * 8);
        #pragma unroll
        for (int mt = 0; mt < 4; ++mt)
            #pragma unroll
            for (int nt = 0; nt < 4; ++nt)
                acc[mt][nt] = __builtin_amdgcn_mfma_f32_16x16x32_bf16(af[mt], bf[nt], acc[mt][nt], 0, 0, 0);
    }
    #pragma unroll
    for (int mt = 0; mt < 4; ++mt)
        #pragma unroll
        for (int nt = 0; nt < 4; ++nt)
            #pragma unroll
            for (int r = 0; r < 4; ++r) {
                int i = ib + mt * 16 + lg * 4 + r;
                int bc = nb0 + bb + nt * 16 + lr;
                outB[(size_t)k * (NENT * H2) + i * H2 + bc] = f2bf(acc[mt][nt][r]);
            }
}

// ---------------- step3 MFMA: per (k,m): W = tep_k @ Tcls_m ; P = hep_k @ W^T ----------------
__global__ __launch_bounds__(512)
void step3_mfma(const unsigned short* __restrict__ hepB,  // [k][i][c]
                const unsigned short* __restrict__ tepB,  // [k][j][b]
                const unsigned short* __restrict__ TclsB, // [m][c][b]
                float* __restrict__ predT)                // [k*5+m][i][j]
{
    __shared__ unsigned short W[128 * 256];   // [j][c] bf16, byte ^= (j&7)<<4
    const int bid = blockIdx.x;
    const int k = bid / 5, m = bid % 5;
    const int tid = threadIdx.x;
    const int w  = tid >> 6;
    const int l  = tid & 63;
    const int lr = l & 15;
    const int lg = l >> 4;

    {
        const int jb = (w & 3) * 32;
        const int cb = (w >> 2) * 128;
        f32x4 acc[2][8];
        #pragma unroll
        for (int a = 0; a < 2; ++a)
            #pragma unroll
            for (int b = 0; b < 8; ++b) acc[a][b] = (f32x4){0.f, 0.f, 0.f, 0.f};

        const unsigned short* tk = tepB  + (size_t)k * (NENT * H2);
        const unsigned short* tc = TclsB + (size_t)m * (H2 * H2);
        for (int ks = 0; ks < 8; ++ks) {
            bf16x8 a0 = *(const bf16x8*)(tk + (jb +      lr) * H2 + ks * 32 + lg * 8);
            bf16x8 a1 = *(const bf16x8*)(tk + (jb + 16 + lr) * H2 + ks * 32 + lg * 8);
            #pragma unroll
            for (int ct = 0; ct < 8; ++ct) {
                bf16x8 bb = *(const bf16x8*)(tc + (cb + ct * 16 + lr) * H2 + ks * 32 + lg * 8);
                acc[0][ct] = __builtin_amdgcn_mfma_f32_16x16x32_bf16(a0, bb, acc[0][ct], 0, 0, 0);
                acc[1][ct] = __builtin_amdgcn_mfma_f32_16x16x32_bf16(a1, bb, acc[1][ct], 0, 0, 0);
            }
        }
        #pragma unroll
        for (int jt = 0; jt < 2; ++jt)
            #pragma unroll
            for (int ct = 0; ct < 8; ++ct)
                #pragma unroll
                for (int r = 0; r < 4; ++r) {
                    int j = jb + jt * 16 + lg * 4 + r;
                    int c = cb + ct * 16 + lr;
                    int byteoff = (((j << 8) + c) << 1) ^ ((j & 7) << 4);
                    *(unsigned short*)((char*)W + byteoff) = f2bf(acc[jt][ct][r]);
                }
    }
    __syncthreads();

    {
        const int ib = (w & 3) * 32;
        const int jb = (w >> 2) * 64;
        f32x4 acc[2][4];
        #pragma unroll
        for (int a = 0; a < 2; ++a)
            #pragma unroll
            for (int b = 0; b < 4; ++b) acc[a][b] = (f32x4){0.f, 0.f, 0.f, 0.f};

        const unsigned short* hk = hepB + (size_t)k * (NENT * H2);
        for (int ks = 0; ks < 8; ++ks) {
            bf16x8 a0 = *(const bf16x8*)(hk + (ib +      lr) * H2 + ks * 32 + lg * 8);
            bf16x8 a1 = *(const bf16x8*)(hk + (ib + 16 + lr) * H2 + ks * 32 + lg * 8);
            #pragma unroll
            for (int jt = 0; jt < 4; ++jt) {
                int j = jb + jt * 16 + lr;
                int byteoff = ((((j << 8) + ks * 32 + lg * 8)) << 1) ^ ((j & 7) << 4);
                bf16x8 bb = *(const bf16x8*)((const char*)W + byteoff);
                acc[0][jt] = __builtin_amdgcn_mfma_f32_16x16x32_bf16(a0, bb, acc[0][jt], 0, 0, 0);
                acc[1][jt] = __builtin_amdgcn_mfma_f32_16x16x32_bf16(a1, bb, acc[1][jt], 0, 0, 0);
            }
        }
        float* po = predT + (size_t)bid * (NENT * NENT);
        #pragma unroll
        for (int it = 0; it < 2; ++it)
            #pragma unroll
            for (int jt = 0; jt < 4; ++jt)
                #pragma unroll
                for (int r = 0; r < 4; ++r) {
                    int i = ib + it * 16 + lg * 4 + r;
                    int j = jb + jt * 16 + lr;
                    po[i * NENT + j] = acc[it][jt][r];
                }
    }
}

// ---------------- transpose: predT[km][ij] -> out[ij][km] ----------------
__global__ __launch_bounds__(256)
void transpose_out(const float* __restrict__ predT, float* __restrict__ out)
{
    __shared__ float Ls[160][33];
    const int bid = blockIdx.x;
    const int ij0 = (bid >> 2) * 32;
    const int km0 = (bid & 3) * 160;
    const int t = threadIdx.x;

    #pragma unroll
    for (int q = 0; q < 20; ++q) {
        int r = (t >> 5) + q * 8;
        int c = t & 31;
        Ls[r][c] = predT[(size_t)(km0 + r) * 16384 + ij0 + c];
    }
    __syncthreads();
    for (int idx = t; idx < 32 * 160; idx += 256) {
        int r = idx / 160, c = idx % 160;
        out[(size_t)(ij0 + r) * 640 + km0 + c] = Ls[c][r];
    }
}

extern "C" void kernel_launch(void* const* d_in, const int* in_sizes, int n_in,
                              void* d_out, int out_size, void* d_ws, size_t ws_size,
                              hipStream_t stream)
{
    (void)in_sizes; (void)n_in; (void)out_size; (void)ws_size;
    const float* enc  = (const float*)d_in[0];
    const int*   hidx = (const int*)d_in[1];
    const int*   tidx = (const int*)d_in[2];
    const int*   eidx = (const int*)d_in[3];
    const float* Whf = (const float*)d_in[4];
    const float* bhf = (const float*)d_in[5];
    const float* Whb = (const float*)d_in[6];
    const float* bhb = (const float*)d_in[7];
    const float* Wtf = (const float*)d_in[8];
    const float* btf = (const float*)d_in[9];
    const float* Wtb = (const float*)d_in[10];
    const float* btb = (const float*)d_in[11];
    const float* Wef = (const float*)d_in[12];
    const float* bef = (const float*)d_in[13];
    const float* Web = (const float*)d_in[14];
    const float* beb = (const float*)d_in[15];
    const float* T_he  = (const float*)d_in[16];
    const float* T_te  = (const float*)d_in[17];
    const float* T_cls = (const float*)d_in[18];

    float* out = (float*)d_out;
    char*  ws  = (char*)d_ws;
    unsigned short* poolB = (unsigned short*)(ws + POOLB_OFF);
    unsigned short* hepB  = (unsigned short*)(ws + HEPB_OFF);
    unsigned short* tepB  = (unsigned short*)(ws + TEPB_OFF);
    unsigned short* TclsB = (unsigned short*)(ws + TCLSB_OFF);
    unsigned short* WB    = (unsigned short*)(ws + WB_OFF);
    unsigned short* tmpT  = (unsigned short*)(ws + TMPT_OFF);
    float*          predT = (float*)(ws + PREDT_OFF);

    unsigned short* HeB = poolB;
    unsigned short* TeB = poolB + 1 * NENT * H2;
    unsigned short* EeB = poolB + 2 * NENT * H2;

    wconv<<<1728, 256, 0, stream>>>(Whf, Whb, Wtf, Wtb, Wef, Web, WB);
    conv_tcls<<<1280, 256, 0, stream>>>(T_cls, TclsB);

    pool_mfma<<<384, 128, 0, stream>>>(enc, hidx, tidx, eidx, WB,
                                       bhf, bhb, btf, btb, bef, beb, poolB);

    gemm1_mfma<<<256, 512, 0, stream>>>(EeB, T_he, tmpT);
    gemm2_mfma<<<256, 256, 0, stream>>>(HeB, tmpT, hepB);

    gemm1_mfma<<<256, 512, 0, stream>>>(EeB, T_te, tmpT);
    gemm2_mfma<<<256, 256, 0, stream>>>(TeB, tmpT, tepB);

    step3_mfma<<<640, 512, 0, stream>>>(hepB, tepB, TclsB, predT);

    transpose_out<<<2048, 256, 0, stream>>>(predT, out);
}

// Round 4
// 245.739 us; speedup vs baseline: 4.8963x; 1.2500x over previous
//
#include <hip/hip_runtime.h>
#include <hip/hip_bf16.h>
#include <math.h>

#define DIM   768
#define HID   128
#define H2    256
#define NENT  128
#define SPAN  16
#define NCLS  5

// ---- ws layout (bytes) ----
// poolB bf16 [3][128][256]              @ 0          (196,608)
// hepB  bf16 [k][i][c]                  @ 196608     (8,388,608)
// tepB  bf16 [k][j][b]                  @ 8585216    (8,388,608)
// TclsB bf16 [m][c][b]                  @ 16973824   (655,360)
// WB    bf16 [3][768][768] (dir*384+g*128+j rows)  @ 17629184 (3,538,944)
// tokB  bf16 [3][2048][768]             @ 21168128   (9,437,184)   dead after gates
// gates fp32 [3][2048][768]             @ 30605312   (18,874,368)  dead after epilogue
// tmpT  bf16 [k][b][a] 128*256*256      @ 21168128   (16,777,216)  dead before step3
// predT fp32 [k*5+m][i][j]              @ 21168128   (41,943,040)  overlaps tmpT/tokB/gates
// end = 63,111,168 B  (ws >= 67.5 MB proven in round 1)
#define POOLB_OFF 0
#define HEPB_OFF  196608
#define TEPB_OFF  (HEPB_OFF + 8388608)
#define TCLSB_OFF (TEPB_OFF + 8388608)
#define WB_OFF    (TCLSB_OFF + 655360)
#define TMPT_OFF  (WB_OFF + 3538944)
#define TOKB_OFF  TMPT_OFF
#define GATES_OFF (TOKB_OFF + 9437184)
#define PREDT_OFF TMPT_OFF

typedef __attribute__((ext_vector_type(8))) short bf16x8;
typedef __attribute__((ext_vector_type(4))) float f32x4;

__device__ __forceinline__ float sigmoidf_(float x) { return 1.0f / (1.0f + __expf(-x)); }

__device__ __forceinline__ unsigned short f2bf(float x) {
    __hip_bfloat16 h = __float2bfloat16(x);
    return *reinterpret_cast<unsigned short*>(&h);
}

// ---------------- weight convert: 6 x fp32[512][768] -> bf16 WB[type][dir*384+g*128+j][768] ----
__global__ __launch_bounds__(256)
void wconv(const float* __restrict__ Whf, const float* __restrict__ Whb,
           const float* __restrict__ Wtf, const float* __restrict__ Wtb,
           const float* __restrict__ Wef, const float* __restrict__ Web,
           unsigned short* __restrict__ WB)
{
    int gid = blockIdx.x * 256 + threadIdx.x;        // < 442368
    int t2  = gid / 73728;                           // type*2+dir
    int rem = gid % 73728;
    int n   = rem / 192;                             // gate*128 + j
    int c4  = rem % 192;
    int gate = n >> 7, j = n & 127;
    int srow = (gate == 0) ? j : (gate == 1) ? 256 + j : 384 + j;
    const float* W = (t2 == 0) ? Whf : (t2 == 1) ? Whb : (t2 == 2) ? Wtf :
                     (t2 == 3) ? Wtb : (t2 == 4) ? Wef : Web;
    float4 v = ((const float4*)(W + srow * DIM))[c4];
    unsigned short* d = WB + ((size_t)(t2 * 384 + n)) * DIM + c4 * 4;
    d[0] = f2bf(v.x); d[1] = f2bf(v.y); d[2] = f2bf(v.z); d[3] = f2bf(v.w);
}

// ---------------- convert T_cls[b][m][c] -> bf16 TclsB[m][c][b] ----------------
__global__ __launch_bounds__(256)
void conv_tcls(const float* __restrict__ T, unsigned short* __restrict__ TB)
{
    int idx = blockIdx.x * 256 + threadIdx.x;        // 327680 total
    int b = idx / (NCLS * H2);
    int r = idx % (NCLS * H2);
    int m = r >> 8, c = r & 255;
    TB[((m << 8) + c) * H2 + b] = f2bf(T[idx]);
}

// ---------------- gather tokens: tokB[type][ent*16+l][k] bf16 ----------------
__global__ __launch_bounds__(256)
void gather_toks(const float* __restrict__ enc,
                 const int* __restrict__ idx_h, const int* __restrict__ idx_t, const int* __restrict__ idx_e,
                 unsigned short* __restrict__ tokB)
{
    int gid = blockIdx.x * 256 + threadIdx.x;        // < 6144*192
    int r  = gid / 192, c4 = gid % 192;
    int type = r >> 11;
    int rem  = r & 2047;                             // ent*16+l
    const int* idx = (type == 0) ? idx_h : (type == 1) ? idx_t : idx_e;
    int row = idx[rem];
    float4 v = ((const float4*)(enc + (size_t)row * DIM))[c4];
    unsigned short h4[4] = { f2bf(v.x), f2bf(v.y), f2bf(v.z), f2bf(v.w) };
    *(uint2*)(tokB + (size_t)r * DIM + c4 * 4) = *(uint2*)h4;
}

// ---------------- gates GEMM (NT): gates[type][r][col] = sum_k tokB[type][r][k]*WB[type][col][k]
// grid 576 = type(3) x mtile(16) x ntile(12); block 256 = 4 waves; tile 128x64, wave 64x32
__global__ __launch_bounds__(256, 2)
void gates_mfma(const unsigned short* __restrict__ tokB,
                const unsigned short* __restrict__ WB,
                float* __restrict__ gates)
{
    const int tid = threadIdx.x;
    const int w = tid >> 6, l = tid & 63;
    const int lr = l & 15, lg = l >> 4;
    const int bid = blockIdx.x;
    const int type = bid / 192;
    const int rem  = bid % 192;
    const int mb = (rem / 12) * 128 + (w & 1) * 64;
    const int cb = (rem % 12) * 64  + (w >> 1) * 32;
    const unsigned short* A = tokB + (size_t)type * 2048 * DIM;
    const unsigned short* B = WB   + (size_t)type * 768 * DIM;

    f32x4 acc[4][2];
    #pragma unroll
    for (int mt = 0; mt < 4; ++mt)
        #pragma unroll
        for (int nt = 0; nt < 2; ++nt) acc[mt][nt] = (f32x4){0.f, 0.f, 0.f, 0.f};

    #pragma unroll 1
    for (int ks = 0; ks < 24; ++ks) {
        bf16x8 af[4], bf[2];
        #pragma unroll
        for (int mt = 0; mt < 4; ++mt)
            af[mt] = *(const bf16x8*)(A + (size_t)(mb + mt * 16 + lr) * DIM + ks * 32 + lg * 8);
        #pragma unroll
        for (int nt = 0; nt < 2; ++nt)
            bf[nt] = *(const bf16x8*)(B + (size_t)(cb + nt * 16 + lr) * DIM + ks * 32 + lg * 8);
        #pragma unroll
        for (int mt = 0; mt < 4; ++mt)
            #pragma unroll
            for (int nt = 0; nt < 2; ++nt)
                acc[mt][nt] = __builtin_amdgcn_mfma_f32_16x16x32_bf16(af[mt], bf[nt], acc[mt][nt], 0, 0, 0);
    }
    float* C = gates + (size_t)type * 2048 * 768;
    #pragma unroll
    for (int mt = 0; mt < 4; ++mt)
        #pragma unroll
        for (int nt = 0; nt < 2; ++nt)
            #pragma unroll
            for (int r = 0; r < 4; ++r)
                C[(size_t)(mb + mt * 16 + lg * 4 + r) * 768 + cb + nt * 16 + lr] = acc[mt][nt][r];
}

// ---------------- pool epilogue: LSTM nonlinearity + span max ----------------
// grid 384 = type x ent; block 256 = (dir, j)
__global__ __launch_bounds__(256)
void pool_epilogue(const float* __restrict__ gates,
                   const float* __restrict__ bhf, const float* __restrict__ bhb,
                   const float* __restrict__ btf, const float* __restrict__ btb,
                   const float* __restrict__ bef, const float* __restrict__ beb,
                   unsigned short* __restrict__ poolB)
{
    const int type = blockIdx.x >> 7;
    const int ent  = blockIdx.x & 127;
    const int tid  = threadIdx.x;
    const int dir  = tid >> 7;
    const int j    = tid & 127;
    const float* Bv = (type == 0) ? (dir ? bhb : bhf)
                    : (type == 1) ? (dir ? btb : btf)
                                  : (dir ? beb : bef);
    const float bi = Bv[j], bg = Bv[2 * HID + j], bo = Bv[3 * HID + j];
    const float* g0 = gates + ((size_t)type * 2048 + ent * 16) * 768 + dir * 384 + j;
    float hmax = -1e30f;
    #pragma unroll
    for (int l = 0; l < SPAN; ++l) {
        const float* gr = g0 + l * 768;
        float iv = sigmoidf_(gr[0]   + bi);
        float gv = tanhf(   gr[128] + bg);
        float ov = sigmoidf_(gr[256] + bo);
        hmax = fmaxf(hmax, ov * tanhf(iv * gv));
    }
    poolB[(size_t)(type * NENT + ent) * H2 + dir * HID + j] = f2bf(hmax);
}

// ---------------- gemm1 MFMA: tmpT[k][b][a] = sum_c Ee[k][c] * T[a][b][c] ----------------
__global__ __launch_bounds__(512, 2)
void gemm1_mfma(const unsigned short* __restrict__ EeB, // [128][256] bf16
                const float* __restrict__ T,            // [a][b][c] fp32
                unsigned short* __restrict__ tmpT)      // [k][b][a] bf16
{
    const int tid = threadIdx.x;
    const int w = tid >> 6, l = tid & 63;
    const int lr = l & 15, lg = l >> 4;
    const int b   = blockIdx.x;
    const int mb  = (w & 1) * 64;
    const int nbw = (w >> 1) * 64;

    f32x4 acc[4][4];
    #pragma unroll
    for (int mt = 0; mt < 4; ++mt)
        #pragma unroll
        for (int nt = 0; nt < 4; ++nt) acc[mt][nt] = (f32x4){0.f, 0.f, 0.f, 0.f};

    #pragma unroll 1
    for (int ks = 0; ks < 8; ++ks) {
        bf16x8 af[4];
        #pragma unroll
        for (int mt = 0; mt < 4; ++mt)
            af[mt] = *(const bf16x8*)(EeB + (mb + mt * 16 + lr) * H2 + ks * 32 + lg * 8);
        #pragma unroll
        for (int nt = 0; nt < 4; ++nt) {
            int a_ = nbw + nt * 16 + lr;
            const float* tr = T + ((size_t)a_ * 256 + b) * 256 + ks * 32 + lg * 8;
            float4 v0 = ((const float4*)tr)[0];
            float4 v1 = ((const float4*)tr)[1];
            bf16x8 bf;
            unsigned short* bp = (unsigned short*)&bf;
            bp[0] = f2bf(v0.x); bp[1] = f2bf(v0.y); bp[2] = f2bf(v0.z); bp[3] = f2bf(v0.w);
            bp[4] = f2bf(v1.x); bp[5] = f2bf(v1.y); bp[6] = f2bf(v1.z); bp[7] = f2bf(v1.w);
            #pragma unroll
            for (int mt = 0; mt < 4; ++mt)
                acc[mt][nt] = __builtin_amdgcn_mfma_f32_16x16x32_bf16(af[mt], bf, acc[mt][nt], 0, 0, 0);
        }
    }
    #pragma unroll
    for (int mt = 0; mt < 4; ++mt)
        #pragma unroll
        for (int nt = 0; nt < 4; ++nt)
            #pragma unroll
            for (int r = 0; r < 4; ++r) {
                int k  = mb + mt * 16 + lg * 4 + r;
                int a_ = nbw + nt * 16 + lr;
                tmpT[(size_t)k * 65536 + b * 256 + a_] = f2bf(acc[mt][nt][r]);
            }
}

// ---------------- gemm2 MFMA (NT): out[k][i][b] = sum_a Hx[i][a] * tmpT[k][b][a] ----------
__global__ __launch_bounds__(256, 2)
void gemm2_mfma(const unsigned short* __restrict__ HxB, // [128][256] bf16
                const unsigned short* __restrict__ tmpT,// [k][b][a] bf16
                unsigned short* __restrict__ outB)      // [k][i][b] bf16
{
    const int tid = threadIdx.x;
    const int w = tid >> 6, l = tid & 63;
    const int lr = l & 15, lg = l >> 4;
    const int k   = blockIdx.x >> 1;
    const int nb0 = (blockIdx.x & 1) * 128;
    const int ib  = (w & 1) * 64;
    const int bb  = (w >> 1) * 64;
    const unsigned short* Bp = tmpT + (size_t)k * 65536;

    f32x4 acc[4][4];
    #pragma unroll
    for (int mt = 0; mt < 4; ++mt)
        #pragma unroll
        for (int nt = 0; nt < 4; ++nt) acc[mt][nt] = (f32x4){0.f, 0.f, 0.f, 0.f};

    #pragma unroll 1
    for (int ks = 0; ks < 8; ++ks) {
        bf16x8 af[4], bf[4];
        #pragma unroll
        for (int mt = 0; mt < 4; ++mt)
            af[mt] = *(const bf16x8*)(HxB + (ib + mt * 16 + lr) * H2 + ks * 32 + lg * 8);
        #pragma unroll
        for (int nt = 0; nt < 4; ++nt)
            bf[nt] = *(const bf16x8*)(Bp + (nb0 + bb + nt * 16 + lr) * H2 + ks * 32 + lg * 8);
        #pragma unroll
        for (int mt = 0; mt < 4; ++mt)
            #pragma unroll
            for (int nt = 0; nt < 4; ++nt)
                acc[mt][nt] = __builtin_amdgcn_mfma_f32_16x16x32_bf16(af[mt], bf[nt], acc[mt][nt], 0, 0, 0);
    }
    #pragma unroll
    for (int mt = 0; mt < 4; ++mt)
        #pragma unroll
        for (int nt = 0; nt < 4; ++nt)
            #pragma unroll
            for (int r = 0; r < 4; ++r) {
                int i = ib + mt * 16 + lg * 4 + r;
                int bc = nb0 + bb + nt * 16 + lr;
                outB[(size_t)k * (NENT * H2) + i * H2 + bc] = f2bf(acc[mt][nt][r]);
            }
}

// ---------------- step3 MFMA: per (k,m): W = tep_k @ Tcls_m ; P = hep_k @ W^T ----------------
__global__ __launch_bounds__(512)
void step3_mfma(const unsigned short* __restrict__ hepB,  // [k][i][c]
                const unsigned short* __restrict__ tepB,  // [k][j][b]
                const unsigned short* __restrict__ TclsB, // [m][c][b]
                float* __restrict__ predT)                // [k*5+m][i][j]
{
    __shared__ unsigned short W[128 * 256];   // [j][c] bf16, byte ^= (j&7)<<4
    const int bid = blockIdx.x;
    const int k = bid / 5, m = bid % 5;
    const int tid = threadIdx.x;
    const int w  = tid >> 6;
    const int l  = tid & 63;
    const int lr = l & 15;
    const int lg = l >> 4;

    {
        const int jb = (w & 3) * 32;
        const int cb = (w >> 2) * 128;
        f32x4 acc[2][8];
        #pragma unroll
        for (int a = 0; a < 2; ++a)
            #pragma unroll
            for (int b = 0; b < 8; ++b) acc[a][b] = (f32x4){0.f, 0.f, 0.f, 0.f};

        const unsigned short* tk = tepB  + (size_t)k * (NENT * H2);
        const unsigned short* tc = TclsB + (size_t)m * (H2 * H2);
        for (int ks = 0; ks < 8; ++ks) {
            bf16x8 a0 = *(const bf16x8*)(tk + (jb +      lr) * H2 + ks * 32 + lg * 8);
            bf16x8 a1 = *(const bf16x8*)(tk + (jb + 16 + lr) * H2 + ks * 32 + lg * 8);
            #pragma unroll
            for (int ct = 0; ct < 8; ++ct) {
                bf16x8 bb = *(const bf16x8*)(tc + (cb + ct * 16 + lr) * H2 + ks * 32 + lg * 8);
                acc[0][ct] = __builtin_amdgcn_mfma_f32_16x16x32_bf16(a0, bb, acc[0][ct], 0, 0, 0);
                acc[1][ct] = __builtin_amdgcn_mfma_f32_16x16x32_bf16(a1, bb, acc[1][ct], 0, 0, 0);
            }
        }
        #pragma unroll
        for (int jt = 0; jt < 2; ++jt)
            #pragma unroll
            for (int ct = 0; ct < 8; ++ct)
                #pragma unroll
                for (int r = 0; r < 4; ++r) {
                    int j = jb + jt * 16 + lg * 4 + r;
                    int c = cb + ct * 16 + lr;
                    int byteoff = (((j << 8) + c) << 1) ^ ((j & 7) << 4);
                    *(unsigned short*)((char*)W + byteoff) = f2bf(acc[jt][ct][r]);
                }
    }
    __syncthreads();

    {
        const int ib = (w & 3) * 32;
        const int jb = (w >> 2) * 64;
        f32x4 acc[2][4];
        #pragma unroll
        for (int a = 0; a < 2; ++a)
            #pragma unroll
            for (int b = 0; b < 4; ++b) acc[a][b] = (f32x4){0.f, 0.f, 0.f, 0.f};

        const unsigned short* hk = hepB + (size_t)k * (NENT * H2);
        for (int ks = 0; ks < 8; ++ks) {
            bf16x8 a0 = *(const bf16x8*)(hk + (ib +      lr) * H2 + ks * 32 + lg * 8);
            bf16x8 a1 = *(const bf16x8*)(hk + (ib + 16 + lr) * H2 + ks * 32 + lg * 8);
            #pragma unroll
            for (int jt = 0; jt < 4; ++jt) {
                int j = jb + jt * 16 + lr;
                int byteoff = ((((j << 8) + ks * 32 + lg * 8)) << 1) ^ ((j & 7) << 4);
                bf16x8 bb = *(const bf16x8*)((const char*)W + byteoff);
                acc[0][jt] = __builtin_amdgcn_mfma_f32_16x16x32_bf16(a0, bb, acc[0][jt], 0, 0, 0);
                acc[1][jt] = __builtin_amdgcn_mfma_f32_16x16x32_bf16(a1, bb, acc[1][jt], 0, 0, 0);
            }
        }
        float* po = predT + (size_t)bid * (NENT * NENT);
        #pragma unroll
        for (int it = 0; it < 2; ++it)
            #pragma unroll
            for (int jt = 0; jt < 4; ++jt)
                #pragma unroll
                for (int r = 0; r < 4; ++r) {
                    int i = ib + it * 16 + lg * 4 + r;
                    int j = jb + jt * 16 + lr;
                    po[i * NENT + j] = acc[it][jt][r];
                }
    }
}

// ---------------- transpose: predT[km][ij] -> out[ij][km] ----------------
__global__ __launch_bounds__(256)
void transpose_out(const float* __restrict__ predT, float* __restrict__ out)
{
    __shared__ float Ls[160][33];
    const int bid = blockIdx.x;
    const int ij0 = (bid >> 2) * 32;
    const int km0 = (bid & 3) * 160;
    const int t = threadIdx.x;

    #pragma unroll
    for (int q = 0; q < 20; ++q) {
        int r = (t >> 5) + q * 8;
        int c = t & 31;
        Ls[r][c] = predT[(size_t)(km0 + r) * 16384 + ij0 + c];
    }
    __syncthreads();
    for (int idx = t; idx < 32 * 160; idx += 256) {
        int r = idx / 160, c = idx % 160;
        out[(size_t)(ij0 + r) * 640 + km0 + c] = Ls[c][r];
    }
}

extern "C" void kernel_launch(void* const* d_in, const int* in_sizes, int n_in,
                              void* d_out, int out_size, void* d_ws, size_t ws_size,
                              hipStream_t stream)
{
    (void)in_sizes; (void)n_in; (void)out_size; (void)ws_size;
    const float* enc  = (const float*)d_in[0];
    const int*   hidx = (const int*)d_in[1];
    const int*   tidx = (const int*)d_in[2];
    const int*   eidx = (const int*)d_in[3];
    const float* Whf = (const float*)d_in[4];
    const float* bhf = (const float*)d_in[5];
    const float* Whb = (const float*)d_in[6];
    const float* bhb = (const float*)d_in[7];
    const float* Wtf = (const float*)d_in[8];
    const float* btf = (const float*)d_in[9];
    const float* Wtb = (const float*)d_in[10];
    const float* btb = (const float*)d_in[11];
    const float* Wef = (const float*)d_in[12];
    const float* bef = (const float*)d_in[13];
    const float* Web = (const float*)d_in[14];
    const float* beb = (const float*)d_in[15];
    const float* T_he  = (const float*)d_in[16];
    const float* T_te  = (const float*)d_in[17];
    const float* T_cls = (const float*)d_in[18];

    float* out = (float*)d_out;
    char*  ws  = (char*)d_ws;
    unsigned short* poolB = (unsigned short*)(ws + POOLB_OFF);
    unsigned short* hepB  = (unsigned short*)(ws + HEPB_OFF);
    unsigned short* tepB  = (unsigned short*)(ws + TEPB_OFF);
    unsigned short* TclsB = (unsigned short*)(ws + TCLSB_OFF);
    unsigned short* WB    = (unsigned short*)(ws + WB_OFF);
    unsigned short* tokB  = (unsigned short*)(ws + TOKB_OFF);
    float*          gates = (float*)(ws + GATES_OFF);
    unsigned short* tmpT  = (unsigned short*)(ws + TMPT_OFF);
    float*          predT = (float*)(ws + PREDT_OFF);

    unsigned short* HeB = poolB;
    unsigned short* TeB = poolB + 1 * NENT * H2;
    unsigned short* EeB = poolB + 2 * NENT * H2;

    wconv<<<1728, 256, 0, stream>>>(Whf, Whb, Wtf, Wtb, Wef, Web, WB);
    conv_tcls<<<1280, 256, 0, stream>>>(T_cls, TclsB);
    gather_toks<<<4608, 256, 0, stream>>>(enc, hidx, tidx, eidx, tokB);

    gates_mfma<<<576, 256, 0, stream>>>(tokB, WB, gates);

    pool_epilogue<<<384, 256, 0, stream>>>(gates, bhf, bhb, btf, btb, bef, beb, poolB);

    gemm1_mfma<<<256, 512, 0, stream>>>(EeB, T_he, tmpT);
    gemm2_mfma<<<256, 256, 0, stream>>>(HeB, tmpT, hepB);

    gemm1_mfma<<<256, 512, 0, stream>>>(EeB, T_te, tmpT);
    gemm2_mfma<<<256, 256, 0, stream>>>(TeB, tmpT, tepB);

    step3_mfma<<<640, 512, 0, stream>>>(hepB, tepB, TclsB, predT);

    transpose_out<<<2048, 256, 0, stream>>>(predT, out);
}

// Round 5
// 241.130 us; speedup vs baseline: 4.9899x; 1.0191x over previous
//
#include <hip/hip_runtime.h>
#include <hip/hip_bf16.h>
#include <math.h>

#define DIM   768
#define HID   128
#define H2    256
#define NENT  128
#define SPAN  16
#define NCLS  5

// ---- ws layout (bytes) ----
// poolB bf16 [3][128][256]              @ 0          (196,608)
// hepB  bf16 [k][i][c]                  @ 196608     (8,388,608)
// tepB  bf16 [k][j][b]                  @ 8585216    (8,388,608)
// TclsB bf16 [m][c][b]                  @ 16973824   (655,360)
// WB    bf16 [3][768][768]              @ 17629184   (3,538,944)
// tokB  bf16 [3][2048][768]             @ 21168128   (9,437,184)   dead after gates
// gates fp32 [3][2048][768]             @ 30605312   (18,874,368)  dead after epilogue
// tmpT  bf16 [k][b][a]                  @ 21168128   (16,777,216)  dead before step3
// predT fp32 [k*5+m][i][j]              @ 21168128   (41,943,040)  overlaps tmpT/tokB/gates
#define POOLB_OFF 0
#define HEPB_OFF  196608
#define TEPB_OFF  (HEPB_OFF + 8388608)
#define TCLSB_OFF (TEPB_OFF + 8388608)
#define WB_OFF    (TCLSB_OFF + 655360)
#define TMPT_OFF  (WB_OFF + 3538944)
#define TOKB_OFF  TMPT_OFF
#define GATES_OFF (TOKB_OFF + 9437184)
#define PREDT_OFF TMPT_OFF

typedef __attribute__((ext_vector_type(8))) short bf16x8;
typedef __attribute__((ext_vector_type(4))) float f32x4;

__device__ __forceinline__ float sigmoidf_(float x) { return 1.0f / (1.0f + __expf(-x)); }

__device__ __forceinline__ unsigned short f2bf(float x) {
    __hip_bfloat16 h = __float2bfloat16(x);
    return *reinterpret_cast<unsigned short*>(&h);
}

// ---------------- weight convert ----------------
__global__ __launch_bounds__(256)
void wconv(const float* __restrict__ Whf, const float* __restrict__ Whb,
           const float* __restrict__ Wtf, const float* __restrict__ Wtb,
           const float* __restrict__ Wef, const float* __restrict__ Web,
           unsigned short* __restrict__ WB)
{
    int gid = blockIdx.x * 256 + threadIdx.x;        // < 442368
    int t2  = gid / 73728;
    int rem = gid % 73728;
    int n   = rem / 192;
    int c4  = rem % 192;
    int gate = n >> 7, j = n & 127;
    int srow = (gate == 0) ? j : (gate == 1) ? 256 + j : 384 + j;
    const float* W = (t2 == 0) ? Whf : (t2 == 1) ? Whb : (t2 == 2) ? Wtf :
                     (t2 == 3) ? Wtb : (t2 == 4) ? Wef : Web;
    float4 v = ((const float4*)(W + srow * DIM))[c4];
    unsigned short* d = WB + ((size_t)(t2 * 384 + n)) * DIM + c4 * 4;
    d[0] = f2bf(v.x); d[1] = f2bf(v.y); d[2] = f2bf(v.z); d[3] = f2bf(v.w);
}

// ---------------- convert T_cls[b][m][c] -> bf16 TclsB[m][c][b] ----------------
__global__ __launch_bounds__(256)
void conv_tcls(const float* __restrict__ T, unsigned short* __restrict__ TB)
{
    int idx = blockIdx.x * 256 + threadIdx.x;        // 327680 total
    int b = idx / (NCLS * H2);
    int r = idx % (NCLS * H2);
    int m = r >> 8, c = r & 255;
    TB[((m << 8) + c) * H2 + b] = f2bf(T[idx]);
}

// ---------------- gather tokens ----------------
__global__ __launch_bounds__(256)
void gather_toks(const float* __restrict__ enc,
                 const int* __restrict__ idx_h, const int* __restrict__ idx_t, const int* __restrict__ idx_e,
                 unsigned short* __restrict__ tokB)
{
    int gid = blockIdx.x * 256 + threadIdx.x;        // < 6144*192
    int r  = gid / 192, c4 = gid % 192;
    int type = r >> 11;
    int rem  = r & 2047;
    const int* idx = (type == 0) ? idx_h : (type == 1) ? idx_t : idx_e;
    int row = idx[rem];
    float4 v = ((const float4*)(enc + (size_t)row * DIM))[c4];
    unsigned short h4[4] = { f2bf(v.x), f2bf(v.y), f2bf(v.z), f2bf(v.w) };
    *(uint2*)(tokB + (size_t)r * DIM + c4 * 4) = *(uint2*)h4;
}

// ---------------- gates GEMM (NT) ----------------
__global__ __launch_bounds__(256, 2)
void gates_mfma(const unsigned short* __restrict__ tokB,
                const unsigned short* __restrict__ WB,
                float* __restrict__ gates)
{
    const int tid = threadIdx.x;
    const int w = tid >> 6, l = tid & 63;
    const int lr = l & 15, lg = l >> 4;
    const int bid = blockIdx.x;
    const int type = bid / 192;
    const int rem  = bid % 192;
    const int mb = (rem / 12) * 128 + (w & 1) * 64;
    const int cb = (rem % 12) * 64  + (w >> 1) * 32;
    const unsigned short* A = tokB + (size_t)type * 2048 * DIM;
    const unsigned short* B = WB   + (size_t)type * 768 * DIM;

    f32x4 acc[4][2];
    #pragma unroll
    for (int mt = 0; mt < 4; ++mt)
        #pragma unroll
        for (int nt = 0; nt < 2; ++nt) acc[mt][nt] = (f32x4){0.f, 0.f, 0.f, 0.f};

    #pragma unroll 1
    for (int ks = 0; ks < 24; ++ks) {
        bf16x8 af[4], bf[2];
        #pragma unroll
        for (int mt = 0; mt < 4; ++mt)
            af[mt] = *(const bf16x8*)(A + (size_t)(mb + mt * 16 + lr) * DIM + ks * 32 + lg * 8);
        #pragma unroll
        for (int nt = 0; nt < 2; ++nt)
            bf[nt] = *(const bf16x8*)(B + (size_t)(cb + nt * 16 + lr) * DIM + ks * 32 + lg * 8);
        #pragma unroll
        for (int mt = 0; mt < 4; ++mt)
            #pragma unroll
            for (int nt = 0; nt < 2; ++nt)
                acc[mt][nt] = __builtin_amdgcn_mfma_f32_16x16x32_bf16(af[mt], bf[nt], acc[mt][nt], 0, 0, 0);
    }
    float* C = gates + (size_t)type * 2048 * 768;
    #pragma unroll
    for (int mt = 0; mt < 4; ++mt)
        #pragma unroll
        for (int nt = 0; nt < 2; ++nt)
            #pragma unroll
            for (int r = 0; r < 4; ++r)
                C[(size_t)(mb + mt * 16 + lg * 4 + r) * 768 + cb + nt * 16 + lr] = acc[mt][nt][r];
}

// ---------------- pool epilogue ----------------
__global__ __launch_bounds__(256)
void pool_epilogue(const float* __restrict__ gates,
                   const float* __restrict__ bhf, const float* __restrict__ bhb,
                   const float* __restrict__ btf, const float* __restrict__ btb,
                   const float* __restrict__ bef, const float* __restrict__ beb,
                   unsigned short* __restrict__ poolB)
{
    const int type = blockIdx.x >> 7;
    const int ent  = blockIdx.x & 127;
    const int tid  = threadIdx.x;
    const int dir  = tid >> 7;
    const int j    = tid & 127;
    const float* Bv = (type == 0) ? (dir ? bhb : bhf)
                    : (type == 1) ? (dir ? btb : btf)
                                  : (dir ? beb : bef);
    const float bi = Bv[j], bg = Bv[2 * HID + j], bo = Bv[3 * HID + j];
    const float* g0 = gates + ((size_t)type * 2048 + ent * 16) * 768 + dir * 384 + j;
    float hmax = -1e30f;
    #pragma unroll
    for (int l = 0; l < SPAN; ++l) {
        const float* gr = g0 + l * 768;
        float iv = sigmoidf_(gr[0]   + bi);
        float gv = tanhf(   gr[128] + bg);
        float ov = sigmoidf_(gr[256] + bo);
        hmax = fmaxf(hmax, ov * tanhf(iv * gv));
    }
    poolB[(size_t)(type * NENT + ent) * H2 + dir * HID + j] = f2bf(hmax);
}

// ---------------- gemm1 MFMA: tmpT[k][b][a] = sum_c Ee[k][c] * T[a][b][c] ----------------
__global__ __launch_bounds__(512, 2)
void gemm1_mfma(const unsigned short* __restrict__ EeB,
                const float* __restrict__ T,
                unsigned short* __restrict__ tmpT)
{
    const int tid = threadIdx.x;
    const int w = tid >> 6, l = tid & 63;
    const int lr = l & 15, lg = l >> 4;
    const int b   = blockIdx.x;
    const int mb  = (w & 1) * 64;
    const int nbw = (w >> 1) * 64;

    f32x4 acc[4][4];
    #pragma unroll
    for (int mt = 0; mt < 4; ++mt)
        #pragma unroll
        for (int nt = 0; nt < 4; ++nt) acc[mt][nt] = (f32x4){0.f, 0.f, 0.f, 0.f};

    #pragma unroll 1
    for (int ks = 0; ks < 8; ++ks) {
        bf16x8 af[4];
        #pragma unroll
        for (int mt = 0; mt < 4; ++mt)
            af[mt] = *(const bf16x8*)(EeB + (mb + mt * 16 + lr) * H2 + ks * 32 + lg * 8);
        #pragma unroll
        for (int nt = 0; nt < 4; ++nt) {
            int a_ = nbw + nt * 16 + lr;
            const float* tr = T + ((size_t)a_ * 256 + b) * 256 + ks * 32 + lg * 8;
            float4 v0 = ((const float4*)tr)[0];
            float4 v1 = ((const float4*)tr)[1];
            bf16x8 bf;
            unsigned short* bp = (unsigned short*)&bf;
            bp[0] = f2bf(v0.x); bp[1] = f2bf(v0.y); bp[2] = f2bf(v0.z); bp[3] = f2bf(v0.w);
            bp[4] = f2bf(v1.x); bp[5] = f2bf(v1.y); bp[6] = f2bf(v1.z); bp[7] = f2bf(v1.w);
            #pragma unroll
            for (int mt = 0; mt < 4; ++mt)
                acc[mt][nt] = __builtin_amdgcn_mfma_f32_16x16x32_bf16(af[mt], bf, acc[mt][nt], 0, 0, 0);
        }
    }
    #pragma unroll
    for (int mt = 0; mt < 4; ++mt)
        #pragma unroll
        for (int nt = 0; nt < 4; ++nt)
            #pragma unroll
            for (int r = 0; r < 4; ++r) {
                int k  = mb + mt * 16 + lg * 4 + r;
                int a_ = nbw + nt * 16 + lr;
                tmpT[(size_t)k * 65536 + b * 256 + a_] = f2bf(acc[mt][nt][r]);
            }
}

// ---------------- gemm2 MFMA (NT) ----------------
__global__ __launch_bounds__(256, 2)
void gemm2_mfma(const unsigned short* __restrict__ HxB,
                const unsigned short* __restrict__ tmpT,
                unsigned short* __restrict__ outB)
{
    const int tid = threadIdx.x;
    const int w = tid >> 6, l = tid & 63;
    const int lr = l & 15, lg = l >> 4;
    const int k   = blockIdx.x >> 1;
    const int nb0 = (blockIdx.x & 1) * 128;
    const int ib  = (w & 1) * 64;
    const int bb  = (w >> 1) * 64;
    const unsigned short* Bp = tmpT + (size_t)k * 65536;

    f32x4 acc[4][4];
    #pragma unroll
    for (int mt = 0; mt < 4; ++mt)
        #pragma unroll
        for (int nt = 0; nt < 4; ++nt) acc[mt][nt] = (f32x4){0.f, 0.f, 0.f, 0.f};

    #pragma unroll 1
    for (int ks = 0; ks < 8; ++ks) {
        bf16x8 af[4], bf[4];
        #pragma unroll
        for (int mt = 0; mt < 4; ++mt)
            af[mt] = *(const bf16x8*)(HxB + (ib + mt * 16 + lr) * H2 + ks * 32 + lg * 8);
        #pragma unroll
        for (int nt = 0; nt < 4; ++nt)
            bf[nt] = *(const bf16x8*)(Bp + (nb0 + bb + nt * 16 + lr) * H2 + ks * 32 + lg * 8);
        #pragma unroll
        for (int mt = 0; mt < 4; ++mt)
            #pragma unroll
            for (int nt = 0; nt < 4; ++nt)
                acc[mt][nt] = __builtin_amdgcn_mfma_f32_16x16x32_bf16(af[mt], bf[nt], acc[mt][nt], 0, 0, 0);
    }
    #pragma unroll
    for (int mt = 0; mt < 4; ++mt)
        #pragma unroll
        for (int nt = 0; nt < 4; ++nt)
            #pragma unroll
            for (int r = 0; r < 4; ++r) {
                int i = ib + mt * 16 + lg * 4 + r;
                int bc = nb0 + bb + nt * 16 + lr;
                outB[(size_t)k * (NENT * H2) + i * H2 + bc] = f2bf(acc[mt][nt][r]);
            }
}

// ---------------- step3 MFMA: per (k,m): W = tep_k @ Tcls_m ; P = hep_k @ W^T ----------------
// XCD swizzle: 640 = 8 xcd * 80; all 5 m's of a k (and 16 consecutive k's) on one XCD
__global__ __launch_bounds__(512, 4)
void step3_mfma(const unsigned short* __restrict__ hepB,
                const unsigned short* __restrict__ tepB,
                const unsigned short* __restrict__ TclsB,
                float* __restrict__ predT)
{
    __shared__ unsigned short W[128 * 256];   // [j][c] bf16, byte ^= (j&7)<<4
    const int lbid = (blockIdx.x & 7) * 80 + (blockIdx.x >> 3);
    const int k = lbid / 5, m = lbid % 5;
    const int tid = threadIdx.x;
    const int w  = tid >> 6;
    const int l  = tid & 63;
    const int lr = l & 15;
    const int lg = l >> 4;

    {
        const int jb = (w & 3) * 32;
        const int cb = (w >> 2) * 128;
        f32x4 acc[2][8];
        #pragma unroll
        for (int a = 0; a < 2; ++a)
            #pragma unroll
            for (int b = 0; b < 8; ++b) acc[a][b] = (f32x4){0.f, 0.f, 0.f, 0.f};

        const unsigned short* tk = tepB  + (size_t)k * (NENT * H2);
        const unsigned short* tc = TclsB + (size_t)m * (H2 * H2);
        #pragma unroll
        for (int ks = 0; ks < 8; ++ks) {
            bf16x8 a0 = *(const bf16x8*)(tk + (jb +      lr) * H2 + ks * 32 + lg * 8);
            bf16x8 a1 = *(const bf16x8*)(tk + (jb + 16 + lr) * H2 + ks * 32 + lg * 8);
            #pragma unroll
            for (int ct = 0; ct < 8; ++ct) {
                bf16x8 bb = *(const bf16x8*)(tc + (cb + ct * 16 + lr) * H2 + ks * 32 + lg * 8);
                acc[0][ct] = __builtin_amdgcn_mfma_f32_16x16x32_bf16(a0, bb, acc[0][ct], 0, 0, 0);
                acc[1][ct] = __builtin_amdgcn_mfma_f32_16x16x32_bf16(a1, bb, acc[1][ct], 0, 0, 0);
            }
        }
        #pragma unroll
        for (int jt = 0; jt < 2; ++jt)
            #pragma unroll
            for (int ct = 0; ct < 8; ++ct)
                #pragma unroll
                for (int r = 0; r < 4; ++r) {
                    int j = jb + jt * 16 + lg * 4 + r;
                    int c = cb + ct * 16 + lr;
                    int byteoff = (((j << 8) + c) << 1) ^ ((j & 7) << 4);
                    *(unsigned short*)((char*)W + byteoff) = f2bf(acc[jt][ct][r]);
                }
    }
    __syncthreads();

    {
        const int ib = (w & 3) * 32;
        const int jb = (w >> 2) * 64;
        f32x4 acc[2][4];
        #pragma unroll
        for (int a = 0; a < 2; ++a)
            #pragma unroll
            for (int b = 0; b < 4; ++b) acc[a][b] = (f32x4){0.f, 0.f, 0.f, 0.f};

        const unsigned short* hk = hepB + (size_t)k * (NENT * H2);
        #pragma unroll
        for (int ks = 0; ks < 8; ++ks) {
            bf16x8 a0 = *(const bf16x8*)(hk + (ib +      lr) * H2 + ks * 32 + lg * 8);
            bf16x8 a1 = *(const bf16x8*)(hk + (ib + 16 + lr) * H2 + ks * 32 + lg * 8);
            #pragma unroll
            for (int jt = 0; jt < 4; ++jt) {
                int j = jb + jt * 16 + lr;
                int byteoff = ((((j << 8) + ks * 32 + lg * 8)) << 1) ^ ((j & 7) << 4);
                bf16x8 bb = *(const bf16x8*)((const char*)W + byteoff);
                acc[0][jt] = __builtin_amdgcn_mfma_f32_16x16x32_bf16(a0, bb, acc[0][jt], 0, 0, 0);
                acc[1][jt] = __builtin_amdgcn_mfma_f32_16x16x32_bf16(a1, bb, acc[1][jt], 0, 0, 0);
            }
        }
        float* po = predT + (size_t)lbid * (NENT * NENT);
        #pragma unroll
        for (int it = 0; it < 2; ++it)
            #pragma unroll
            for (int jt = 0; jt < 4; ++jt)
                #pragma unroll
                for (int r = 0; r < 4; ++r) {
                    int i = ib + it * 16 + lg * 4 + r;
                    int j = jb + jt * 16 + lr;
                    po[i * NENT + j] = acc[it][jt][r];
                }
    }
}

// ---------------- transpose: predT[km][ij] -> out[ij][km] ----------------
__global__ __launch_bounds__(256)
void transpose_out(const float* __restrict__ predT, float* __restrict__ out)
{
    __shared__ float Ls[160][33];
    const int bid = blockIdx.x;
    const int ij0 = (bid >> 2) * 32;
    const int km0 = (bid & 3) * 160;
    const int t = threadIdx.x;

    #pragma unroll
    for (int q = 0; q < 20; ++q) {
        int r = (t >> 5) + q * 8;
        int c = t & 31;
        Ls[r][c] = predT[(size_t)(km0 + r) * 16384 + ij0 + c];
    }
    __syncthreads();
    for (int idx = t; idx < 32 * 160; idx += 256) {
        int r = idx / 160, c = idx % 160;
        out[(size_t)(ij0 + r) * 640 + km0 + c] = Ls[c][r];
    }
}

extern "C" void kernel_launch(void* const* d_in, const int* in_sizes, int n_in,
                              void* d_out, int out_size, void* d_ws, size_t ws_size,
                              hipStream_t stream)
{
    (void)in_sizes; (void)n_in; (void)out_size; (void)ws_size;
    const float* enc  = (const float*)d_in[0];
    const int*   hidx = (const int*)d_in[1];
    const int*   tidx = (const int*)d_in[2];
    const int*   eidx = (const int*)d_in[3];
    const float* Whf = (const float*)d_in[4];
    const float* bhf = (const float*)d_in[5];
    const float* Whb = (const float*)d_in[6];
    const float* bhb = (const float*)d_in[7];
    const float* Wtf = (const float*)d_in[8];
    const float* btf = (const float*)d_in[9];
    const float* Wtb = (const float*)d_in[10];
    const float* btb = (const float*)d_in[11];
    const float* Wef = (const float*)d_in[12];
    const float* bef = (const float*)d_in[13];
    const float* Web = (const float*)d_in[14];
    const float* beb = (const float*)d_in[15];
    const float* T_he  = (const float*)d_in[16];
    const float* T_te  = (const float*)d_in[17];
    const float* T_cls = (const float*)d_in[18];

    float* out = (float*)d_out;
    char*  ws  = (char*)d_ws;
    unsigned short* poolB = (unsigned short*)(ws + POOLB_OFF);
    unsigned short* hepB  = (unsigned short*)(ws + HEPB_OFF);
    unsigned short* tepB  = (unsigned short*)(ws + TEPB_OFF);
    unsigned short* TclsB = (unsigned short*)(ws + TCLSB_OFF);
    unsigned short* WB    = (unsigned short*)(ws + WB_OFF);
    unsigned short* tokB  = (unsigned short*)(ws + TOKB_OFF);
    float*          gates = (float*)(ws + GATES_OFF);
    unsigned short* tmpT  = (unsigned short*)(ws + TMPT_OFF);
    float*          predT = (float*)(ws + PREDT_OFF);

    unsigned short* HeB = poolB;
    unsigned short* TeB = poolB + 1 * NENT * H2;
    unsigned short* EeB = poolB + 2 * NENT * H2;

    wconv<<<1728, 256, 0, stream>>>(Whf, Whb, Wtf, Wtb, Wef, Web, WB);
    conv_tcls<<<1280, 256, 0, stream>>>(T_cls, TclsB);
    gather_toks<<<4608, 256, 0, stream>>>(enc, hidx, tidx, eidx, tokB);

    gates_mfma<<<576, 256, 0, stream>>>(tokB, WB, gates);

    pool_epilogue<<<384, 256, 0, stream>>>(gates, bhf, bhb, btf, btb, bef, beb, poolB);

    gemm1_mfma<<<256, 512, 0, stream>>>(EeB, T_he, tmpT);
    gemm2_mfma<<<256, 256, 0, stream>>>(HeB, tmpT, hepB);

    gemm1_mfma<<<256, 512, 0, stream>>>(EeB, T_te, tmpT);
    gemm2_mfma<<<256, 256, 0, stream>>>(TeB, tmpT, tepB);

    step3_mfma<<<640, 512, 0, stream>>>(hepB, tepB, TclsB, predT);

    transpose_out<<<2048, 256, 0, stream>>>(predT, out);
}

// Round 6
// 206.328 us; speedup vs baseline: 5.8316x; 1.1687x over previous
//
#include <hip/hip_runtime.h>
#include <hip/hip_bf16.h>
#include <math.h>

#define DIM   768
#define HID   128
#define H2    256
#define NENT  128
#define SPAN  16
#define NCLS  5

// ---- ws layout (bytes) ----
// poolB bf16 [3][128][256]              @ 0          (196,608)
// hepB  bf16 [k][i][c]                  @ 196608     (8,388,608)
// tepB  bf16 [k][j][b]                  @ 8585216    (8,388,608)
// TclsB bf16 [m][c][b]                  @ 16973824   (655,360)
// WB    bf16 [3][768][768]              @ 17629184   (3,538,944)
// tokB  bf16 [3][2048][768]             @ 21168128   (9,437,184)   dead after gates
// gates fp32 [3][2048][768]             @ 30605312   (18,874,368)  dead after epilogue
// tmpT  bf16 [k][b][a]                  @ 21168128   (16,777,216)  dead before step3
// predT fp32 [k*5+m][i][j]              @ 21168128   (41,943,040)  overlaps tmpT/tokB/gates
#define POOLB_OFF 0
#define HEPB_OFF  196608
#define TEPB_OFF  (HEPB_OFF + 8388608)
#define TCLSB_OFF (TEPB_OFF + 8388608)
#define WB_OFF    (TCLSB_OFF + 655360)
#define TMPT_OFF  (WB_OFF + 3538944)
#define TOKB_OFF  TMPT_OFF
#define GATES_OFF (TOKB_OFF + 9437184)
#define PREDT_OFF TMPT_OFF

typedef __attribute__((ext_vector_type(8))) short bf16x8;
typedef __attribute__((ext_vector_type(4))) float f32x4;

__device__ __forceinline__ float sigmoidf_(float x) { return 1.0f / (1.0f + __expf(-x)); }

__device__ __forceinline__ unsigned short f2bf(float x) {
    __hip_bfloat16 h = __float2bfloat16(x);
    return *reinterpret_cast<unsigned short*>(&h);
}

// ---------------- weight convert ----------------
__global__ __launch_bounds__(256)
void wconv(const float* __restrict__ Whf, const float* __restrict__ Whb,
           const float* __restrict__ Wtf, const float* __restrict__ Wtb,
           const float* __restrict__ Wef, const float* __restrict__ Web,
           unsigned short* __restrict__ WB)
{
    int gid = blockIdx.x * 256 + threadIdx.x;        // < 442368
    int t2  = gid / 73728;
    int rem = gid % 73728;
    int n   = rem / 192;
    int c4  = rem % 192;
    int gate = n >> 7, j = n & 127;
    int srow = (gate == 0) ? j : (gate == 1) ? 256 + j : 384 + j;
    const float* W = (t2 == 0) ? Whf : (t2 == 1) ? Whb : (t2 == 2) ? Wtf :
                     (t2 == 3) ? Wtb : (t2 == 4) ? Wef : Web;
    float4 v = ((const float4*)(W + srow * DIM))[c4];
    unsigned short* d = WB + ((size_t)(t2 * 384 + n)) * DIM + c4 * 4;
    d[0] = f2bf(v.x); d[1] = f2bf(v.y); d[2] = f2bf(v.z); d[3] = f2bf(v.w);
}

// ---------------- convert T_cls[b][m][c] -> bf16 TclsB[m][c][b] ----------------
__global__ __launch_bounds__(256)
void conv_tcls(const float* __restrict__ T, unsigned short* __restrict__ TB)
{
    int idx = blockIdx.x * 256 + threadIdx.x;        // 327680 total
    int b = idx / (NCLS * H2);
    int r = idx % (NCLS * H2);
    int m = r >> 8, c = r & 255;
    TB[((m << 8) + c) * H2 + b] = f2bf(T[idx]);
}

// ---------------- gather tokens ----------------
__global__ __launch_bounds__(256)
void gather_toks(const float* __restrict__ enc,
                 const int* __restrict__ idx_h, const int* __restrict__ idx_t, const int* __restrict__ idx_e,
                 unsigned short* __restrict__ tokB)
{
    int gid = blockIdx.x * 256 + threadIdx.x;        // < 6144*192
    int r  = gid / 192, c4 = gid % 192;
    int type = r >> 11;
    int rem  = r & 2047;
    const int* idx = (type == 0) ? idx_h : (type == 1) ? idx_t : idx_e;
    int row = idx[rem];
    float4 v = ((const float4*)(enc + (size_t)row * DIM))[c4];
    unsigned short h4[4] = { f2bf(v.x), f2bf(v.y), f2bf(v.z), f2bf(v.w) };
    *(uint2*)(tokB + (size_t)r * DIM + c4 * 4) = *(uint2*)h4;
}

// ---------------- gates GEMM (NT) ----------------
__global__ __launch_bounds__(256, 2)
void gates_mfma(const unsigned short* __restrict__ tokB,
                const unsigned short* __restrict__ WB,
                float* __restrict__ gates)
{
    const int tid = threadIdx.x;
    const int w = tid >> 6, l = tid & 63;
    const int lr = l & 15, lg = l >> 4;
    const int bid = blockIdx.x;
    const int type = bid / 192;
    const int rem  = bid % 192;
    const int mb = (rem / 12) * 128 + (w & 1) * 64;
    const int cb = (rem % 12) * 64  + (w >> 1) * 32;
    const unsigned short* A = tokB + (size_t)type * 2048 * DIM;
    const unsigned short* B = WB   + (size_t)type * 768 * DIM;

    f32x4 acc[4][2];
    #pragma unroll
    for (int mt = 0; mt < 4; ++mt)
        #pragma unroll
        for (int nt = 0; nt < 2; ++nt) acc[mt][nt] = (f32x4){0.f, 0.f, 0.f, 0.f};

    #pragma unroll 1
    for (int ks = 0; ks < 24; ++ks) {
        bf16x8 af[4], bf[2];
        #pragma unroll
        for (int mt = 0; mt < 4; ++mt)
            af[mt] = *(const bf16x8*)(A + (size_t)(mb + mt * 16 + lr) * DIM + ks * 32 + lg * 8);
        #pragma unroll
        for (int nt = 0; nt < 2; ++nt)
            bf[nt] = *(const bf16x8*)(B + (size_t)(cb + nt * 16 + lr) * DIM + ks * 32 + lg * 8);
        #pragma unroll
        for (int mt = 0; mt < 4; ++mt)
            #pragma unroll
            for (int nt = 0; nt < 2; ++nt)
                acc[mt][nt] = __builtin_amdgcn_mfma_f32_16x16x32_bf16(af[mt], bf[nt], acc[mt][nt], 0, 0, 0);
    }
    float* C = gates + (size_t)type * 2048 * 768;
    #pragma unroll
    for (int mt = 0; mt < 4; ++mt)
        #pragma unroll
        for (int nt = 0; nt < 2; ++nt)
            #pragma unroll
            for (int r = 0; r < 4; ++r)
                C[(size_t)(mb + mt * 16 + lg * 4 + r) * 768 + cb + nt * 16 + lr] = acc[mt][nt][r];
}

// ---------------- pool epilogue ----------------
__global__ __launch_bounds__(256)
void pool_epilogue(const float* __restrict__ gates,
                   const float* __restrict__ bhf, const float* __restrict__ bhb,
                   const float* __restrict__ btf, const float* __restrict__ btb,
                   const float* __restrict__ bef, const float* __restrict__ beb,
                   unsigned short* __restrict__ poolB)
{
    const int type = blockIdx.x >> 7;
    const int ent  = blockIdx.x & 127;
    const int tid  = threadIdx.x;
    const int dir  = tid >> 7;
    const int j    = tid & 127;
    const float* Bv = (type == 0) ? (dir ? bhb : bhf)
                    : (type == 1) ? (dir ? btb : btf)
                                  : (dir ? beb : bef);
    const float bi = Bv[j], bg = Bv[2 * HID + j], bo = Bv[3 * HID + j];
    const float* g0 = gates + ((size_t)type * 2048 + ent * 16) * 768 + dir * 384 + j;
    float hmax = -1e30f;
    #pragma unroll
    for (int l = 0; l < SPAN; ++l) {
        const float* gr = g0 + l * 768;
        float iv = sigmoidf_(gr[0]   + bi);
        float gv = tanhf(   gr[128] + bg);
        float ov = sigmoidf_(gr[256] + bo);
        hmax = fmaxf(hmax, ov * tanhf(iv * gv));
    }
    poolB[(size_t)(type * NENT + ent) * H2 + dir * HID + j] = f2bf(hmax);
}

// ---------------- gemm1 MFMA: tmpT[k][b][a] = sum_c Ee[k][c] * T[a][b][c] ----------------
__global__ __launch_bounds__(512, 2)
void gemm1_mfma(const unsigned short* __restrict__ EeB,
                const float* __restrict__ T,
                unsigned short* __restrict__ tmpT)
{
    const int tid = threadIdx.x;
    const int w = tid >> 6, l = tid & 63;
    const int lr = l & 15, lg = l >> 4;
    const int b   = blockIdx.x;
    const int mb  = (w & 1) * 64;
    const int nbw = (w >> 1) * 64;

    f32x4 acc[4][4];
    #pragma unroll
    for (int mt = 0; mt < 4; ++mt)
        #pragma unroll
        for (int nt = 0; nt < 4; ++nt) acc[mt][nt] = (f32x4){0.f, 0.f, 0.f, 0.f};

    #pragma unroll 1
    for (int ks = 0; ks < 8; ++ks) {
        bf16x8 af[4];
        #pragma unroll
        for (int mt = 0; mt < 4; ++mt)
            af[mt] = *(const bf16x8*)(EeB + (mb + mt * 16 + lr) * H2 + ks * 32 + lg * 8);
        #pragma unroll
        for (int nt = 0; nt < 4; ++nt) {
            int a_ = nbw + nt * 16 + lr;
            const float* tr = T + ((size_t)a_ * 256 + b) * 256 + ks * 32 + lg * 8;
            float4 v0 = ((const float4*)tr)[0];
            float4 v1 = ((const float4*)tr)[1];
            bf16x8 bf;
            unsigned short* bp = (unsigned short*)&bf;
            bp[0] = f2bf(v0.x); bp[1] = f2bf(v0.y); bp[2] = f2bf(v0.z); bp[3] = f2bf(v0.w);
            bp[4] = f2bf(v1.x); bp[5] = f2bf(v1.y); bp[6] = f2bf(v1.z); bp[7] = f2bf(v1.w);
            #pragma unroll
            for (int mt = 0; mt < 4; ++mt)
                acc[mt][nt] = __builtin_amdgcn_mfma_f32_16x16x32_bf16(af[mt], bf, acc[mt][nt], 0, 0, 0);
        }
    }
    #pragma unroll
    for (int mt = 0; mt < 4; ++mt)
        #pragma unroll
        for (int nt = 0; nt < 4; ++nt)
            #pragma unroll
            for (int r = 0; r < 4; ++r) {
                int k  = mb + mt * 16 + lg * 4 + r;
                int a_ = nbw + nt * 16 + lr;
                tmpT[(size_t)k * 65536 + b * 256 + a_] = f2bf(acc[mt][nt][r]);
            }
}

// ---------------- gemm2 MFMA (NT) ----------------
__global__ __launch_bounds__(256, 2)
void gemm2_mfma(const unsigned short* __restrict__ HxB,
                const unsigned short* __restrict__ tmpT,
                unsigned short* __restrict__ outB)
{
    const int tid = threadIdx.x;
    const int w = tid >> 6, l = tid & 63;
    const int lr = l & 15, lg = l >> 4;
    const int k   = blockIdx.x >> 1;
    const int nb0 = (blockIdx.x & 1) * 128;
    const int ib  = (w & 1) * 64;
    const int bb  = (w >> 1) * 64;
    const unsigned short* Bp = tmpT + (size_t)k * 65536;

    f32x4 acc[4][4];
    #pragma unroll
    for (int mt = 0; mt < 4; ++mt)
        #pragma unroll
        for (int nt = 0; nt < 4; ++nt) acc[mt][nt] = (f32x4){0.f, 0.f, 0.f, 0.f};

    #pragma unroll 1
    for (int ks = 0; ks < 8; ++ks) {
        bf16x8 af[4], bf[4];
        #pragma unroll
        for (int mt = 0; mt < 4; ++mt)
            af[mt] = *(const bf16x8*)(HxB + (ib + mt * 16 + lr) * H2 + ks * 32 + lg * 8);
        #pragma unroll
        for (int nt = 0; nt < 4; ++nt)
            bf[nt] = *(const bf16x8*)(Bp + (nb0 + bb + nt * 16 + lr) * H2 + ks * 32 + lg * 8);
        #pragma unroll
        for (int mt = 0; mt < 4; ++mt)
            #pragma unroll
            for (int nt = 0; nt < 4; ++nt)
                acc[mt][nt] = __builtin_amdgcn_mfma_f32_16x16x32_bf16(af[mt], bf[nt], acc[mt][nt], 0, 0, 0);
    }
    #pragma unroll
    for (int mt = 0; mt < 4; ++mt)
        #pragma unroll
        for (int nt = 0; nt < 4; ++nt)
            #pragma unroll
            for (int r = 0; r < 4; ++r) {
                int i = ib + mt * 16 + lg * 4 + r;
                int bc = nb0 + bb + nt * 16 + lr;
                outB[(size_t)k * (NENT * H2) + i * H2 + bc] = f2bf(acc[mt][nt][r]);
            }
}

// ---------------- step3: block per (k, j-half); m-loop inside ----------------
// grid 256 = k(128) x jh(2), XCD-swizzled; 512 thr = 8 waves
// LDS: tepS [64 j][256 b] swz (32 KB) + WS [64 j][256 c] swz (32 KB)
// per m: G1: W[j][c] = sum_b tep[j][b]*TclsB[m][c][b]  (wave: 64j x 32c slice)
//        G2: P[i][j] = sum_c hep[i][c]*W[j][c]          (wave: 16i x 64j, A in regs)
__global__ __launch_bounds__(512)
void step3_mfma(const unsigned short* __restrict__ hepB,
                const unsigned short* __restrict__ tepB,
                const unsigned short* __restrict__ TclsB,
                float* __restrict__ predT)
{
    __shared__ unsigned short tepS[64 * 256];
    __shared__ unsigned short WS[64 * 256];
    const int lbid = (blockIdx.x & 7) * 32 + (blockIdx.x >> 3);  // bijective, k's grouped per XCD
    const int k  = lbid >> 1;
    const int jh = lbid & 1;
    const int tid = threadIdx.x;
    const int w  = tid >> 6;
    const int l  = tid & 63;
    const int lr = l & 15;
    const int lg = l >> 4;
    const int swz = (lr & 7) << 4;           // XOR swizzle for rows read at fixed col

    // ---- stage tep half: rows jh*64.., swizzled ----
    {
        const unsigned short* tk = tepB + (size_t)k * (NENT * H2) + (size_t)jh * 64 * H2;
        int row = tid >> 5;                  // 0..15, then +16 per q
        int col = (tid & 31) * 8;            // 0..255 step 8
        #pragma unroll
        for (int q = 0; q < 4; ++q) {
            int r = row + q * 16;
            bf16x8 v = *(const bf16x8*)(tk + r * H2 + col);
            int byteoff = (((r << 8) + col) << 1) ^ ((r & 7) << 4);
            *(bf16x8*)((char*)tepS + byteoff) = v;
        }
    }

    // ---- preload hep A-fragments (wave w owns i-tile w*16, reused for all m) ----
    bf16x8 ha[8];
    {
        const unsigned short* hk = hepB + (size_t)k * (NENT * H2);
        #pragma unroll
        for (int ks = 0; ks < 8; ++ks)
            ha[ks] = *(const bf16x8*)(hk + (w * 16 + lr) * H2 + ks * 32 + lg * 8);
    }
    __syncthreads();

    #pragma unroll 1
    for (int m = 0; m < NCLS; ++m) {
        // ---- G1: wave computes W[all 64 j][c-slice w*32..+32] ----
        {
            const unsigned short* tcm = TclsB + (size_t)m * (H2 * H2);
            f32x4 acc1[4][2];
            #pragma unroll
            for (int jt = 0; jt < 4; ++jt)
                #pragma unroll
                for (int ct = 0; ct < 2; ++ct) acc1[jt][ct] = (f32x4){0.f, 0.f, 0.f, 0.f};

            #pragma unroll
            for (int ks = 0; ks < 8; ++ks) {
                bf16x8 a[4], bb[2];
                #pragma unroll
                for (int jt = 0; jt < 4; ++jt) {
                    int byteoff = ((((jt * 16 + lr) << 8) + ks * 32 + lg * 8) << 1) ^ swz;
                    a[jt] = *(const bf16x8*)((const char*)tepS + byteoff);
                }
                #pragma unroll
                for (int ct = 0; ct < 2; ++ct)
                    bb[ct] = *(const bf16x8*)(tcm + (size_t)(w * 32 + ct * 16 + lr) * H2 + ks * 32 + lg * 8);
                #pragma unroll
                for (int jt = 0; jt < 4; ++jt)
                    #pragma unroll
                    for (int ct = 0; ct < 2; ++ct)
                        acc1[jt][ct] = __builtin_amdgcn_mfma_f32_16x16x32_bf16(a[jt], bb[ct], acc1[jt][ct], 0, 0, 0);
            }
            // write W to LDS (swizzled): row j = jt*16+lg*4+r, col c = w*32+ct*16+lr
            #pragma unroll
            for (int jt = 0; jt < 4; ++jt)
                #pragma unroll
                for (int ct = 0; ct < 2; ++ct)
                    #pragma unroll
                    for (int r = 0; r < 4; ++r) {
                        int j = jt * 16 + lg * 4 + r;
                        int c = w * 32 + ct * 16 + lr;
                        int byteoff = ((((j << 8) + c)) << 1) ^ ((j & 7) << 4);
                        *(unsigned short*)((char*)WS + byteoff) = f2bf(acc1[jt][ct][r]);
                    }
        }
        __syncthreads();

        // ---- G2: wave computes P[i-tile w*16][all 64 j] ----
        {
            f32x4 acc2[4];
            #pragma unroll
            for (int jt = 0; jt < 4; ++jt) acc2[jt] = (f32x4){0.f, 0.f, 0.f, 0.f};

            #pragma unroll
            for (int ks = 0; ks < 8; ++ks) {
                #pragma unroll
                for (int jt = 0; jt < 4; ++jt) {
                    int byteoff = ((((jt * 16 + lr) << 8) + ks * 32 + lg * 8) << 1) ^ swz;
                    bf16x8 wb = *(const bf16x8*)((const char*)WS + byteoff);
                    acc2[jt] = __builtin_amdgcn_mfma_f32_16x16x32_bf16(ha[ks], wb, acc2[jt], 0, 0, 0);
                }
            }
            float* po = predT + (size_t)(k * NCLS + m) * (NENT * NENT);
            #pragma unroll
            for (int jt = 0; jt < 4; ++jt)
                #pragma unroll
                for (int r = 0; r < 4; ++r) {
                    int i = w * 16 + lg * 4 + r;
                    int j = jh * 64 + jt * 16 + lr;
                    po[i * NENT + j] = acc2[jt][r];
                }
        }
        __syncthreads();
    }
}

// ---------------- transpose: predT[km][ij] -> out[ij][km] ----------------
__global__ __launch_bounds__(256)
void transpose_out(const float* __restrict__ predT, float* __restrict__ out)
{
    __shared__ float Ls[160][33];
    const int bid = blockIdx.x;
    const int ij0 = (bid >> 2) * 32;
    const int km0 = (bid & 3) * 160;
    const int t = threadIdx.x;

    #pragma unroll
    for (int q = 0; q < 20; ++q) {
        int r = (t >> 5) + q * 8;
        int c = t & 31;
        Ls[r][c] = predT[(size_t)(km0 + r) * 16384 + ij0 + c];
    }
    __syncthreads();
    for (int idx = t; idx < 32 * 160; idx += 256) {
        int r = idx / 160, c = idx % 160;
        out[(size_t)(ij0 + r) * 640 + km0 + c] = Ls[c][r];
    }
}

extern "C" void kernel_launch(void* const* d_in, const int* in_sizes, int n_in,
                              void* d_out, int out_size, void* d_ws, size_t ws_size,
                              hipStream_t stream)
{
    (void)in_sizes; (void)n_in; (void)out_size; (void)ws_size;
    const float* enc  = (const float*)d_in[0];
    const int*   hidx = (const int*)d_in[1];
    const int*   tidx = (const int*)d_in[2];
    const int*   eidx = (const int*)d_in[3];
    const float* Whf = (const float*)d_in[4];
    const float* bhf = (const float*)d_in[5];
    const float* Whb = (const float*)d_in[6];
    const float* bhb = (const float*)d_in[7];
    const float* Wtf = (const float*)d_in[8];
    const float* btf = (const float*)d_in[9];
    const float* Wtb = (const float*)d_in[10];
    const float* btb = (const float*)d_in[11];
    const float* Wef = (const float*)d_in[12];
    const float* bef = (const float*)d_in[13];
    const float* Web = (const float*)d_in[14];
    const float* beb = (const float*)d_in[15];
    const float* T_he  = (const float*)d_in[16];
    const float* T_te  = (const float*)d_in[17];
    const float* T_cls = (const float*)d_in[18];

    float* out = (float*)d_out;
    char*  ws  = (char*)d_ws;
    unsigned short* poolB = (unsigned short*)(ws + POOLB_OFF);
    unsigned short* hepB  = (unsigned short*)(ws + HEPB_OFF);
    unsigned short* tepB  = (unsigned short*)(ws + TEPB_OFF);
    unsigned short* TclsB = (unsigned short*)(ws + TCLSB_OFF);
    unsigned short* WB    = (unsigned short*)(ws + WB_OFF);
    unsigned short* tokB  = (unsigned short*)(ws + TOKB_OFF);
    float*          gates = (float*)(ws + GATES_OFF);
    unsigned short* tmpT  = (unsigned short*)(ws + TMPT_OFF);
    float*          predT = (float*)(ws + PREDT_OFF);

    unsigned short* HeB = poolB;
    unsigned short* TeB = poolB + 1 * NENT * H2;
    unsigned short* EeB = poolB + 2 * NENT * H2;

    wconv<<<1728, 256, 0, stream>>>(Whf, Whb, Wtf, Wtb, Wef, Web, WB);
    conv_tcls<<<1280, 256, 0, stream>>>(T_cls, TclsB);
    gather_toks<<<4608, 256, 0, stream>>>(enc, hidx, tidx, eidx, tokB);

    gates_mfma<<<576, 256, 0, stream>>>(tokB, WB, gates);

    pool_epilogue<<<384, 256, 0, stream>>>(gates, bhf, bhb, btf, btb, bef, beb, poolB);

    gemm1_mfma<<<256, 512, 0, stream>>>(EeB, T_he, tmpT);
    gemm2_mfma<<<256, 256, 0, stream>>>(HeB, tmpT, hepB);

    gemm1_mfma<<<256, 512, 0, stream>>>(EeB, T_te, tmpT);
    gemm2_mfma<<<256, 256, 0, stream>>>(TeB, tmpT, tepB);

    step3_mfma<<<256, 512, 0, stream>>>(hepB, tepB, TclsB, predT);

    transpose_out<<<2048, 256, 0, stream>>>(predT, out);
}

// Round 7
// 171.882 us; speedup vs baseline: 7.0003x; 1.2004x over previous
//
#include <hip/hip_runtime.h>
#include <hip/hip_bf16.h>
#include <math.h>

#define DIM   768
#define HID   128
#define H2    256
#define NENT  128
#define SPAN  16
#define NCLS  5

// ---- ws layout (bytes) ----
// poolB bf16 [3][128][256]              @ 0          (196,608)
// hepB  bf16 [k][i][c]                  @ 196608     (8,388,608)
// tepB  bf16 [k][j][b]                  @ 8585216    (8,388,608)
// TclsB bf16 [m][c][b]                  @ 16973824   (655,360)
// WB    bf16 [3][768][768]              @ 17629184   (3,538,944)
// tokB  bf16 [3][2048][768]             @ 21168128   (9,437,184)   dead after gates
// gates fp32 [3][2048][768]             @ 30605312   (18,874,368)  dead after epilogue
// tmpT  bf16 [k][b][a]                  @ 21168128   (16,777,216)  dead before step3
// predT fp32 [k*5+m][i][j]              @ 21168128   (41,943,040)  overlaps tmpT/tokB/gates
#define POOLB_OFF 0
#define HEPB_OFF  196608
#define TEPB_OFF  (HEPB_OFF + 8388608)
#define TCLSB_OFF (TEPB_OFF + 8388608)
#define WB_OFF    (TCLSB_OFF + 655360)
#define TMPT_OFF  (WB_OFF + 3538944)
#define TOKB_OFF  TMPT_OFF
#define GATES_OFF (TOKB_OFF + 9437184)
#define PREDT_OFF TMPT_OFF

typedef __attribute__((ext_vector_type(8))) short bf16x8;
typedef __attribute__((ext_vector_type(4))) float f32x4;

__device__ __forceinline__ float sigmoidf_(float x) { return 1.0f / (1.0f + __expf(-x)); }

__device__ __forceinline__ unsigned short f2bf(float x) {
    __hip_bfloat16 h = __float2bfloat16(x);
    return *reinterpret_cast<unsigned short*>(&h);
}

// ---------------- weight convert ----------------
__global__ __launch_bounds__(256)
void wconv(const float* __restrict__ Whf, const float* __restrict__ Whb,
           const float* __restrict__ Wtf, const float* __restrict__ Wtb,
           const float* __restrict__ Wef, const float* __restrict__ Web,
           unsigned short* __restrict__ WB)
{
    int gid = blockIdx.x * 256 + threadIdx.x;        // < 442368
    int t2  = gid / 73728;
    int rem = gid % 73728;
    int n   = rem / 192;
    int c4  = rem % 192;
    int gate = n >> 7, j = n & 127;
    int srow = (gate == 0) ? j : (gate == 1) ? 256 + j : 384 + j;
    const float* W = (t2 == 0) ? Whf : (t2 == 1) ? Whb : (t2 == 2) ? Wtf :
                     (t2 == 3) ? Wtb : (t2 == 4) ? Wef : Web;
    float4 v = ((const float4*)(W + srow * DIM))[c4];
    unsigned short* d = WB + ((size_t)(t2 * 384 + n)) * DIM + c4 * 4;
    d[0] = f2bf(v.x); d[1] = f2bf(v.y); d[2] = f2bf(v.z); d[3] = f2bf(v.w);
}

// ---------------- convert T_cls[b][m][c] -> bf16 TclsB[m][c][b] ----------------
__global__ __launch_bounds__(256)
void conv_tcls(const float* __restrict__ T, unsigned short* __restrict__ TB)
{
    int idx = blockIdx.x * 256 + threadIdx.x;        // 327680 total
    int b = idx / (NCLS * H2);
    int r = idx % (NCLS * H2);
    int m = r >> 8, c = r & 255;
    TB[((m << 8) + c) * H2 + b] = f2bf(T[idx]);
}

// ---------------- gather tokens ----------------
__global__ __launch_bounds__(256)
void gather_toks(const float* __restrict__ enc,
                 const int* __restrict__ idx_h, const int* __restrict__ idx_t, const int* __restrict__ idx_e,
                 unsigned short* __restrict__ tokB)
{
    int gid = blockIdx.x * 256 + threadIdx.x;        // < 6144*192
    int r  = gid / 192, c4 = gid % 192;
    int type = r >> 11;
    int rem  = r & 2047;
    const int* idx = (type == 0) ? idx_h : (type == 1) ? idx_t : idx_e;
    int row = idx[rem];
    float4 v = ((const float4*)(enc + (size_t)row * DIM))[c4];
    unsigned short h4[4] = { f2bf(v.x), f2bf(v.y), f2bf(v.z), f2bf(v.w) };
    *(uint2*)(tokB + (size_t)r * DIM + c4 * 4) = *(uint2*)h4;
}

// ---------------- gates GEMM (NT), LDS-staged 2-phase double-buffer ----------------
// C[type][r][n] = sum_k tokB[type][r][k] * WB[type][n][k]
// M=2048/type, N=768, K=768. Block 128x128, BK=64, 4 waves (2x2), wave 64x64.
// grid 288 = 3*16*6, XCD-swizzled (288 = 8*36).
__global__ __launch_bounds__(256)
void gates_mfma(const unsigned short* __restrict__ tokB,
                const unsigned short* __restrict__ WB,
                float* __restrict__ gates)
{
    __shared__ unsigned short As[2][128 * 64];
    __shared__ unsigned short Bs[2][128 * 64];
    const int lbid = ((int)blockIdx.x & 7) * 36 + ((int)blockIdx.x >> 3);  // bijective
    const int type = lbid / 96;
    const int rem  = lbid % 96;
    const int mb0  = (rem / 6) * 128;
    const int nb0  = (rem % 6) * 128;
    const int tid = threadIdx.x;
    const int w = tid >> 6, l = tid & 63;
    const int lr = l & 15, lg = l >> 4;
    const unsigned short* A = tokB + (size_t)type * 2048 * DIM + (size_t)mb0 * DIM;
    const unsigned short* B = WB   + (size_t)type * 768  * DIM + (size_t)nb0 * DIM;

    // stage mapping: p=0..3, row = (tid>>3)+p*32, colchunk = tid&7 (8 bf16 = 16B)
    const int sr0 = tid >> 3;
    const int sc  = tid & 7;

    bf16x8 ra[4], rb[4];
    #define LOADT(kt)                                                        \
        {                                                                    \
            const int koff = (kt) * 64 + sc * 8;                             \
            _Pragma("unroll")                                                \
            for (int p = 0; p < 4; ++p) {                                    \
                int rr = sr0 + p * 32;                                       \
                ra[p] = *(const bf16x8*)(A + (size_t)rr * DIM + koff);       \
                rb[p] = *(const bf16x8*)(B + (size_t)rr * DIM + koff);       \
            }                                                                \
        }
    #define WRITET(buf)                                                      \
        {                                                                    \
            _Pragma("unroll")                                                \
            for (int p = 0; p < 4; ++p) {                                    \
                int rr = sr0 + p * 32;                                       \
                int bo = (rr * 128 + sc * 16) ^ ((rr & 7) << 4);             \
                *(bf16x8*)((char*)As[buf] + bo) = ra[p];                     \
                *(bf16x8*)((char*)Bs[buf] + bo) = rb[p];                     \
            }                                                                \
        }

    f32x4 acc[4][4];
    #pragma unroll
    for (int mt = 0; mt < 4; ++mt)
        #pragma unroll
        for (int nt = 0; nt < 4; ++nt) acc[mt][nt] = (f32x4){0.f, 0.f, 0.f, 0.f};

    const int am0 = (w & 1) * 64;       // wave A-row base
    const int bn0 = (w >> 1) * 64;      // wave B-row base

    LOADT(0);
    WRITET(0);
    __syncthreads();

    int cur = 0;
    #pragma unroll 1
    for (int kt = 0; kt < 12; ++kt) {
        if (kt + 1 < 12) LOADT(kt + 1);

        #pragma unroll
        for (int ks = 0; ks < 2; ++ks) {
            bf16x8 af[4], bf[4];
            #pragma unroll
            for (int mt = 0; mt < 4; ++mt) {
                int rr = am0 + mt * 16 + lr;
                int bo = (rr * 128 + ks * 64 + lg * 16) ^ ((rr & 7) << 4);
                af[mt] = *(const bf16x8*)((const char*)As[cur] + bo);
            }
            #pragma unroll
            for (int nt = 0; nt < 4; ++nt) {
                int rr = bn0 + nt * 16 + lr;
                int bo = (rr * 128 + ks * 64 + lg * 16) ^ ((rr & 7) << 4);
                bf[nt] = *(const bf16x8*)((const char*)Bs[cur] + bo);
            }
            #pragma unroll
            for (int mt = 0; mt < 4; ++mt)
                #pragma unroll
                for (int nt = 0; nt < 4; ++nt)
                    acc[mt][nt] = __builtin_amdgcn_mfma_f32_16x16x32_bf16(af[mt], bf[nt], acc[mt][nt], 0, 0, 0);
        }

        if (kt + 1 < 12) {
            WRITET(cur ^ 1);
        }
        __syncthreads();
        cur ^= 1;
    }
    #undef LOADT
    #undef WRITET

    float* C = gates + (size_t)type * 2048 * 768 + (size_t)mb0 * 768 + nb0;
    #pragma unroll
    for (int mt = 0; mt < 4; ++mt)
        #pragma unroll
        for (int nt = 0; nt < 4; ++nt)
            #pragma unroll
            for (int r = 0; r < 4; ++r)
                C[(size_t)(am0 + mt * 16 + lg * 4 + r) * 768 + bn0 + nt * 16 + lr] = acc[mt][nt][r];
}

// ---------------- pool epilogue ----------------
__global__ __launch_bounds__(256)
void pool_epilogue(const float* __restrict__ gates,
                   const float* __restrict__ bhf, const float* __restrict__ bhb,
                   const float* __restrict__ btf, const float* __restrict__ btb,
                   const float* __restrict__ bef, const float* __restrict__ beb,
                   unsigned short* __restrict__ poolB)
{
    const int type = blockIdx.x >> 7;
    const int ent  = blockIdx.x & 127;
    const int tid  = threadIdx.x;
    const int dir  = tid >> 7;
    const int j    = tid & 127;
    const float* Bv = (type == 0) ? (dir ? bhb : bhf)
                    : (type == 1) ? (dir ? btb : btf)
                                  : (dir ? beb : bef);
    const float bi = Bv[j], bg = Bv[2 * HID + j], bo = Bv[3 * HID + j];
    const float* g0 = gates + ((size_t)type * 2048 + ent * 16) * 768 + dir * 384 + j;
    float hmax = -1e30f;
    #pragma unroll
    for (int l = 0; l < SPAN; ++l) {
        const float* gr = g0 + l * 768;
        float iv = sigmoidf_(gr[0]   + bi);
        float gv = tanhf(   gr[128] + bg);
        float ov = sigmoidf_(gr[256] + bo);
        hmax = fmaxf(hmax, ov * tanhf(iv * gv));
    }
    poolB[(size_t)(type * NENT + ent) * H2 + dir * HID + j] = f2bf(hmax);
}

// ---------------- gemm1 MFMA: tmpT[k][b][a] = sum_c Ee[k][c] * T[a][b][c] ----------------
__global__ __launch_bounds__(512, 2)
void gemm1_mfma(const unsigned short* __restrict__ EeB,
                const float* __restrict__ T,
                unsigned short* __restrict__ tmpT)
{
    const int tid = threadIdx.x;
    const int w = tid >> 6, l = tid & 63;
    const int lr = l & 15, lg = l >> 4;
    const int b   = blockIdx.x;
    const int mb  = (w & 1) * 64;
    const int nbw = (w >> 1) * 64;

    f32x4 acc[4][4];
    #pragma unroll
    for (int mt = 0; mt < 4; ++mt)
        #pragma unroll
        for (int nt = 0; nt < 4; ++nt) acc[mt][nt] = (f32x4){0.f, 0.f, 0.f, 0.f};

    #pragma unroll 1
    for (int ks = 0; ks < 8; ++ks) {
        bf16x8 af[4];
        #pragma unroll
        for (int mt = 0; mt < 4; ++mt)
            af[mt] = *(const bf16x8*)(EeB + (mb + mt * 16 + lr) * H2 + ks * 32 + lg * 8);
        #pragma unroll
        for (int nt = 0; nt < 4; ++nt) {
            int a_ = nbw + nt * 16 + lr;
            const float* tr = T + ((size_t)a_ * 256 + b) * 256 + ks * 32 + lg * 8;
            float4 v0 = ((const float4*)tr)[0];
            float4 v1 = ((const float4*)tr)[1];
            bf16x8 bf;
            unsigned short* bp = (unsigned short*)&bf;
            bp[0] = f2bf(v0.x); bp[1] = f2bf(v0.y); bp[2] = f2bf(v0.z); bp[3] = f2bf(v0.w);
            bp[4] = f2bf(v1.x); bp[5] = f2bf(v1.y); bp[6] = f2bf(v1.z); bp[7] = f2bf(v1.w);
            #pragma unroll
            for (int mt = 0; mt < 4; ++mt)
                acc[mt][nt] = __builtin_amdgcn_mfma_f32_16x16x32_bf16(af[mt], bf, acc[mt][nt], 0, 0, 0);
        }
    }
    #pragma unroll
    for (int mt = 0; mt < 4; ++mt)
        #pragma unroll
        for (int nt = 0; nt < 4; ++nt)
            #pragma unroll
            for (int r = 0; r < 4; ++r) {
                int k  = mb + mt * 16 + lg * 4 + r;
                int a_ = nbw + nt * 16 + lr;
                tmpT[(size_t)k * 65536 + b * 256 + a_] = f2bf(acc[mt][nt][r]);
            }
}

// ---------------- gemm2 MFMA (NT) ----------------
__global__ __launch_bounds__(256, 2)
void gemm2_mfma(const unsigned short* __restrict__ HxB,
                const unsigned short* __restrict__ tmpT,
                unsigned short* __restrict__ outB)
{
    const int tid = threadIdx.x;
    const int w = tid >> 6, l = tid & 63;
    const int lr = l & 15, lg = l >> 4;
    const int k   = blockIdx.x >> 1;
    const int nb0 = (blockIdx.x & 1) * 128;
    const int ib  = (w & 1) * 64;
    const int bb  = (w >> 1) * 64;
    const unsigned short* Bp = tmpT + (size_t)k * 65536;

    f32x4 acc[4][4];
    #pragma unroll
    for (int mt = 0; mt < 4; ++mt)
        #pragma unroll
        for (int nt = 0; nt < 4; ++nt) acc[mt][nt] = (f32x4){0.f, 0.f, 0.f, 0.f};

    #pragma unroll 1
    for (int ks = 0; ks < 8; ++ks) {
        bf16x8 af[4], bf[4];
        #pragma unroll
        for (int mt = 0; mt < 4; ++mt)
            af[mt] = *(const bf16x8*)(HxB + (ib + mt * 16 + lr) * H2 + ks * 32 + lg * 8);
        #pragma unroll
        for (int nt = 0; nt < 4; ++nt)
            bf[nt] = *(const bf16x8*)(Bp + (nb0 + bb + nt * 16 + lr) * H2 + ks * 32 + lg * 8);
        #pragma unroll
        for (int mt = 0; mt < 4; ++mt)
            #pragma unroll
            for (int nt = 0; nt < 4; ++nt)
                acc[mt][nt] = __builtin_amdgcn_mfma_f32_16x16x32_bf16(af[mt], bf[nt], acc[mt][nt], 0, 0, 0);
    }
    #pragma unroll
    for (int mt = 0; mt < 4; ++mt)
        #pragma unroll
        for (int nt = 0; nt < 4; ++nt)
            #pragma unroll
            for (int r = 0; r < 4; ++r) {
                int i = ib + mt * 16 + lg * 4 + r;
                int bc = nb0 + bb + nt * 16 + lr;
                outB[(size_t)k * (NENT * H2) + i * H2 + bc] = f2bf(acc[mt][nt][r]);
            }
}

// ---------------- step3: block per (k, j-half); m-loop inside ----------------
__global__ __launch_bounds__(512)
void step3_mfma(const unsigned short* __restrict__ hepB,
                const unsigned short* __restrict__ tepB,
                const unsigned short* __restrict__ TclsB,
                float* __restrict__ predT)
{
    __shared__ unsigned short tepS[64 * 256];
    __shared__ unsigned short WS[64 * 256];
    const int lbid = (blockIdx.x & 7) * 32 + (blockIdx.x >> 3);
    const int k  = lbid >> 1;
    const int jh = lbid & 1;
    const int tid = threadIdx.x;
    const int w  = tid >> 6;
    const int l  = tid & 63;
    const int lr = l & 15;
    const int lg = l >> 4;
    const int swz = (lr & 7) << 4;

    {
        const unsigned short* tk = tepB + (size_t)k * (NENT * H2) + (size_t)jh * 64 * H2;
        int row = tid >> 5;
        int col = (tid & 31) * 8;
        #pragma unroll
        for (int q = 0; q < 4; ++q) {
            int r = row + q * 16;
            bf16x8 v = *(const bf16x8*)(tk + r * H2 + col);
            int byteoff = (((r << 8) + col) << 1) ^ ((r & 7) << 4);
            *(bf16x8*)((char*)tepS + byteoff) = v;
        }
    }

    bf16x8 ha[8];
    {
        const unsigned short* hk = hepB + (size_t)k * (NENT * H2);
        #pragma unroll
        for (int ks = 0; ks < 8; ++ks)
            ha[ks] = *(const bf16x8*)(hk + (w * 16 + lr) * H2 + ks * 32 + lg * 8);
    }
    __syncthreads();

    #pragma unroll 1
    for (int m = 0; m < NCLS; ++m) {
        {
            const unsigned short* tcm = TclsB + (size_t)m * (H2 * H2);
            f32x4 acc1[4][2];
            #pragma unroll
            for (int jt = 0; jt < 4; ++jt)
                #pragma unroll
                for (int ct = 0; ct < 2; ++ct) acc1[jt][ct] = (f32x4){0.f, 0.f, 0.f, 0.f};

            #pragma unroll
            for (int ks = 0; ks < 8; ++ks) {
                bf16x8 a[4], bb[2];
                #pragma unroll
                for (int jt = 0; jt < 4; ++jt) {
                    int byteoff = ((((jt * 16 + lr) << 8) + ks * 32 + lg * 8) << 1) ^ swz;
                    a[jt] = *(const bf16x8*)((const char*)tepS + byteoff);
                }
                #pragma unroll
                for (int ct = 0; ct < 2; ++ct)
                    bb[ct] = *(const bf16x8*)(tcm + (size_t)(w * 32 + ct * 16 + lr) * H2 + ks * 32 + lg * 8);
                #pragma unroll
                for (int jt = 0; jt < 4; ++jt)
                    #pragma unroll
                    for (int ct = 0; ct < 2; ++ct)
                        acc1[jt][ct] = __builtin_amdgcn_mfma_f32_16x16x32_bf16(a[jt], bb[ct], acc1[jt][ct], 0, 0, 0);
            }
            #pragma unroll
            for (int jt = 0; jt < 4; ++jt)
                #pragma unroll
                for (int ct = 0; ct < 2; ++ct)
                    #pragma unroll
                    for (int r = 0; r < 4; ++r) {
                        int j = jt * 16 + lg * 4 + r;
                        int c = w * 32 + ct * 16 + lr;
                        int byteoff = ((((j << 8) + c)) << 1) ^ ((j & 7) << 4);
                        *(unsigned short*)((char*)WS + byteoff) = f2bf(acc1[jt][ct][r]);
                    }
        }
        __syncthreads();

        {
            f32x4 acc2[4];
            #pragma unroll
            for (int jt = 0; jt < 4; ++jt) acc2[jt] = (f32x4){0.f, 0.f, 0.f, 0.f};

            #pragma unroll
            for (int ks = 0; ks < 8; ++ks) {
                #pragma unroll
                for (int jt = 0; jt < 4; ++jt) {
                    int byteoff = ((((jt * 16 + lr) << 8) + ks * 32 + lg * 8) << 1) ^ swz;
                    bf16x8 wb = *(const bf16x8*)((const char*)WS + byteoff);
                    acc2[jt] = __builtin_amdgcn_mfma_f32_16x16x32_bf16(ha[ks], wb, acc2[jt], 0, 0, 0);
                }
            }
            float* po = predT + (size_t)(k * NCLS + m) * (NENT * NENT);
            #pragma unroll
            for (int jt = 0; jt < 4; ++jt)
                #pragma unroll
                for (int r = 0; r < 4; ++r) {
                    int i = w * 16 + lg * 4 + r;
                    int j = jh * 64 + jt * 16 + lr;
                    po[i * NENT + j] = acc2[jt][r];
                }
        }
        __syncthreads();
    }
}

// ---------------- transpose: predT[km][ij] -> out[ij][km] ----------------
__global__ __launch_bounds__(256)
void transpose_out(const float* __restrict__ predT, float* __restrict__ out)
{
    __shared__ float Ls[160][33];
    const int bid = blockIdx.x;
    const int ij0 = (bid >> 2) * 32;
    const int km0 = (bid & 3) * 160;
    const int t = threadIdx.x;

    #pragma unroll
    for (int q = 0; q < 20; ++q) {
        int r = (t >> 5) + q * 8;
        int c = t & 31;
        Ls[r][c] = predT[(size_t)(km0 + r) * 16384 + ij0 + c];
    }
    __syncthreads();
    for (int idx = t; idx < 32 * 160; idx += 256) {
        int r = idx / 160, c = idx % 160;
        out[(size_t)(ij0 + r) * 640 + km0 + c] = Ls[c][r];
    }
}

extern "C" void kernel_launch(void* const* d_in, const int* in_sizes, int n_in,
                              void* d_out, int out_size, void* d_ws, size_t ws_size,
                              hipStream_t stream)
{
    (void)in_sizes; (void)n_in; (void)out_size; (void)ws_size;
    const float* enc  = (const float*)d_in[0];
    const int*   hidx = (const int*)d_in[1];
    const int*   tidx = (const int*)d_in[2];
    const int*   eidx = (const int*)d_in[3];
    const float* Whf = (const float*)d_in[4];
    const float* bhf = (const float*)d_in[5];
    const float* Whb = (const float*)d_in[6];
    const float* bhb = (const float*)d_in[7];
    const float* Wtf = (const float*)d_in[8];
    const float* btf = (const float*)d_in[9];
    const float* Wtb = (const float*)d_in[10];
    const float* btb = (const float*)d_in[11];
    const float* Wef = (const float*)d_in[12];
    const float* bef = (const float*)d_in[13];
    const float* Web = (const float*)d_in[14];
    const float* beb = (const float*)d_in[15];
    const float* T_he  = (const float*)d_in[16];
    const float* T_te  = (const float*)d_in[17];
    const float* T_cls = (const float*)d_in[18];

    float* out = (float*)d_out;
    char*  ws  = (char*)d_ws;
    unsigned short* poolB = (unsigned short*)(ws + POOLB_OFF);
    unsigned short* hepB  = (unsigned short*)(ws + HEPB_OFF);
    unsigned short* tepB  = (unsigned short*)(ws + TEPB_OFF);
    unsigned short* TclsB = (unsigned short*)(ws + TCLSB_OFF);
    unsigned short* WB    = (unsigned short*)(ws + WB_OFF);
    unsigned short* tokB  = (unsigned short*)(ws + TOKB_OFF);
    float*          gates = (float*)(ws + GATES_OFF);
    unsigned short* tmpT  = (unsigned short*)(ws + TMPT_OFF);
    float*          predT = (float*)(ws + PREDT_OFF);

    unsigned short* HeB = poolB;
    unsigned short* TeB = poolB + 1 * NENT * H2;
    unsigned short* EeB = poolB + 2 * NENT * H2;

    wconv<<<1728, 256, 0, stream>>>(Whf, Whb, Wtf, Wtb, Wef, Web, WB);
    conv_tcls<<<1280, 256, 0, stream>>>(T_cls, TclsB);
    gather_toks<<<4608, 256, 0, stream>>>(enc, hidx, tidx, eidx, tokB);

    gates_mfma<<<288, 256, 0, stream>>>(tokB, WB, gates);

    pool_epilogue<<<384, 256, 0, stream>>>(gates, bhf, bhb, btf, btb, bef, beb, poolB);

    gemm1_mfma<<<256, 512, 0, stream>>>(EeB, T_he, tmpT);
    gemm2_mfma<<<256, 256, 0, stream>>>(HeB, tmpT, hepB);

    gemm1_mfma<<<256, 512, 0, stream>>>(EeB, T_te, tmpT);
    gemm2_mfma<<<256, 256, 0, stream>>>(TeB, tmpT, tepB);

    step3_mfma<<<256, 512, 0, stream>>>(hepB, tepB, TclsB, predT);

    transpose_out<<<2048, 256, 0, stream>>>(predT, out);
}

// Round 8
// 154.602 us; speedup vs baseline: 7.7827x; 1.1118x over previous
//
#include <hip/hip_runtime.h>
#include <hip/hip_bf16.h>
#include <math.h>

#define DIM   768
#define HID   128
#define H2    256
#define NENT  128
#define SPAN  16
#define NCLS  5

// ---- ws layout (bytes) ----
// poolB bf16 [3][128][256]              @ 0          (196,608)
// hepB  bf16 [k][i][c]                  @ 196608     (8,388,608)
// tepB  bf16 [k][j][b]                  @ 8585216    (8,388,608)
// TclsB bf16 [m][c][b]                  @ 16973824   (655,360)
// WB    bf16 [3][768][768]              @ 17629184   (3,538,944)
// tokB  bf16 [3][2048][768]             @ 21168128   (9,437,184)   dead after gates
// gates fp32 [3][2048][768]             @ 30605312   (18,874,368)  dead after epilogue
// tmpT0 bf16 [k][b][a]                  @ 21168128   (16,777,216)  dead after gemm2
// tmpT1 bf16 [k][b][a]                  @ 37945344   (16,777,216)  dead after gemm2
// predT fp32 [k*5+m][i][j]              @ 21168128   (41,943,040)  overlaps tmpT/tokB/gates
// max end = 63,111,168 B (ws >= 67.5 MB proven in round 1)
#define POOLB_OFF 0
#define HEPB_OFF  196608
#define TEPB_OFF  (HEPB_OFF + 8388608)
#define TCLSB_OFF (TEPB_OFF + 8388608)
#define WB_OFF    (TCLSB_OFF + 655360)
#define TOKB_OFF  21168128
#define GATES_OFF (TOKB_OFF + 9437184)
#define TMPT0_OFF 21168128
#define TMPT1_OFF (TMPT0_OFF + 16777216)
#define PREDT_OFF 21168128

typedef __attribute__((ext_vector_type(8))) short bf16x8;
typedef __attribute__((ext_vector_type(4))) float f32x4;

__device__ __forceinline__ float sigmoidf_(float x) { return 1.0f / (1.0f + __expf(-x)); }

__device__ __forceinline__ unsigned short f2bf(float x) {
    __hip_bfloat16 h = __float2bfloat16(x);
    return *reinterpret_cast<unsigned short*>(&h);
}

// ---------------- prep: wconv + conv_tcls + gather_toks fused ----------------
// blocks [0,1728): wconv; [1728,3008): conv_tcls; [3008,7616): gather
__global__ __launch_bounds__(256)
void prep_kernel(const float* __restrict__ Whf, const float* __restrict__ Whb,
                 const float* __restrict__ Wtf, const float* __restrict__ Wtb,
                 const float* __restrict__ Wef, const float* __restrict__ Web,
                 const float* __restrict__ Tcls, const float* __restrict__ enc,
                 const int* __restrict__ idx_h, const int* __restrict__ idx_t,
                 const int* __restrict__ idx_e,
                 unsigned short* __restrict__ WB, unsigned short* __restrict__ TB,
                 unsigned short* __restrict__ tokB)
{
    const int bb = blockIdx.x;
    const int tid = threadIdx.x;
    if (bb < 1728) {
        int gid = bb * 256 + tid;                        // < 442368
        int t2  = gid / 73728;
        int rem = gid % 73728;
        int n   = rem / 192;
        int c4  = rem % 192;
        int gate = n >> 7, j = n & 127;
        int srow = (gate == 0) ? j : (gate == 1) ? 256 + j : 384 + j;
        const float* W = (t2 == 0) ? Whf : (t2 == 1) ? Whb : (t2 == 2) ? Wtf :
                         (t2 == 3) ? Wtb : (t2 == 4) ? Wef : Web;
        float4 v = ((const float4*)(W + srow * DIM))[c4];
        unsigned short* d = WB + ((size_t)(t2 * 384 + n)) * DIM + c4 * 4;
        d[0] = f2bf(v.x); d[1] = f2bf(v.y); d[2] = f2bf(v.z); d[3] = f2bf(v.w);
    } else if (bb < 3008) {
        int idx = (bb - 1728) * 256 + tid;               // < 327680
        int b = idx / (NCLS * H2);
        int r = idx % (NCLS * H2);
        int m = r >> 8, c = r & 255;
        TB[((m << 8) + c) * H2 + b] = f2bf(Tcls[idx]);
    } else {
        int gid = (bb - 3008) * 256 + tid;               // < 6144*192
        int r  = gid / 192, c4 = gid % 192;
        int type = r >> 11;
        int rem  = r & 2047;
        const int* idx = (type == 0) ? idx_h : (type == 1) ? idx_t : idx_e;
        int row = idx[rem];
        float4 v = ((const float4*)(enc + (size_t)row * DIM))[c4];
        unsigned short h4[4] = { f2bf(v.x), f2bf(v.y), f2bf(v.z), f2bf(v.w) };
        *(uint2*)(tokB + (size_t)r * DIM + c4 * 4) = *(uint2*)h4;
    }
}

// ---------------- gates GEMM (NT), LDS-staged 2-phase double-buffer ----------------
__global__ __launch_bounds__(256)
void gates_mfma(const unsigned short* __restrict__ tokB,
                const unsigned short* __restrict__ WB,
                float* __restrict__ gates)
{
    __shared__ unsigned short As[2][128 * 64];
    __shared__ unsigned short Bs[2][128 * 64];
    const int lbid = ((int)blockIdx.x & 7) * 36 + ((int)blockIdx.x >> 3);  // bijective
    const int type = lbid / 96;
    const int rem  = lbid % 96;
    const int mb0  = (rem / 6) * 128;
    const int nb0  = (rem % 6) * 128;
    const int tid = threadIdx.x;
    const int w = tid >> 6, l = tid & 63;
    const int lr = l & 15, lg = l >> 4;
    const unsigned short* A = tokB + (size_t)type * 2048 * DIM + (size_t)mb0 * DIM;
    const unsigned short* B = WB   + (size_t)type * 768  * DIM + (size_t)nb0 * DIM;

    const int sr0 = tid >> 3;
    const int sc  = tid & 7;

    bf16x8 ra[4], rb[4];
    #define LOADT(kt)                                                        \
        {                                                                    \
            const int koff = (kt) * 64 + sc * 8;                             \
            _Pragma("unroll")                                                \
            for (int p = 0; p < 4; ++p) {                                    \
                int rr = sr0 + p * 32;                                       \
                ra[p] = *(const bf16x8*)(A + (size_t)rr * DIM + koff);       \
                rb[p] = *(const bf16x8*)(B + (size_t)rr * DIM + koff);       \
            }                                                                \
        }
    #define WRITET(buf)                                                      \
        {                                                                    \
            _Pragma("unroll")                                                \
            for (int p = 0; p < 4; ++p) {                                    \
                int rr = sr0 + p * 32;                                       \
                int bo = (rr * 128 + sc * 16) ^ ((rr & 7) << 4);             \
                *(bf16x8*)((char*)As[buf] + bo) = ra[p];                     \
                *(bf16x8*)((char*)Bs[buf] + bo) = rb[p];                     \
            }                                                                \
        }

    f32x4 acc[4][4];
    #pragma unroll
    for (int mt = 0; mt < 4; ++mt)
        #pragma unroll
        for (int nt = 0; nt < 4; ++nt) acc[mt][nt] = (f32x4){0.f, 0.f, 0.f, 0.f};

    const int am0 = (w & 1) * 64;
    const int bn0 = (w >> 1) * 64;

    LOADT(0);
    WRITET(0);
    __syncthreads();

    int cur = 0;
    #pragma unroll 1
    for (int kt = 0; kt < 12; ++kt) {
        if (kt + 1 < 12) LOADT(kt + 1);

        #pragma unroll
        for (int ks = 0; ks < 2; ++ks) {
            bf16x8 af[4], bf[4];
            #pragma unroll
            for (int mt = 0; mt < 4; ++mt) {
                int rr = am0 + mt * 16 + lr;
                int bo = (rr * 128 + ks * 64 + lg * 16) ^ ((rr & 7) << 4);
                af[mt] = *(const bf16x8*)((const char*)As[cur] + bo);
            }
            #pragma unroll
            for (int nt = 0; nt < 4; ++nt) {
                int rr = bn0 + nt * 16 + lr;
                int bo = (rr * 128 + ks * 64 + lg * 16) ^ ((rr & 7) << 4);
                bf[nt] = *(const bf16x8*)((const char*)Bs[cur] + bo);
            }
            #pragma unroll
            for (int mt = 0; mt < 4; ++mt)
                #pragma unroll
                for (int nt = 0; nt < 4; ++nt)
                    acc[mt][nt] = __builtin_amdgcn_mfma_f32_16x16x32_bf16(af[mt], bf[nt], acc[mt][nt], 0, 0, 0);
        }

        if (kt + 1 < 12) {
            WRITET(cur ^ 1);
        }
        __syncthreads();
        cur ^= 1;
    }
    #undef LOADT
    #undef WRITET

    float* C = gates + (size_t)type * 2048 * 768 + (size_t)mb0 * 768 + nb0;
    #pragma unroll
    for (int mt = 0; mt < 4; ++mt)
        #pragma unroll
        for (int nt = 0; nt < 4; ++nt)
            #pragma unroll
            for (int r = 0; r < 4; ++r)
                C[(size_t)(am0 + mt * 16 + lg * 4 + r) * 768 + bn0 + nt * 16 + lr] = acc[mt][nt][r];
}

// ---------------- pool epilogue ----------------
__global__ __launch_bounds__(256)
void pool_epilogue(const float* __restrict__ gates,
                   const float* __restrict__ bhf, const float* __restrict__ bhb,
                   const float* __restrict__ btf, const float* __restrict__ btb,
                   const float* __restrict__ bef, const float* __restrict__ beb,
                   unsigned short* __restrict__ poolB)
{
    const int type = blockIdx.x >> 7;
    const int ent  = blockIdx.x & 127;
    const int tid  = threadIdx.x;
    const int dir  = tid >> 7;
    const int j    = tid & 127;
    const float* Bv = (type == 0) ? (dir ? bhb : bhf)
                    : (type == 1) ? (dir ? btb : btf)
                                  : (dir ? beb : bef);
    const float bi = Bv[j], bg = Bv[2 * HID + j], bo = Bv[3 * HID + j];
    const float* g0 = gates + ((size_t)type * 2048 + ent * 16) * 768 + dir * 384 + j;
    float hmax = -1e30f;
    #pragma unroll
    for (int l = 0; l < SPAN; ++l) {
        const float* gr = g0 + l * 768;
        float iv = sigmoidf_(gr[0]   + bi);
        float gv = tanhf(   gr[128] + bg);
        float ov = sigmoidf_(gr[256] + bo);
        hmax = fmaxf(hmax, ov * tanhf(iv * gv));
    }
    poolB[(size_t)(type * NENT + ent) * H2 + dir * HID + j] = f2bf(hmax);
}

// ---------------- gemm1 (both tensors), LDS-staged double-buffer ----------------
// tmpT[t][k][b][a] = sum_c Ee[k][c] * T_t[a][b][c]
// grid 512: t = bid>>8, b = bid&255. 512 thr = 8 waves (2 kw x 4 aw).
// LDS: Ts[2][256 a][64 c] bf16, XOR-swizzled; T staged once (no wave duplication).
__global__ __launch_bounds__(512)
void gemm1_mfma(const unsigned short* __restrict__ EeB,
                const float* __restrict__ T0, const float* __restrict__ T1,
                unsigned short* __restrict__ tmpT0, unsigned short* __restrict__ tmpT1)
{
    __shared__ unsigned short Ts[2][256 * 64];
    const int bid = blockIdx.x;
    const int tz = bid >> 8;
    const int b  = bid & 255;
    const float* T = tz ? T1 : T0;
    unsigned short* outp = tz ? tmpT1 : tmpT0;
    const int tid = threadIdx.x;
    const int w = tid >> 6, l = tid & 63;
    const int lr = l & 15, lg = l >> 4;
    const int kw = (w & 1) * 64;
    const int aw = (w >> 1) * 64;

    // staging: 256 rows (a) x 64 c fp32 -> bf16; thread: sr0 = tid>>3, sc = tid&7
    const int sr0 = tid >> 3;
    const int sc  = tid & 7;

    float4 rv[4][2];
    #define G1LOAD(kt)                                                            \
        {                                                                         \
            _Pragma("unroll")                                                     \
            for (int p = 0; p < 4; ++p) {                                         \
                const float* tr = T + ((size_t)(sr0 + p * 64) * 256 + b) * 256    \
                                    + (kt) * 64 + sc * 8;                         \
                rv[p][0] = ((const float4*)tr)[0];                                \
                rv[p][1] = ((const float4*)tr)[1];                                \
            }                                                                     \
        }
    #define G1WRITE(buf)                                                          \
        {                                                                         \
            _Pragma("unroll")                                                     \
            for (int p = 0; p < 4; ++p) {                                         \
                int rr = sr0 + p * 64;                                            \
                bf16x8 hv; unsigned short* hp = (unsigned short*)&hv;             \
                hp[0]=f2bf(rv[p][0].x); hp[1]=f2bf(rv[p][0].y);                   \
                hp[2]=f2bf(rv[p][0].z); hp[3]=f2bf(rv[p][0].w);                   \
                hp[4]=f2bf(rv[p][1].x); hp[5]=f2bf(rv[p][1].y);                   \
                hp[6]=f2bf(rv[p][1].z); hp[7]=f2bf(rv[p][1].w);                   \
                int bo = (rr * 128 + sc * 16) ^ ((rr & 7) << 4);                  \
                *(bf16x8*)((char*)Ts[buf] + bo) = hv;                             \
            }                                                                     \
        }

    f32x4 acc[4][4];
    #pragma unroll
    for (int mt = 0; mt < 4; ++mt)
        #pragma unroll
        for (int nt = 0; nt < 4; ++nt) acc[mt][nt] = (f32x4){0.f, 0.f, 0.f, 0.f};

    G1LOAD(0);
    G1WRITE(0);
    __syncthreads();

    int cur = 0;
    #pragma unroll 1
    for (int kt = 0; kt < 4; ++kt) {
        if (kt + 1 < 4) G1LOAD(kt + 1);

        #pragma unroll
        for (int ks = 0; ks < 2; ++ks) {
            bf16x8 af[4], bf[4];
            #pragma unroll
            for (int mt = 0; mt < 4; ++mt)
                af[mt] = *(const bf16x8*)(EeB + (kw + mt * 16 + lr) * H2 + kt * 64 + ks * 32 + lg * 8);
            #pragma unroll
            for (int nt = 0; nt < 4; ++nt) {
                int rr = aw + nt * 16 + lr;
                int bo = (rr * 128 + ks * 64 + lg * 16) ^ ((rr & 7) << 4);
                bf[nt] = *(const bf16x8*)((const char*)Ts[cur] + bo);
            }
            #pragma unroll
            for (int mt = 0; mt < 4; ++mt)
                #pragma unroll
                for (int nt = 0; nt < 4; ++nt)
                    acc[mt][nt] = __builtin_amdgcn_mfma_f32_16x16x32_bf16(af[mt], bf[nt], acc[mt][nt], 0, 0, 0);
        }

        if (kt + 1 < 4) G1WRITE(cur ^ 1);
        __syncthreads();
        cur ^= 1;
    }
    #undef G1LOAD
    #undef G1WRITE

    #pragma unroll
    for (int mt = 0; mt < 4; ++mt)
        #pragma unroll
        for (int nt = 0; nt < 4; ++nt)
            #pragma unroll
            for (int r = 0; r < 4; ++r) {
                int k  = kw + mt * 16 + lg * 4 + r;
                int a_ = aw + nt * 16 + lr;
                outp[(size_t)k * 65536 + b * 256 + a_] = f2bf(acc[mt][nt][r]);
            }
}

// ---------------- gemm2 (both tensors, NT): out[k][i][bc] = sum_a Hx[i][a]*tmpT[k][bc][a] ----
// grid 512: t = bid>>8, k = (bid>>1)&127, nb0 = (bid&1)*128. 4 waves 1x4 (no B dup).
__global__ __launch_bounds__(256)
void gemm2_mfma(const unsigned short* __restrict__ HeB, const unsigned short* __restrict__ TeB,
                const unsigned short* __restrict__ tmpT0, const unsigned short* __restrict__ tmpT1,
                unsigned short* __restrict__ hepB, unsigned short* __restrict__ tepB)
{
    const int bid = blockIdx.x;
    const int t  = bid >> 8;
    const int k  = (bid >> 1) & 127;
    const int nb0 = (bid & 1) * 128;
    const unsigned short* HxB = t ? TeB : HeB;
    const unsigned short* Bp  = (t ? tmpT1 : tmpT0) + (size_t)k * 65536;
    unsigned short* outB = t ? tepB : hepB;
    const int tid = threadIdx.x;
    const int w = tid >> 6, l = tid & 63;
    const int lr = l & 15, lg = l >> 4;
    const int bb = w * 32;

    f32x4 acc[8][2];
    #pragma unroll
    for (int mt = 0; mt < 8; ++mt)
        #pragma unroll
        for (int nt = 0; nt < 2; ++nt) acc[mt][nt] = (f32x4){0.f, 0.f, 0.f, 0.f};

    #pragma unroll 2
    for (int ks = 0; ks < 8; ++ks) {
        bf16x8 af[8], bf[2];
        #pragma unroll
        for (int mt = 0; mt < 8; ++mt)
            af[mt] = *(const bf16x8*)(HxB + (mt * 16 + lr) * H2 + ks * 32 + lg * 8);
        #pragma unroll
        for (int nt = 0; nt < 2; ++nt)
            bf[nt] = *(const bf16x8*)(Bp + (nb0 + bb + nt * 16 + lr) * H2 + ks * 32 + lg * 8);
        #pragma unroll
        for (int mt = 0; mt < 8; ++mt)
            #pragma unroll
            for (int nt = 0; nt < 2; ++nt)
                acc[mt][nt] = __builtin_amdgcn_mfma_f32_16x16x32_bf16(af[mt], bf[nt], acc[mt][nt], 0, 0, 0);
    }
    #pragma unroll
    for (int mt = 0; mt < 8; ++mt)
        #pragma unroll
        for (int nt = 0; nt < 2; ++nt)
            #pragma unroll
            for (int r = 0; r < 4; ++r) {
                int i = mt * 16 + lg * 4 + r;
                int bc = nb0 + bb + nt * 16 + lr;
                outB[(size_t)k * (NENT * H2) + i * H2 + bc] = f2bf(acc[mt][nt][r]);
            }
}

// ---------------- step3: block per (k, j-half); m-loop inside ----------------
__global__ __launch_bounds__(512)
void step3_mfma(const unsigned short* __restrict__ hepB,
                const unsigned short* __restrict__ tepB,
                const unsigned short* __restrict__ TclsB,
                float* __restrict__ predT)
{
    __shared__ unsigned short tepS[64 * 256];
    __shared__ unsigned short WS[64 * 256];
    const int lbid = (blockIdx.x & 7) * 32 + (blockIdx.x >> 3);
    const int k  = lbid >> 1;
    const int jh = lbid & 1;
    const int tid = threadIdx.x;
    const int w  = tid >> 6;
    const int l  = tid & 63;
    const int lr = l & 15;
    const int lg = l >> 4;
    const int swz = (lr & 7) << 4;

    {
        const unsigned short* tk = tepB + (size_t)k * (NENT * H2) + (size_t)jh * 64 * H2;
        int row = tid >> 5;
        int col = (tid & 31) * 8;
        #pragma unroll
        for (int q = 0; q < 4; ++q) {
            int r = row + q * 16;
            bf16x8 v = *(const bf16x8*)(tk + r * H2 + col);
            int byteoff = (((r << 8) + col) << 1) ^ ((r & 7) << 4);
            *(bf16x8*)((char*)tepS + byteoff) = v;
        }
    }

    bf16x8 ha[8];
    {
        const unsigned short* hk = hepB + (size_t)k * (NENT * H2);
        #pragma unroll
        for (int ks = 0; ks < 8; ++ks)
            ha[ks] = *(const bf16x8*)(hk + (w * 16 + lr) * H2 + ks * 32 + lg * 8);
    }
    __syncthreads();

    #pragma unroll 1
    for (int m = 0; m < NCLS; ++m) {
        {
            const unsigned short* tcm = TclsB + (size_t)m * (H2 * H2);
            f32x4 acc1[4][2];
            #pragma unroll
            for (int jt = 0; jt < 4; ++jt)
                #pragma unroll
                for (int ct = 0; ct < 2; ++ct) acc1[jt][ct] = (f32x4){0.f, 0.f, 0.f, 0.f};

            #pragma unroll
            for (int ks = 0; ks < 8; ++ks) {
                bf16x8 a[4], bb[2];
                #pragma unroll
                for (int jt = 0; jt < 4; ++jt) {
                    int byteoff = ((((jt * 16 + lr) << 8) + ks * 32 + lg * 8) << 1) ^ swz;
                    a[jt] = *(const bf16x8*)((const char*)tepS + byteoff);
                }
                #pragma unroll
                for (int ct = 0; ct < 2; ++ct)
                    bb[ct] = *(const bf16x8*)(tcm + (size_t)(w * 32 + ct * 16 + lr) * H2 + ks * 32 + lg * 8);
                #pragma unroll
                for (int jt = 0; jt < 4; ++jt)
                    #pragma unroll
                    for (int ct = 0; ct < 2; ++ct)
                        acc1[jt][ct] = __builtin_amdgcn_mfma_f32_16x16x32_bf16(a[jt], bb[ct], acc1[jt][ct], 0, 0, 0);
            }
            #pragma unroll
            for (int jt = 0; jt < 4; ++jt)
                #pragma unroll
                for (int ct = 0; ct < 2; ++ct)
                    #pragma unroll
                    for (int r = 0; r < 4; ++r) {
                        int j = jt * 16 + lg * 4 + r;
                        int c = w * 32 + ct * 16 + lr;
                        int byteoff = ((((j << 8) + c)) << 1) ^ ((j & 7) << 4);
                        *(unsigned short*)((char*)WS + byteoff) = f2bf(acc1[jt][ct][r]);
                    }
        }
        __syncthreads();

        {
            f32x4 acc2[4];
            #pragma unroll
            for (int jt = 0; jt < 4; ++jt) acc2[jt] = (f32x4){0.f, 0.f, 0.f, 0.f};

            #pragma unroll
            for (int ks = 0; ks < 8; ++ks) {
                #pragma unroll
                for (int jt = 0; jt < 4; ++jt) {
                    int byteoff = ((((jt * 16 + lr) << 8) + ks * 32 + lg * 8) << 1) ^ swz;
                    bf16x8 wb = *(const bf16x8*)((const char*)WS + byteoff);
                    acc2[jt] = __builtin_amdgcn_mfma_f32_16x16x32_bf16(ha[ks], wb, acc2[jt], 0, 0, 0);
                }
            }
            float* po = predT + (size_t)(k * NCLS + m) * (NENT * NENT);
            #pragma unroll
            for (int jt = 0; jt < 4; ++jt)
                #pragma unroll
                for (int r = 0; r < 4; ++r) {
                    int i = w * 16 + lg * 4 + r;
                    int j = jh * 64 + jt * 16 + lr;
                    po[i * NENT + j] = acc2[jt][r];
                }
        }
        __syncthreads();
    }
}

// ---------------- transpose: predT[km][ij] -> out[ij][km] ----------------
__global__ __launch_bounds__(256)
void transpose_out(const float* __restrict__ predT, float* __restrict__ out)
{
    __shared__ float Ls[160][33];
    const int bid = blockIdx.x;
    const int ij0 = (bid >> 2) * 32;
    const int km0 = (bid & 3) * 160;
    const int t = threadIdx.x;

    #pragma unroll
    for (int q = 0; q < 20; ++q) {
        int r = (t >> 5) + q * 8;
        int c = t & 31;
        Ls[r][c] = predT[(size_t)(km0 + r) * 16384 + ij0 + c];
    }
    __syncthreads();
    for (int idx = t; idx < 32 * 160; idx += 256) {
        int r = idx / 160, c = idx % 160;
        out[(size_t)(ij0 + r) * 640 + km0 + c] = Ls[c][r];
    }
}

extern "C" void kernel_launch(void* const* d_in, const int* in_sizes, int n_in,
                              void* d_out, int out_size, void* d_ws, size_t ws_size,
                              hipStream_t stream)
{
    (void)in_sizes; (void)n_in; (void)out_size; (void)ws_size;
    const float* enc  = (const float*)d_in[0];
    const int*   hidx = (const int*)d_in[1];
    const int*   tidx = (const int*)d_in[2];
    const int*   eidx = (const int*)d_in[3];
    const float* Whf = (const float*)d_in[4];
    const float* bhf = (const float*)d_in[5];
    const float* Whb = (const float*)d_in[6];
    const float* bhb = (const float*)d_in[7];
    const float* Wtf = (const float*)d_in[8];
    const float* btf = (const float*)d_in[9];
    const float* Wtb = (const float*)d_in[10];
    const float* btb = (const float*)d_in[11];
    const float* Wef = (const float*)d_in[12];
    const float* bef = (const float*)d_in[13];
    const float* Web = (const float*)d_in[14];
    const float* beb = (const float*)d_in[15];
    const float* T_he  = (const float*)d_in[16];
    const float* T_te  = (const float*)d_in[17];
    const float* T_cls = (const float*)d_in[18];

    float* out = (float*)d_out;
    char*  ws  = (char*)d_ws;
    unsigned short* poolB = (unsigned short*)(ws + POOLB_OFF);
    unsigned short* hepB  = (unsigned short*)(ws + HEPB_OFF);
    unsigned short* tepB  = (unsigned short*)(ws + TEPB_OFF);
    unsigned short* TclsB = (unsigned short*)(ws + TCLSB_OFF);
    unsigned short* WB    = (unsigned short*)(ws + WB_OFF);
    unsigned short* tokB  = (unsigned short*)(ws + TOKB_OFF);
    float*          gates = (float*)(ws + GATES_OFF);
    unsigned short* tmpT0 = (unsigned short*)(ws + TMPT0_OFF);
    unsigned short* tmpT1 = (unsigned short*)(ws + TMPT1_OFF);
    float*          predT = (float*)(ws + PREDT_OFF);

    unsigned short* HeB = poolB;
    unsigned short* TeB = poolB + 1 * NENT * H2;
    unsigned short* EeB = poolB + 2 * NENT * H2;

    prep_kernel<<<7616, 256, 0, stream>>>(Whf, Whb, Wtf, Wtb, Wef, Web,
                                          T_cls, enc, hidx, tidx, eidx,
                                          WB, TclsB, tokB);

    gates_mfma<<<288, 256, 0, stream>>>(tokB, WB, gates);

    pool_epilogue<<<384, 256, 0, stream>>>(gates, bhf, bhb, btf, btb, bef, beb, poolB);

    gemm1_mfma<<<512, 512, 0, stream>>>(EeB, T_he, T_te, tmpT0, tmpT1);

    gemm2_mfma<<<512, 256, 0, stream>>>(HeB, TeB, tmpT0, tmpT1, hepB, tepB);

    step3_mfma<<<256, 512, 0, stream>>>(hepB, tepB, TclsB, predT);

    transpose_out<<<2048, 256, 0, stream>>>(predT, out);
}

// Round 9
// 153.428 us; speedup vs baseline: 7.8423x; 1.0077x over previous
//
#include <hip/hip_runtime.h>
#include <hip/hip_bf16.h>
#include <math.h>

#define DIM   768
#define HID   128
#define H2    256
#define NENT  128
#define SPAN  16
#define NCLS  5

// ---- ws layout (bytes) ----
#define POOLB_OFF 0
#define HEPB_OFF  196608
#define TEPB_OFF  (HEPB_OFF + 8388608)
#define TCLSB_OFF (TEPB_OFF + 8388608)
#define WB_OFF    (TCLSB_OFF + 655360)
#define TOKB_OFF  21168128
#define GATES_OFF (TOKB_OFF + 9437184)
#define TMPT0_OFF 21168128
#define TMPT1_OFF (TMPT0_OFF + 16777216)
#define PREDT_OFF 21168128

typedef __attribute__((ext_vector_type(8))) short bf16x8;
typedef __attribute__((ext_vector_type(4))) float f32x4;

__device__ __forceinline__ float sigmoidf_(float x) { return 1.0f / (1.0f + __expf(-x)); }

__device__ __forceinline__ unsigned short f2bf(float x) {
    __hip_bfloat16 h = __float2bfloat16(x);
    return *reinterpret_cast<unsigned short*>(&h);
}

// ---------------- prep: wconv + conv_tcls + gather_toks fused ----------------
__global__ __launch_bounds__(256)
void prep_kernel(const float* __restrict__ Whf, const float* __restrict__ Whb,
                 const float* __restrict__ Wtf, const float* __restrict__ Wtb,
                 const float* __restrict__ Wef, const float* __restrict__ Web,
                 const float* __restrict__ Tcls, const float* __restrict__ enc,
                 const int* __restrict__ idx_h, const int* __restrict__ idx_t,
                 const int* __restrict__ idx_e,
                 unsigned short* __restrict__ WB, unsigned short* __restrict__ TB,
                 unsigned short* __restrict__ tokB)
{
    const int bb = blockIdx.x;
    const int tid = threadIdx.x;
    if (bb < 1728) {
        int gid = bb * 256 + tid;                        // < 442368
        int t2  = gid / 73728;
        int rem = gid % 73728;
        int n   = rem / 192;
        int c4  = rem % 192;
        int gate = n >> 7, j = n & 127;
        int srow = (gate == 0) ? j : (gate == 1) ? 256 + j : 384 + j;
        const float* W = (t2 == 0) ? Whf : (t2 == 1) ? Whb : (t2 == 2) ? Wtf :
                         (t2 == 3) ? Wtb : (t2 == 4) ? Wef : Web;
        float4 v = ((const float4*)(W + srow * DIM))[c4];
        unsigned short* d = WB + ((size_t)(t2 * 384 + n)) * DIM + c4 * 4;
        d[0] = f2bf(v.x); d[1] = f2bf(v.y); d[2] = f2bf(v.z); d[3] = f2bf(v.w);
    } else if (bb < 3008) {
        int idx = (bb - 1728) * 256 + tid;               // < 327680
        int b = idx / (NCLS * H2);
        int r = idx % (NCLS * H2);
        int m = r >> 8, c = r & 255;
        TB[((m << 8) + c) * H2 + b] = f2bf(Tcls[idx]);
    } else {
        int gid = (bb - 3008) * 256 + tid;               // < 6144*192
        int r  = gid / 192, c4 = gid % 192;
        int type = r >> 11;
        int rem  = r & 2047;
        const int* idx = (type == 0) ? idx_h : (type == 1) ? idx_t : idx_e;
        int row = idx[rem];
        float4 v = ((const float4*)(enc + (size_t)row * DIM))[c4];
        unsigned short h4[4] = { f2bf(v.x), f2bf(v.y), f2bf(v.z), f2bf(v.w) };
        *(uint2*)(tokB + (size_t)r * DIM + c4 * 4) = *(uint2*)h4;
    }
}

// ---------------- gates GEMM (NT), LDS-staged 2-phase double-buffer ----------------
__global__ __launch_bounds__(256)
void gates_mfma(const unsigned short* __restrict__ tokB,
                const unsigned short* __restrict__ WB,
                float* __restrict__ gates)
{
    __shared__ unsigned short As[2][128 * 64];
    __shared__ unsigned short Bs[2][128 * 64];
    const int lbid = ((int)blockIdx.x & 7) * 36 + ((int)blockIdx.x >> 3);  // bijective
    const int type = lbid / 96;
    const int rem  = lbid % 96;
    const int mb0  = (rem / 6) * 128;
    const int nb0  = (rem % 6) * 128;
    const int tid = threadIdx.x;
    const int w = tid >> 6, l = tid & 63;
    const int lr = l & 15, lg = l >> 4;
    const unsigned short* A = tokB + (size_t)type * 2048 * DIM + (size_t)mb0 * DIM;
    const unsigned short* B = WB   + (size_t)type * 768  * DIM + (size_t)nb0 * DIM;

    const int sr0 = tid >> 3;
    const int sc  = tid & 7;

    bf16x8 ra[4], rb[4];
    #define LOADT(kt)                                                        \
        {                                                                    \
            const int koff = (kt) * 64 + sc * 8;                             \
            _Pragma("unroll")                                                \
            for (int p = 0; p < 4; ++p) {                                    \
                int rr = sr0 + p * 32;                                       \
                ra[p] = *(const bf16x8*)(A + (size_t)rr * DIM + koff);       \
                rb[p] = *(const bf16x8*)(B + (size_t)rr * DIM + koff);       \
            }                                                                \
        }
    #define WRITET(buf)                                                      \
        {                                                                    \
            _Pragma("unroll")                                                \
            for (int p = 0; p < 4; ++p) {                                    \
                int rr = sr0 + p * 32;                                       \
                int bo = (rr * 128 + sc * 16) ^ ((rr & 7) << 4);             \
                *(bf16x8*)((char*)As[buf] + bo) = ra[p];                     \
                *(bf16x8*)((char*)Bs[buf] + bo) = rb[p];                     \
            }                                                                \
        }

    f32x4 acc[4][4];
    #pragma unroll
    for (int mt = 0; mt < 4; ++mt)
        #pragma unroll
        for (int nt = 0; nt < 4; ++nt) acc[mt][nt] = (f32x4){0.f, 0.f, 0.f, 0.f};

    const int am0 = (w & 1) * 64;
    const int bn0 = (w >> 1) * 64;

    LOADT(0);
    WRITET(0);
    __syncthreads();

    int cur = 0;
    #pragma unroll 1
    for (int kt = 0; kt < 12; ++kt) {
        if (kt + 1 < 12) LOADT(kt + 1);

        #pragma unroll
        for (int ks = 0; ks < 2; ++ks) {
            bf16x8 af[4], bf[4];
            #pragma unroll
            for (int mt = 0; mt < 4; ++mt) {
                int rr = am0 + mt * 16 + lr;
                int bo = (rr * 128 + ks * 64 + lg * 16) ^ ((rr & 7) << 4);
                af[mt] = *(const bf16x8*)((const char*)As[cur] + bo);
            }
            #pragma unroll
            for (int nt = 0; nt < 4; ++nt) {
                int rr = bn0 + nt * 16 + lr;
                int bo = (rr * 128 + ks * 64 + lg * 16) ^ ((rr & 7) << 4);
                bf[nt] = *(const bf16x8*)((const char*)Bs[cur] + bo);
            }
            #pragma unroll
            for (int mt = 0; mt < 4; ++mt)
                #pragma unroll
                for (int nt = 0; nt < 4; ++nt)
                    acc[mt][nt] = __builtin_amdgcn_mfma_f32_16x16x32_bf16(af[mt], bf[nt], acc[mt][nt], 0, 0, 0);
        }

        if (kt + 1 < 12) {
            WRITET(cur ^ 1);
        }
        __syncthreads();
        cur ^= 1;
    }
    #undef LOADT
    #undef WRITET

    float* C = gates + (size_t)type * 2048 * 768 + (size_t)mb0 * 768 + nb0;
    #pragma unroll
    for (int mt = 0; mt < 4; ++mt)
        #pragma unroll
        for (int nt = 0; nt < 4; ++nt)
            #pragma unroll
            for (int r = 0; r < 4; ++r)
                C[(size_t)(am0 + mt * 16 + lg * 4 + r) * 768 + bn0 + nt * 16 + lr] = acc[mt][nt][r];
}

// ---------------- pool epilogue ----------------
__global__ __launch_bounds__(256)
void pool_epilogue(const float* __restrict__ gates,
                   const float* __restrict__ bhf, const float* __restrict__ bhb,
                   const float* __restrict__ btf, const float* __restrict__ btb,
                   const float* __restrict__ bef, const float* __restrict__ beb,
                   unsigned short* __restrict__ poolB)
{
    const int type = blockIdx.x >> 7;
    const int ent  = blockIdx.x & 127;
    const int tid  = threadIdx.x;
    const int dir  = tid >> 7;
    const int j    = tid & 127;
    const float* Bv = (type == 0) ? (dir ? bhb : bhf)
                    : (type == 1) ? (dir ? btb : btf)
                                  : (dir ? beb : bef);
    const float bi = Bv[j], bg = Bv[2 * HID + j], bo = Bv[3 * HID + j];
    const float* g0 = gates + ((size_t)type * 2048 + ent * 16) * 768 + dir * 384 + j;
    float hmax = -1e30f;
    #pragma unroll
    for (int l = 0; l < SPAN; ++l) {
        const float* gr = g0 + l * 768;
        float iv = sigmoidf_(gr[0]   + bi);
        float gv = tanhf(   gr[128] + bg);
        float ov = sigmoidf_(gr[256] + bo);
        hmax = fmaxf(hmax, ov * tanhf(iv * gv));
    }
    poolB[(size_t)(type * NENT + ent) * H2 + dir * HID + j] = f2bf(hmax);
}

// ---------------- gemm1 (both tensors), channel-spread tiling ----------------
// tmpT[t][k][b][a] = sum_c Ee[k][c] * T_t[a][b][c]
// grid 512 = tz(2) x at(4: a-tile 64) x bg(64: b-group 4); block 512 = 8 waves = kw(2) x bw(4)
// LDS: Ts[2][64a][4b][64c] bf16 swizzled (2x32 KB). Reads vary addr bits 10-17 (b, bg)
// -> no L2 channel camping (round-8 bug: fixed-b blocks camped on ~1/4 of channels).
__global__ __launch_bounds__(512)
void gemm1_mfma(const unsigned short* __restrict__ EeB,
                const float* __restrict__ T0, const float* __restrict__ T1,
                unsigned short* __restrict__ tmpT0, unsigned short* __restrict__ tmpT1)
{
    __shared__ unsigned short Ts[2][64 * 4 * 64];
    const int bid = blockIdx.x;
    const int tz  = bid >> 8;
    const int rem = bid & 255;
    const int a0  = (rem >> 6) * 64;
    const int b0  = (rem & 63) * 4;
    const float* T = tz ? T1 : T0;
    unsigned short* outp = tz ? tmpT1 : tmpT0;
    const int tid = threadIdx.x;
    const int w = tid >> 6, l = tid & 63;
    const int lr = l & 15, lg = l >> 4;
    const int kw = (w >> 2) * 64;     // wave k-base
    const int bw = w & 3;             // wave b within group
    const int srow = tid >> 3;        // staging row base (0..63), +64 per p
    const int sc   = tid & 7;         // staging c-chunk (8 floats)

    float4 rv[4][2];
    #define G1LOAD(kt)                                                            \
        {                                                                         \
            _Pragma("unroll")                                                     \
            for (int p = 0; p < 4; ++p) {                                         \
                int row = srow + p * 64;          /* a_l*4 + b_l */               \
                const float* tr = T + ((size_t)(a0 + (row >> 2)) * 256            \
                                       + b0 + (row & 3)) * 256                    \
                                    + (kt) * 64 + sc * 8;                         \
                rv[p][0] = ((const float4*)tr)[0];                                \
                rv[p][1] = ((const float4*)tr)[1];                                \
            }                                                                     \
        }
    #define G1WRITE(buf)                                                          \
        {                                                                         \
            _Pragma("unroll")                                                     \
            for (int p = 0; p < 4; ++p) {                                         \
                int row = srow + p * 64;                                          \
                int al  = row >> 2;                                               \
                bf16x8 hv; unsigned short* hp = (unsigned short*)&hv;             \
                hp[0]=f2bf(rv[p][0].x); hp[1]=f2bf(rv[p][0].y);                   \
                hp[2]=f2bf(rv[p][0].z); hp[3]=f2bf(rv[p][0].w);                   \
                hp[4]=f2bf(rv[p][1].x); hp[5]=f2bf(rv[p][1].y);                   \
                hp[6]=f2bf(rv[p][1].z); hp[7]=f2bf(rv[p][1].w);                   \
                int bo = (row * 128 + sc * 16) ^ ((al & 7) << 4);                 \
                *(bf16x8*)((char*)Ts[buf] + bo) = hv;                             \
            }                                                                     \
        }

    f32x4 acc[4][4];
    #pragma unroll
    for (int mt = 0; mt < 4; ++mt)
        #pragma unroll
        for (int nt = 0; nt < 4; ++nt) acc[mt][nt] = (f32x4){0.f, 0.f, 0.f, 0.f};

    G1LOAD(0);
    G1WRITE(0);
    __syncthreads();

    int cur = 0;
    #pragma unroll 1
    for (int kt = 0; kt < 4; ++kt) {
        if (kt + 1 < 4) G1LOAD(kt + 1);

        #pragma unroll
        for (int ks = 0; ks < 2; ++ks) {
            bf16x8 af[4], bf[4];
            #pragma unroll
            for (int mt = 0; mt < 4; ++mt)
                af[mt] = *(const bf16x8*)(EeB + (kw + mt * 16 + lr) * H2 + kt * 64 + ks * 32 + lg * 8);
            #pragma unroll
            for (int nt = 0; nt < 4; ++nt) {
                int al = nt * 16 + lr;
                int bo = (al * 512 + bw * 128 + ks * 64 + lg * 16) ^ ((al & 7) << 4);
                bf[nt] = *(const bf16x8*)((const char*)Ts[cur] + bo);
            }
            #pragma unroll
            for (int mt = 0; mt < 4; ++mt)
                #pragma unroll
                for (int nt = 0; nt < 4; ++nt)
                    acc[mt][nt] = __builtin_amdgcn_mfma_f32_16x16x32_bf16(af[mt], bf[nt], acc[mt][nt], 0, 0, 0);
        }

        if (kt + 1 < 4) G1WRITE(cur ^ 1);
        __syncthreads();
        cur ^= 1;
    }
    #undef G1LOAD
    #undef G1WRITE

    #pragma unroll
    for (int mt = 0; mt < 4; ++mt)
        #pragma unroll
        for (int nt = 0; nt < 4; ++nt)
            #pragma unroll
            for (int r = 0; r < 4; ++r) {
                int k  = kw + mt * 16 + lg * 4 + r;
                int a_ = a0 + nt * 16 + lr;
                outp[(size_t)k * 65536 + (b0 + bw) * 256 + a_] = f2bf(acc[mt][nt][r]);
            }
}

// ---------------- gemm2 (both tensors, NT): out[k][i][bc] = sum_a Hx[i][a]*tmpT[k][bc][a] ----
__global__ __launch_bounds__(256)
void gemm2_mfma(const unsigned short* __restrict__ HeB, const unsigned short* __restrict__ TeB,
                const unsigned short* __restrict__ tmpT0, const unsigned short* __restrict__ tmpT1,
                unsigned short* __restrict__ hepB, unsigned short* __restrict__ tepB)
{
    const int bid = blockIdx.x;
    const int t  = bid >> 8;
    const int k  = (bid >> 1) & 127;
    const int nb0 = (bid & 1) * 128;
    const unsigned short* HxB = t ? TeB : HeB;
    const unsigned short* Bp  = (t ? tmpT1 : tmpT0) + (size_t)k * 65536;
    unsigned short* outB = t ? tepB : hepB;
    const int tid = threadIdx.x;
    const int w = tid >> 6, l = tid & 63;
    const int lr = l & 15, lg = l >> 4;
    const int bb = w * 32;

    f32x4 acc[8][2];
    #pragma unroll
    for (int mt = 0; mt < 8; ++mt)
        #pragma unroll
        for (int nt = 0; nt < 2; ++nt) acc[mt][nt] = (f32x4){0.f, 0.f, 0.f, 0.f};

    #pragma unroll 2
    for (int ks = 0; ks < 8; ++ks) {
        bf16x8 af[8], bf[2];
        #pragma unroll
        for (int mt = 0; mt < 8; ++mt)
            af[mt] = *(const bf16x8*)(HxB + (mt * 16 + lr) * H2 + ks * 32 + lg * 8);
        #pragma unroll
        for (int nt = 0; nt < 2; ++nt)
            bf[nt] = *(const bf16x8*)(Bp + (nb0 + bb + nt * 16 + lr) * H2 + ks * 32 + lg * 8);
        #pragma unroll
        for (int mt = 0; mt < 8; ++mt)
            #pragma unroll
            for (int nt = 0; nt < 2; ++nt)
                acc[mt][nt] = __builtin_amdgcn_mfma_f32_16x16x32_bf16(af[mt], bf[nt], acc[mt][nt], 0, 0, 0);
    }
    #pragma unroll
    for (int mt = 0; mt < 8; ++mt)
        #pragma unroll
        for (int nt = 0; nt < 2; ++nt)
            #pragma unroll
            for (int r = 0; r < 4; ++r) {
                int i = mt * 16 + lg * 4 + r;
                int bc = nb0 + bb + nt * 16 + lr;
                outB[(size_t)k * (NENT * H2) + i * H2 + bc] = f2bf(acc[mt][nt][r]);
            }
}

// ---------------- step3: block per (k, j-half); m-loop inside ----------------
__global__ __launch_bounds__(512)
void step3_mfma(const unsigned short* __restrict__ hepB,
                const unsigned short* __restrict__ tepB,
                const unsigned short* __restrict__ TclsB,
                float* __restrict__ predT)
{
    __shared__ unsigned short tepS[64 * 256];
    __shared__ unsigned short WS[64 * 256];
    const int lbid = (blockIdx.x & 7) * 32 + (blockIdx.x >> 3);
    const int k  = lbid >> 1;
    const int jh = lbid & 1;
    const int tid = threadIdx.x;
    const int w  = tid >> 6;
    const int l  = tid & 63;
    const int lr = l & 15;
    const int lg = l >> 4;
    const int swz = (lr & 7) << 4;

    {
        const unsigned short* tk = tepB + (size_t)k * (NENT * H2) + (size_t)jh * 64 * H2;
        int row = tid >> 5;
        int col = (tid & 31) * 8;
        #pragma unroll
        for (int q = 0; q < 4; ++q) {
            int r = row + q * 16;
            bf16x8 v = *(const bf16x8*)(tk + r * H2 + col);
            int byteoff = (((r << 8) + col) << 1) ^ ((r & 7) << 4);
            *(bf16x8*)((char*)tepS + byteoff) = v;
        }
    }

    bf16x8 ha[8];
    {
        const unsigned short* hk = hepB + (size_t)k * (NENT * H2);
        #pragma unroll
        for (int ks = 0; ks < 8; ++ks)
            ha[ks] = *(const bf16x8*)(hk + (w * 16 + lr) * H2 + ks * 32 + lg * 8);
    }
    __syncthreads();

    #pragma unroll 1
    for (int m = 0; m < NCLS; ++m) {
        {
            const unsigned short* tcm = TclsB + (size_t)m * (H2 * H2);
            f32x4 acc1[4][2];
            #pragma unroll
            for (int jt = 0; jt < 4; ++jt)
                #pragma unroll
                for (int ct = 0; ct < 2; ++ct) acc1[jt][ct] = (f32x4){0.f, 0.f, 0.f, 0.f};

            #pragma unroll
            for (int ks = 0; ks < 8; ++ks) {
                bf16x8 a[4], bb[2];
                #pragma unroll
                for (int jt = 0; jt < 4; ++jt) {
                    int byteoff = ((((jt * 16 + lr) << 8) + ks * 32 + lg * 8) << 1) ^ swz;
                    a[jt] = *(const bf16x8*)((const char*)tepS + byteoff);
                }
                #pragma unroll
                for (int ct = 0; ct < 2; ++ct)
                    bb[ct] = *(const bf16x8*)(tcm + (size_t)(w * 32 + ct * 16 + lr) * H2 + ks * 32 + lg * 8);
                #pragma unroll
                for (int jt = 0; jt < 4; ++jt)
                    #pragma unroll
                    for (int ct = 0; ct < 2; ++ct)
                        acc1[jt][ct] = __builtin_amdgcn_mfma_f32_16x16x32_bf16(a[jt], bb[ct], acc1[jt][ct], 0, 0, 0);
            }
            #pragma unroll
            for (int jt = 0; jt < 4; ++jt)
                #pragma unroll
                for (int ct = 0; ct < 2; ++ct)
                    #pragma unroll
                    for (int r = 0; r < 4; ++r) {
                        int j = jt * 16 + lg * 4 + r;
                        int c = w * 32 + ct * 16 + lr;
                        int byteoff = ((((j << 8) + c)) << 1) ^ ((j & 7) << 4);
                        *(unsigned short*)((char*)WS + byteoff) = f2bf(acc1[jt][ct][r]);
                    }
        }
        __syncthreads();

        {
            f32x4 acc2[4];
            #pragma unroll
            for (int jt = 0; jt < 4; ++jt) acc2[jt] = (f32x4){0.f, 0.f, 0.f, 0.f};

            #pragma unroll
            for (int ks = 0; ks < 8; ++ks) {
                #pragma unroll
                for (int jt = 0; jt < 4; ++jt) {
                    int byteoff = ((((jt * 16 + lr) << 8) + ks * 32 + lg * 8) << 1) ^ swz;
                    bf16x8 wb = *(const bf16x8*)((const char*)WS + byteoff);
                    acc2[jt] = __builtin_amdgcn_mfma_f32_16x16x32_bf16(ha[ks], wb, acc2[jt], 0, 0, 0);
                }
            }
            float* po = predT + (size_t)(k * NCLS + m) * (NENT * NENT);
            #pragma unroll
            for (int jt = 0; jt < 4; ++jt)
                #pragma unroll
                for (int r = 0; r < 4; ++r) {
                    int i = w * 16 + lg * 4 + r;
                    int j = jh * 64 + jt * 16 + lr;
                    po[i * NENT + j] = acc2[jt][r];
                }
        }
        __syncthreads();
    }
}

// ---------------- transpose: predT[km][ij] -> out[ij][km] ----------------
__global__ __launch_bounds__(256)
void transpose_out(const float* __restrict__ predT, float* __restrict__ out)
{
    __shared__ float Ls[160][33];
    const int bid = blockIdx.x;
    const int ij0 = (bid >> 2) * 32;
    const int km0 = (bid & 3) * 160;
    const int t = threadIdx.x;

    #pragma unroll
    for (int q = 0; q < 20; ++q) {
        int r = (t >> 5) + q * 8;
        int c = t & 31;
        Ls[r][c] = predT[(size_t)(km0 + r) * 16384 + ij0 + c];
    }
    __syncthreads();
    for (int idx = t; idx < 32 * 160; idx += 256) {
        int r = idx / 160, c = idx % 160;
        out[(size_t)(ij0 + r) * 640 + km0 + c] = Ls[c][r];
    }
}

extern "C" void kernel_launch(void* const* d_in, const int* in_sizes, int n_in,
                              void* d_out, int out_size, void* d_ws, size_t ws_size,
                              hipStream_t stream)
{
    (void)in_sizes; (void)n_in; (void)out_size; (void)ws_size;
    const float* enc  = (const float*)d_in[0];
    const int*   hidx = (const int*)d_in[1];
    const int*   tidx = (const int*)d_in[2];
    const int*   eidx = (const int*)d_in[3];
    const float* Whf = (const float*)d_in[4];
    const float* bhf = (const float*)d_in[5];
    const float* Whb = (const float*)d_in[6];
    const float* bhb = (const float*)d_in[7];
    const float* Wtf = (const float*)d_in[8];
    const float* btf = (const float*)d_in[9];
    const float* Wtb = (const float*)d_in[10];
    const float* btb = (const float*)d_in[11];
    const float* Wef = (const float*)d_in[12];
    const float* bef = (const float*)d_in[13];
    const float* Web = (const float*)d_in[14];
    const float* beb = (const float*)d_in[15];
    const float* T_he  = (const float*)d_in[16];
    const float* T_te  = (const float*)d_in[17];
    const float* T_cls = (const float*)d_in[18];

    float* out = (float*)d_out;
    char*  ws  = (char*)d_ws;
    unsigned short* poolB = (unsigned short*)(ws + POOLB_OFF);
    unsigned short* hepB  = (unsigned short*)(ws + HEPB_OFF);
    unsigned short* tepB  = (unsigned short*)(ws + TEPB_OFF);
    unsigned short* TclsB = (unsigned short*)(ws + TCLSB_OFF);
    unsigned short* WB    = (unsigned short*)(ws + WB_OFF);
    unsigned short* tokB  = (unsigned short*)(ws + TOKB_OFF);
    float*          gates = (float*)(ws + GATES_OFF);
    unsigned short* tmpT0 = (unsigned short*)(ws + TMPT0_OFF);
    unsigned short* tmpT1 = (unsigned short*)(ws + TMPT1_OFF);
    float*          predT = (float*)(ws + PREDT_OFF);

    unsigned short* HeB = poolB;
    unsigned short* TeB = poolB + 1 * NENT * H2;
    unsigned short* EeB = poolB + 2 * NENT * H2;

    prep_kernel<<<7616, 256, 0, stream>>>(Whf, Whb, Wtf, Wtb, Wef, Web,
                                          T_cls, enc, hidx, tidx, eidx,
                                          WB, TclsB, tokB);

    gates_mfma<<<288, 256, 0, stream>>>(tokB, WB, gates);

    pool_epilogue<<<384, 256, 0, stream>>>(gates, bhf, bhb, btf, btb, bef, beb, poolB);

    gemm1_mfma<<<512, 512, 0, stream>>>(EeB, T_he, T_te, tmpT0, tmpT1);

    gemm2_mfma<<<512, 256, 0, stream>>>(HeB, TeB, tmpT0, tmpT1, hepB, tepB);

    step3_mfma<<<256, 512, 0, stream>>>(hepB, tepB, TclsB, predT);

    transpose_out<<<2048, 256, 0, stream>>>(predT, out);
}

// Round 10
// 135.709 us; speedup vs baseline: 8.8662x; 1.1306x over previous
//
#include <hip/hip_runtime.h>
#include <hip/hip_bf16.h>
#include <math.h>

#define DIM   768
#define HID   128
#define H2    256
#define NENT  128
#define SPAN  16
#define NCLS  5

// ---- ws layout (bytes) ----
// poolB bf16 [3][128][256]              @ 0          (196,608)
// hepN  bf16 [beta 256][k 128][i 128]   @ 196608     (8,388,608)
// tepN  bf16 [b 256][k 128][j 128]      @ 8585216    (8,388,608)
// TclsB bf16 [m][c][b]                  @ 16973824   (655,360)
// WB    bf16 [3][768][768]              @ 17629184   (3,538,944)
// tokB  bf16 [3][2048][768]             @ 21168128   (9,437,184)   dead after gates
// gates fp32 [3][2048][768]             @ 30605312   (18,874,368)  dead after epilogue
// predT fp32 [k*5+m][i][j]              @ 21168128   (41,943,040)  overlaps tokB/gates
// max end = 63,111,168 B (ws >= 67.5 MB proven in round 1)
#define POOLB_OFF 0
#define HEPB_OFF  196608
#define TEPB_OFF  (HEPB_OFF + 8388608)
#define TCLSB_OFF (TEPB_OFF + 8388608)
#define WB_OFF    (TCLSB_OFF + 655360)
#define TOKB_OFF  21168128
#define GATES_OFF (TOKB_OFF + 9437184)
#define PREDT_OFF 21168128

typedef __attribute__((ext_vector_type(8))) short bf16x8;
typedef __attribute__((ext_vector_type(4))) float f32x4;

__device__ __forceinline__ float sigmoidf_(float x) { return 1.0f / (1.0f + __expf(-x)); }

__device__ __forceinline__ unsigned short f2bf(float x) {
    __hip_bfloat16 h = __float2bfloat16(x);
    return *reinterpret_cast<unsigned short*>(&h);
}

// ---------------- prep: wconv + conv_tcls + gather_toks fused ----------------
__global__ __launch_bounds__(256)
void prep_kernel(const float* __restrict__ Whf, const float* __restrict__ Whb,
                 const float* __restrict__ Wtf, const float* __restrict__ Wtb,
                 const float* __restrict__ Wef, const float* __restrict__ Web,
                 const float* __restrict__ Tcls, const float* __restrict__ enc,
                 const int* __restrict__ idx_h, const int* __restrict__ idx_t,
                 const int* __restrict__ idx_e,
                 unsigned short* __restrict__ WB, unsigned short* __restrict__ TB,
                 unsigned short* __restrict__ tokB)
{
    const int bb = blockIdx.x;
    const int tid = threadIdx.x;
    if (bb < 1728) {
        int gid = bb * 256 + tid;                        // < 442368
        int t2  = gid / 73728;
        int rem = gid % 73728;
        int n   = rem / 192;
        int c4  = rem % 192;
        int gate = n >> 7, j = n & 127;
        int srow = (gate == 0) ? j : (gate == 1) ? 256 + j : 384 + j;
        const float* W = (t2 == 0) ? Whf : (t2 == 1) ? Whb : (t2 == 2) ? Wtf :
                         (t2 == 3) ? Wtb : (t2 == 4) ? Wef : Web;
        float4 v = ((const float4*)(W + srow * DIM))[c4];
        unsigned short* d = WB + ((size_t)(t2 * 384 + n)) * DIM + c4 * 4;
        d[0] = f2bf(v.x); d[1] = f2bf(v.y); d[2] = f2bf(v.z); d[3] = f2bf(v.w);
    } else if (bb < 3008) {
        int idx = (bb - 1728) * 256 + tid;               // < 327680
        int b = idx / (NCLS * H2);
        int r = idx % (NCLS * H2);
        int m = r >> 8, c = r & 255;
        TB[((m << 8) + c) * H2 + b] = f2bf(Tcls[idx]);
    } else {
        int gid = (bb - 3008) * 256 + tid;               // < 6144*192
        int r  = gid / 192, c4 = gid % 192;
        int type = r >> 11;
        int rem  = r & 2047;
        const int* idx = (type == 0) ? idx_h : (type == 1) ? idx_t : idx_e;
        int row = idx[rem];
        float4 v = ((const float4*)(enc + (size_t)row * DIM))[c4];
        unsigned short h4[4] = { f2bf(v.x), f2bf(v.y), f2bf(v.z), f2bf(v.w) };
        *(uint2*)(tokB + (size_t)r * DIM + c4 * 4) = *(uint2*)h4;
    }
}

// ---------------- gates GEMM (NT), LDS-staged 2-phase double-buffer ----------------
__global__ __launch_bounds__(256)
void gates_mfma(const unsigned short* __restrict__ tokB,
                const unsigned short* __restrict__ WB,
                float* __restrict__ gates)
{
    __shared__ unsigned short As[2][128 * 64];
    __shared__ unsigned short Bs[2][128 * 64];
    const int lbid = ((int)blockIdx.x & 7) * 36 + ((int)blockIdx.x >> 3);  // bijective
    const int type = lbid / 96;
    const int rem  = lbid % 96;
    const int mb0  = (rem / 6) * 128;
    const int nb0  = (rem % 6) * 128;
    const int tid = threadIdx.x;
    const int w = tid >> 6, l = tid & 63;
    const int lr = l & 15, lg = l >> 4;
    const unsigned short* A = tokB + (size_t)type * 2048 * DIM + (size_t)mb0 * DIM;
    const unsigned short* B = WB   + (size_t)type * 768  * DIM + (size_t)nb0 * DIM;

    const int sr0 = tid >> 3;
    const int sc  = tid & 7;

    bf16x8 ra[4], rb[4];
    #define LOADT(kt)                                                        \
        {                                                                    \
            const int koff = (kt) * 64 + sc * 8;                             \
            _Pragma("unroll")                                                \
            for (int p = 0; p < 4; ++p) {                                    \
                int rr = sr0 + p * 32;                                       \
                ra[p] = *(const bf16x8*)(A + (size_t)rr * DIM + koff);       \
                rb[p] = *(const bf16x8*)(B + (size_t)rr * DIM + koff);       \
            }                                                                \
        }
    #define WRITET(buf)                                                      \
        {                                                                    \
            _Pragma("unroll")                                                \
            for (int p = 0; p < 4; ++p) {                                    \
                int rr = sr0 + p * 32;                                       \
                int bo = (rr * 128 + sc * 16) ^ ((rr & 7) << 4);             \
                *(bf16x8*)((char*)As[buf] + bo) = ra[p];                     \
                *(bf16x8*)((char*)Bs[buf] + bo) = rb[p];                     \
            }                                                                \
        }

    f32x4 acc[4][4];
    #pragma unroll
    for (int mt = 0; mt < 4; ++mt)
        #pragma unroll
        for (int nt = 0; nt < 4; ++nt) acc[mt][nt] = (f32x4){0.f, 0.f, 0.f, 0.f};

    const int am0 = (w & 1) * 64;
    const int bn0 = (w >> 1) * 64;

    LOADT(0);
    WRITET(0);
    __syncthreads();

    int cur = 0;
    #pragma unroll 1
    for (int kt = 0; kt < 12; ++kt) {
        if (kt + 1 < 12) LOADT(kt + 1);

        #pragma unroll
        for (int ks = 0; ks < 2; ++ks) {
            bf16x8 af[4], bf[4];
            #pragma unroll
            for (int mt = 0; mt < 4; ++mt) {
                int rr = am0 + mt * 16 + lr;
                int bo = (rr * 128 + ks * 64 + lg * 16) ^ ((rr & 7) << 4);
                af[mt] = *(const bf16x8*)((const char*)As[cur] + bo);
            }
            #pragma unroll
            for (int nt = 0; nt < 4; ++nt) {
                int rr = bn0 + nt * 16 + lr;
                int bo = (rr * 128 + ks * 64 + lg * 16) ^ ((rr & 7) << 4);
                bf[nt] = *(const bf16x8*)((const char*)Bs[cur] + bo);
            }
            #pragma unroll
            for (int mt = 0; mt < 4; ++mt)
                #pragma unroll
                for (int nt = 0; nt < 4; ++nt)
                    acc[mt][nt] = __builtin_amdgcn_mfma_f32_16x16x32_bf16(af[mt], bf[nt], acc[mt][nt], 0, 0, 0);
        }

        if (kt + 1 < 12) {
            WRITET(cur ^ 1);
        }
        __syncthreads();
        cur ^= 1;
    }
    #undef LOADT
    #undef WRITET

    float* C = gates + (size_t)type * 2048 * 768 + (size_t)mb0 * 768 + nb0;
    #pragma unroll
    for (int mt = 0; mt < 4; ++mt)
        #pragma unroll
        for (int nt = 0; nt < 4; ++nt)
            #pragma unroll
            for (int r = 0; r < 4; ++r)
                C[(size_t)(am0 + mt * 16 + lg * 4 + r) * 768 + bn0 + nt * 16 + lr] = acc[mt][nt][r];
}

// ---------------- pool epilogue ----------------
__global__ __launch_bounds__(256)
void pool_epilogue(const float* __restrict__ gates,
                   const float* __restrict__ bhf, const float* __restrict__ bhb,
                   const float* __restrict__ btf, const float* __restrict__ btb,
                   const float* __restrict__ bef, const float* __restrict__ beb,
                   unsigned short* __restrict__ poolB)
{
    const int type = blockIdx.x >> 7;
    const int ent  = blockIdx.x & 127;
    const int tid  = threadIdx.x;
    const int dir  = tid >> 7;
    const int j    = tid & 127;
    const float* Bv = (type == 0) ? (dir ? bhb : bhf)
                    : (type == 1) ? (dir ? btb : btf)
                                  : (dir ? beb : bef);
    const float bi = Bv[j], bg = Bv[2 * HID + j], bo = Bv[3 * HID + j];
    const float* g0 = gates + ((size_t)type * 2048 + ent * 16) * 768 + dir * 384 + j;
    float hmax = -1e30f;
    #pragma unroll
    for (int l = 0; l < SPAN; ++l) {
        const float* gr = g0 + l * 768;
        float iv = sigmoidf_(gr[0]   + bi);
        float gv = tanhf(   gr[128] + bg);
        float ov = sigmoidf_(gr[256] + bo);
        hmax = fmaxf(hmax, ov * tanhf(iv * gv));
    }
    poolB[(size_t)(type * NENT + ent) * H2 + dir * HID + j] = f2bf(hmax);
}

// ---------------- pair: fused gemm1+gemm2, no tmpT ----------------
// block = (t, beta): W[a][k] = sum_c T_t[a][beta][c]*Ee[k][c]; out[beta][k][i] = sum_a W[a][k]*Hx[i][a]
// grid 512; 512 thr = 8 waves. LDS 128 KB: slabS bf16[256a][256c] swz; WT bf16[128k][256a] swz reuses first 64 KB.
__global__ __launch_bounds__(512)
void pair_mfma(const unsigned short* __restrict__ EeB,
               const unsigned short* __restrict__ HeB,
               const unsigned short* __restrict__ TeB,
               const float* __restrict__ T0, const float* __restrict__ T1,
               unsigned short* __restrict__ hepN,   // [256][128][128]
               unsigned short* __restrict__ tepN)
{
    __shared__ __align__(16) char smem[131072];
    const int bid = blockIdx.x;
    const int t = bid >> 8;
    const int b = bid & 255;
    const float* T = t ? T1 : T0;
    const unsigned short* Hx = t ? TeB : HeB;
    unsigned short* outp = t ? tepN : hepN;
    const int tid = threadIdx.x;
    const int w = tid >> 6, l = tid & 63;
    const int lr = l & 15, lg = l >> 4;

    // ---- stage T[:,b,:] fp32 -> slabS bf16 swz (one long per-lane-sequential burst)
    {
        const int a    = tid >> 1;
        const int chalf = (tid & 1) * 128;
        const float* src = T + ((size_t)a * 256 + b) * 256 + chalf;
        #pragma unroll 8
        for (int f = 0; f < 32; ++f) {
            float4 v = ((const float4*)src)[f];
            unsigned short h4[4] = { f2bf(v.x), f2bf(v.y), f2bf(v.z), f2bf(v.w) };
            int c = chalf + f * 4;
            int bo = (a * 512 + c * 2) ^ ((a & 7) << 4);
            *(uint2*)(smem + bo) = *(uint2*)h4;
        }
    }
    __syncthreads();

    // ---- P1: acc1[a-frag][k-frag]; waves (aw = w&3, kw = w>>2)
    {
        const int aw = (w & 3) * 64;
        const int kw = (w >> 2) * 64;
        f32x4 acc1[4][4];
        #pragma unroll
        for (int mt = 0; mt < 4; ++mt)
            #pragma unroll
            for (int nt = 0; nt < 4; ++nt) acc1[mt][nt] = (f32x4){0.f, 0.f, 0.f, 0.f};

        #pragma unroll
        for (int ks = 0; ks < 8; ++ks) {
            bf16x8 af[4], bf[4];
            #pragma unroll
            for (int mt = 0; mt < 4; ++mt) {
                int ar = aw + mt * 16 + lr;
                int bo = (ar * 512 + (ks * 32 + lg * 8) * 2) ^ ((ar & 7) << 4);
                af[mt] = *(const bf16x8*)(smem + bo);
            }
            #pragma unroll
            for (int nt = 0; nt < 4; ++nt)
                bf[nt] = *(const bf16x8*)(EeB + (kw + nt * 16 + lr) * H2 + ks * 32 + lg * 8);
            #pragma unroll
            for (int mt = 0; mt < 4; ++mt)
                #pragma unroll
                for (int nt = 0; nt < 4; ++nt)
                    acc1[mt][nt] = __builtin_amdgcn_mfma_f32_16x16x32_bf16(af[mt], bf[nt], acc1[mt][nt], 0, 0, 0);
        }
        __syncthreads();   // slab fully consumed

        // write WT[k][a] bf16 swz into smem[0:64K]
        #pragma unroll
        for (int mt = 0; mt < 4; ++mt)
            #pragma unroll
            for (int nt = 0; nt < 4; ++nt) {
                int k  = kw + nt * 16 + lr;
                int a0 = aw + mt * 16 + lg * 4;
                unsigned short h4[4] = { f2bf(acc1[mt][nt][0]), f2bf(acc1[mt][nt][1]),
                                         f2bf(acc1[mt][nt][2]), f2bf(acc1[mt][nt][3]) };
                int bo = (k * 512 + a0 * 2) ^ ((k & 7) << 4);
                *(uint2*)(smem + bo) = *(uint2*)h4;
            }
    }
    __syncthreads();

    // ---- P2: out[b][k][i]; waves (kw2 = w&1, iw = w>>1)
    {
        const int kw2 = (w & 1) * 64;
        const int iw  = (w >> 1) * 32;
        f32x4 acc2[4][2];
        #pragma unroll
        for (int mt = 0; mt < 4; ++mt)
            #pragma unroll
            for (int nt = 0; nt < 2; ++nt) acc2[mt][nt] = (f32x4){0.f, 0.f, 0.f, 0.f};

        #pragma unroll
        for (int ks = 0; ks < 8; ++ks) {
            bf16x8 af[4], bf[2];
            #pragma unroll
            for (int mt = 0; mt < 4; ++mt) {
                int kr = kw2 + mt * 16 + lr;
                int bo = (kr * 512 + (ks * 32 + lg * 8) * 2) ^ ((kr & 7) << 4);
                af[mt] = *(const bf16x8*)(smem + bo);
            }
            #pragma unroll
            for (int nt = 0; nt < 2; ++nt)
                bf[nt] = *(const bf16x8*)(Hx + (iw + nt * 16 + lr) * H2 + ks * 32 + lg * 8);
            #pragma unroll
            for (int mt = 0; mt < 4; ++mt)
                #pragma unroll
                for (int nt = 0; nt < 2; ++nt)
                    acc2[mt][nt] = __builtin_amdgcn_mfma_f32_16x16x32_bf16(af[mt], bf[nt], acc2[mt][nt], 0, 0, 0);
        }
        unsigned short* po = outp + (size_t)b * (128 * 128);
        #pragma unroll
        for (int mt = 0; mt < 4; ++mt)
            #pragma unroll
            for (int nt = 0; nt < 2; ++nt)
                #pragma unroll
                for (int r = 0; r < 4; ++r) {
                    int k = kw2 + mt * 16 + lg * 4 + r;
                    int i = iw + nt * 16 + lr;
                    po[k * 128 + i] = f2bf(acc2[mt][nt][r]);
                }
    }
}

// ---------------- step3: block per (k, j-half); m-loop inside ----------------
// hep/tep now [beta/b][k][row] -> transpose-staged into swizzled LDS.
__global__ __launch_bounds__(512)
void step3_mfma(const unsigned short* __restrict__ hepN,  // [256 beta][128 k][128 i]
                const unsigned short* __restrict__ tepN,  // [256 b][128 k][128 j]
                const unsigned short* __restrict__ TclsB, // [m][c][b]
                float* __restrict__ predT)
{
    __shared__ unsigned short hepS[128 * 256];  // [i][beta] swz, 64 KB
    __shared__ unsigned short tepS[64 * 256];   // [j][b] swz, 32 KB
    __shared__ unsigned short WS[64 * 256];     // [j][c] swz, 32 KB
    const int lbid = (blockIdx.x & 7) * 32 + (blockIdx.x >> 3);
    const int k  = lbid >> 1;
    const int jh = lbid & 1;
    const int tid = threadIdx.x;
    const int w  = tid >> 6;
    const int l  = tid & 63;
    const int lr = l & 15;
    const int lg = l >> 4;
    const int swz = (lr & 7) << 4;

    // ---- stage tepS[j][b]: wave w owns j-chunk w*8..+8; lanes = b (contiguous LDS writes)
    #pragma unroll
    for (int q = 0; q < 4; ++q) {
        int bcol = q * 64 + l;
        bf16x8 v = *(const bf16x8*)(tepN + ((size_t)bcol * 128 + k) * 128 + jh * 64 + w * 8);
        #pragma unroll
        for (int r = 0; r < 8; ++r) {
            int j = w * 8 + r;                   // j&7 == r
            int bo = (j * 512 + bcol * 2) ^ (r << 4);
            *(unsigned short*)((char*)tepS + bo) = ((unsigned short*)&v)[r];
        }
    }
    // ---- stage hepS[i][beta]: wave w owns i-chunks w*16 and w*16+8
    #pragma unroll
    for (int s = 0; s < 2; ++s)
        #pragma unroll
        for (int q = 0; q < 4; ++q) {
            int bcol = q * 64 + l;
            bf16x8 v = *(const bf16x8*)(hepN + ((size_t)bcol * 128 + k) * 128 + w * 16 + s * 8);
            #pragma unroll
            for (int r = 0; r < 8; ++r) {
                int i = w * 16 + s * 8 + r;      // i&7 == r
                int bo = (i * 512 + bcol * 2) ^ (r << 4);
                *(unsigned short*)((char*)hepS + bo) = ((unsigned short*)&v)[r];
            }
        }
    __syncthreads();

    // ---- preload ha frags (wave w owns i-tile w*16, reused for all m)
    bf16x8 ha[8];
    #pragma unroll
    for (int ks = 0; ks < 8; ++ks) {
        int ir = w * 16 + lr;
        int bo = (ir * 512 + (ks * 32 + lg * 8) * 2) ^ ((ir & 7) << 4);
        ha[ks] = *(const bf16x8*)((const char*)hepS + bo);
    }

    #pragma unroll 1
    for (int m = 0; m < NCLS; ++m) {
        {
            const unsigned short* tcm = TclsB + (size_t)m * (H2 * H2);
            f32x4 acc1[4][2];
            #pragma unroll
            for (int jt = 0; jt < 4; ++jt)
                #pragma unroll
                for (int ct = 0; ct < 2; ++ct) acc1[jt][ct] = (f32x4){0.f, 0.f, 0.f, 0.f};

            #pragma unroll
            for (int ks = 0; ks < 8; ++ks) {
                bf16x8 a[4], bb[2];
                #pragma unroll
                for (int jt = 0; jt < 4; ++jt) {
                    int byteoff = ((((jt * 16 + lr) << 8) + ks * 32 + lg * 8) << 1) ^ swz;
                    a[jt] = *(const bf16x8*)((const char*)tepS + byteoff);
                }
                #pragma unroll
                for (int ct = 0; ct < 2; ++ct)
                    bb[ct] = *(const bf16x8*)(tcm + (size_t)(w * 32 + ct * 16 + lr) * H2 + ks * 32 + lg * 8);
                #pragma unroll
                for (int jt = 0; jt < 4; ++jt)
                    #pragma unroll
                    for (int ct = 0; ct < 2; ++ct)
                        acc1[jt][ct] = __builtin_amdgcn_mfma_f32_16x16x32_bf16(a[jt], bb[ct], acc1[jt][ct], 0, 0, 0);
            }
            #pragma unroll
            for (int jt = 0; jt < 4; ++jt)
                #pragma unroll
                for (int ct = 0; ct < 2; ++ct)
                    #pragma unroll
                    for (int r = 0; r < 4; ++r) {
                        int j = jt * 16 + lg * 4 + r;
                        int c = w * 32 + ct * 16 + lr;
                        int byteoff = ((((j << 8) + c)) << 1) ^ ((j & 7) << 4);
                        *(unsigned short*)((char*)WS + byteoff) = f2bf(acc1[jt][ct][r]);
                    }
        }
        __syncthreads();

        {
            f32x4 acc2[4];
            #pragma unroll
            for (int jt = 0; jt < 4; ++jt) acc2[jt] = (f32x4){0.f, 0.f, 0.f, 0.f};

            #pragma unroll
            for (int ks = 0; ks < 8; ++ks) {
                #pragma unroll
                for (int jt = 0; jt < 4; ++jt) {
                    int byteoff = ((((jt * 16 + lr) << 8) + ks * 32 + lg * 8) << 1) ^ swz;
                    bf16x8 wb = *(const bf16x8*)((const char*)WS + byteoff);
                    acc2[jt] = __builtin_amdgcn_mfma_f32_16x16x32_bf16(ha[ks], wb, acc2[jt], 0, 0, 0);
                }
            }
            float* po = predT + (size_t)(k * NCLS + m) * (NENT * NENT);
            #pragma unroll
            for (int jt = 0; jt < 4; ++jt)
                #pragma unroll
                for (int r = 0; r < 4; ++r) {
                    int i = w * 16 + lg * 4 + r;
                    int j = jh * 64 + jt * 16 + lr;
                    po[i * NENT + j] = acc2[jt][r];
                }
        }
        __syncthreads();
    }
}

// ---------------- transpose: predT[km][ij] -> out[ij][km] ----------------
__global__ __launch_bounds__(256)
void transpose_out(const float* __restrict__ predT, float* __restrict__ out)
{
    __shared__ float Ls[160][33];
    const int bid = blockIdx.x;
    const int ij0 = (bid >> 2) * 32;
    const int km0 = (bid & 3) * 160;
    const int t = threadIdx.x;

    #pragma unroll
    for (int q = 0; q < 20; ++q) {
        int r = (t >> 5) + q * 8;
        int c = t & 31;
        Ls[r][c] = predT[(size_t)(km0 + r) * 16384 + ij0 + c];
    }
    __syncthreads();
    for (int idx = t; idx < 32 * 160; idx += 256) {
        int r = idx / 160, c = idx % 160;
        out[(size_t)(ij0 + r) * 640 + km0 + c] = Ls[c][r];
    }
}

extern "C" void kernel_launch(void* const* d_in, const int* in_sizes, int n_in,
                              void* d_out, int out_size, void* d_ws, size_t ws_size,
                              hipStream_t stream)
{
    (void)in_sizes; (void)n_in; (void)out_size; (void)ws_size;
    const float* enc  = (const float*)d_in[0];
    const int*   hidx = (const int*)d_in[1];
    const int*   tidx = (const int*)d_in[2];
    const int*   eidx = (const int*)d_in[3];
    const float* Whf = (const float*)d_in[4];
    const float* bhf = (const float*)d_in[5];
    const float* Whb = (const float*)d_in[6];
    const float* bhb = (const float*)d_in[7];
    const float* Wtf = (const float*)d_in[8];
    const float* btf = (const float*)d_in[9];
    const float* Wtb = (const float*)d_in[10];
    const float* btb = (const float*)d_in[11];
    const float* Wef = (const float*)d_in[12];
    const float* bef = (const float*)d_in[13];
    const float* Web = (const float*)d_in[14];
    const float* beb = (const float*)d_in[15];
    const float* T_he  = (const float*)d_in[16];
    const float* T_te  = (const float*)d_in[17];
    const float* T_cls = (const float*)d_in[18];

    float* out = (float*)d_out;
    char*  ws  = (char*)d_ws;
    unsigned short* poolB = (unsigned short*)(ws + POOLB_OFF);
    unsigned short* hepN  = (unsigned short*)(ws + HEPB_OFF);
    unsigned short* tepN  = (unsigned short*)(ws + TEPB_OFF);
    unsigned short* TclsB = (unsigned short*)(ws + TCLSB_OFF);
    unsigned short* WB    = (unsigned short*)(ws + WB_OFF);
    unsigned short* tokB  = (unsigned short*)(ws + TOKB_OFF);
    float*          gates = (float*)(ws + GATES_OFF);
    float*          predT = (float*)(ws + PREDT_OFF);

    unsigned short* HeB = poolB;
    unsigned short* TeB = poolB + 1 * NENT * H2;
    unsigned short* EeB = poolB + 2 * NENT * H2;

    prep_kernel<<<7616, 256, 0, stream>>>(Whf, Whb, Wtf, Wtb, Wef, Web,
                                          T_cls, enc, hidx, tidx, eidx,
                                          WB, TclsB, tokB);

    gates_mfma<<<288, 256, 0, stream>>>(tokB, WB, gates);

    pool_epilogue<<<384, 256, 0, stream>>>(gates, bhf, bhb, btf, btb, bef, beb, poolB);

    pair_mfma<<<512, 512, 0, stream>>>(EeB, HeB, TeB, T_he, T_te, hepN, tepN);

    step3_mfma<<<256, 512, 0, stream>>>(hepN, tepN, TclsB, predT);

    transpose_out<<<2048, 256, 0, stream>>>(predT, out);
}

// Round 11
// 134.849 us; speedup vs baseline: 8.9228x; 1.0064x over previous
//
#include <hip/hip_runtime.h>
#include <hip/hip_bf16.h>
#include <math.h>

#define DIM   768
#define HID   128
#define H2    256
#define NENT  128
#define SPAN  16
#define NCLS  5

// ---- ws layout (bytes) ----
#define POOLB_OFF 0
#define HEPB_OFF  196608
#define TEPB_OFF  (HEPB_OFF + 8388608)
#define TCLSB_OFF (TEPB_OFF + 8388608)
#define WB_OFF    (TCLSB_OFF + 655360)
#define TOKB_OFF  21168128
#define GATES_OFF (TOKB_OFF + 9437184)
#define PREDT_OFF 21168128

typedef __attribute__((ext_vector_type(8))) short bf16x8;
typedef __attribute__((ext_vector_type(4))) float f32x4;

__device__ __forceinline__ float sigmoidf_(float x) { return 1.0f / (1.0f + __expf(-x)); }

__device__ __forceinline__ unsigned short f2bf(float x) {
    __hip_bfloat16 h = __float2bfloat16(x);
    return *reinterpret_cast<unsigned short*>(&h);
}

// ---------------- prep: wconv + conv_tcls + gather_toks fused ----------------
__global__ __launch_bounds__(256)
void prep_kernel(const float* __restrict__ Whf, const float* __restrict__ Whb,
                 const float* __restrict__ Wtf, const float* __restrict__ Wtb,
                 const float* __restrict__ Wef, const float* __restrict__ Web,
                 const float* __restrict__ Tcls, const float* __restrict__ enc,
                 const int* __restrict__ idx_h, const int* __restrict__ idx_t,
                 const int* __restrict__ idx_e,
                 unsigned short* __restrict__ WB, unsigned short* __restrict__ TB,
                 unsigned short* __restrict__ tokB)
{
    const int bb = blockIdx.x;
    const int tid = threadIdx.x;
    if (bb < 1728) {
        int gid = bb * 256 + tid;                        // < 442368
        int t2  = gid / 73728;
        int rem = gid % 73728;
        int n   = rem / 192;
        int c4  = rem % 192;
        int gate = n >> 7, j = n & 127;
        int srow = (gate == 0) ? j : (gate == 1) ? 256 + j : 384 + j;
        const float* W = (t2 == 0) ? Whf : (t2 == 1) ? Whb : (t2 == 2) ? Wtf :
                         (t2 == 3) ? Wtb : (t2 == 4) ? Wef : Web;
        float4 v = ((const float4*)(W + srow * DIM))[c4];
        unsigned short* d = WB + ((size_t)(t2 * 384 + n)) * DIM + c4 * 4;
        d[0] = f2bf(v.x); d[1] = f2bf(v.y); d[2] = f2bf(v.z); d[3] = f2bf(v.w);
    } else if (bb < 3008) {
        int idx = (bb - 1728) * 256 + tid;               // < 327680
        int b = idx / (NCLS * H2);
        int r = idx % (NCLS * H2);
        int m = r >> 8, c = r & 255;
        TB[((m << 8) + c) * H2 + b] = f2bf(Tcls[idx]);
    } else {
        int gid = (bb - 3008) * 256 + tid;               // < 6144*192
        int r  = gid / 192, c4 = gid % 192;
        int type = r >> 11;
        int rem  = r & 2047;
        const int* idx = (type == 0) ? idx_h : (type == 1) ? idx_t : idx_e;
        int row = idx[rem];
        float4 v = ((const float4*)(enc + (size_t)row * DIM))[c4];
        unsigned short h4[4] = { f2bf(v.x), f2bf(v.y), f2bf(v.z), f2bf(v.w) };
        *(uint2*)(tokB + (size_t)r * DIM + c4 * 4) = *(uint2*)h4;
    }
}

// ---------------- gates GEMM (NT), LDS-staged 2-phase double-buffer ----------------
__global__ __launch_bounds__(256)
void gates_mfma(const unsigned short* __restrict__ tokB,
                const unsigned short* __restrict__ WB,
                float* __restrict__ gates)
{
    __shared__ unsigned short As[2][128 * 64];
    __shared__ unsigned short Bs[2][128 * 64];
    const int lbid = ((int)blockIdx.x & 7) * 36 + ((int)blockIdx.x >> 3);  // bijective
    const int type = lbid / 96;
    const int rem  = lbid % 96;
    const int mb0  = (rem / 6) * 128;
    const int nb0  = (rem % 6) * 128;
    const int tid = threadIdx.x;
    const int w = tid >> 6, l = tid & 63;
    const int lr = l & 15, lg = l >> 4;
    const unsigned short* A = tokB + (size_t)type * 2048 * DIM + (size_t)mb0 * DIM;
    const unsigned short* B = WB   + (size_t)type * 768  * DIM + (size_t)nb0 * DIM;

    const int sr0 = tid >> 3;
    const int sc  = tid & 7;

    bf16x8 ra[4], rb[4];
    #define LOADT(kt)                                                        \
        {                                                                    \
            const int koff = (kt) * 64 + sc * 8;                             \
            _Pragma("unroll")                                                \
            for (int p = 0; p < 4; ++p) {                                    \
                int rr = sr0 + p * 32;                                       \
                ra[p] = *(const bf16x8*)(A + (size_t)rr * DIM + koff);       \
                rb[p] = *(const bf16x8*)(B + (size_t)rr * DIM + koff);       \
            }                                                                \
        }
    #define WRITET(buf)                                                      \
        {                                                                    \
            _Pragma("unroll")                                                \
            for (int p = 0; p < 4; ++p) {                                    \
                int rr = sr0 + p * 32;                                       \
                int bo = (rr * 128 + sc * 16) ^ ((rr & 7) << 4);             \
                *(bf16x8*)((char*)As[buf] + bo) = ra[p];                     \
                *(bf16x8*)((char*)Bs[buf] + bo) = rb[p];                     \
            }                                                                \
        }

    f32x4 acc[4][4];
    #pragma unroll
    for (int mt = 0; mt < 4; ++mt)
        #pragma unroll
        for (int nt = 0; nt < 4; ++nt) acc[mt][nt] = (f32x4){0.f, 0.f, 0.f, 0.f};

    const int am0 = (w & 1) * 64;
    const int bn0 = (w >> 1) * 64;

    LOADT(0);
    WRITET(0);
    __syncthreads();

    int cur = 0;
    #pragma unroll 1
    for (int kt = 0; kt < 12; ++kt) {
        if (kt + 1 < 12) LOADT(kt + 1);

        #pragma unroll
        for (int ks = 0; ks < 2; ++ks) {
            bf16x8 af[4], bf[4];
            #pragma unroll
            for (int mt = 0; mt < 4; ++mt) {
                int rr = am0 + mt * 16 + lr;
                int bo = (rr * 128 + ks * 64 + lg * 16) ^ ((rr & 7) << 4);
                af[mt] = *(const bf16x8*)((const char*)As[cur] + bo);
            }
            #pragma unroll
            for (int nt = 0; nt < 4; ++nt) {
                int rr = bn0 + nt * 16 + lr;
                int bo = (rr * 128 + ks * 64 + lg * 16) ^ ((rr & 7) << 4);
                bf[nt] = *(const bf16x8*)((const char*)Bs[cur] + bo);
            }
            #pragma unroll
            for (int mt = 0; mt < 4; ++mt)
                #pragma unroll
                for (int nt = 0; nt < 4; ++nt)
                    acc[mt][nt] = __builtin_amdgcn_mfma_f32_16x16x32_bf16(af[mt], bf[nt], acc[mt][nt], 0, 0, 0);
        }

        if (kt + 1 < 12) {
            WRITET(cur ^ 1);
        }
        __syncthreads();
        cur ^= 1;
    }
    #undef LOADT
    #undef WRITET

    float* C = gates + (size_t)type * 2048 * 768 + (size_t)mb0 * 768 + nb0;
    #pragma unroll
    for (int mt = 0; mt < 4; ++mt)
        #pragma unroll
        for (int nt = 0; nt < 4; ++nt)
            #pragma unroll
            for (int r = 0; r < 4; ++r)
                C[(size_t)(am0 + mt * 16 + lg * 4 + r) * 768 + bn0 + nt * 16 + lr] = acc[mt][nt][r];
}

// ---------------- pool epilogue ----------------
__global__ __launch_bounds__(256)
void pool_epilogue(const float* __restrict__ gates,
                   const float* __restrict__ bhf, const float* __restrict__ bhb,
                   const float* __restrict__ btf, const float* __restrict__ btb,
                   const float* __restrict__ bef, const float* __restrict__ beb,
                   unsigned short* __restrict__ poolB)
{
    const int type = blockIdx.x >> 7;
    const int ent  = blockIdx.x & 127;
    const int tid  = threadIdx.x;
    const int dir  = tid >> 7;
    const int j    = tid & 127;
    const float* Bv = (type == 0) ? (dir ? bhb : bhf)
                    : (type == 1) ? (dir ? btb : btf)
                                  : (dir ? beb : bef);
    const float bi = Bv[j], bg = Bv[2 * HID + j], bo = Bv[3 * HID + j];
    const float* g0 = gates + ((size_t)type * 2048 + ent * 16) * 768 + dir * 384 + j;
    float hmax = -1e30f;
    #pragma unroll
    for (int l = 0; l < SPAN; ++l) {
        const float* gr = g0 + l * 768;
        float iv = sigmoidf_(gr[0]   + bi);
        float gv = tanhf(   gr[128] + bg);
        float ov = sigmoidf_(gr[256] + bo);
        hmax = fmaxf(hmax, ov * tanhf(iv * gv));
    }
    poolB[(size_t)(type * NENT + ent) * H2 + dir * HID + j] = f2bf(hmax);
}

// ---------------- pair: fused gemm1+gemm2, 1024 threads, conflict-free staging ----------------
// block = (t, beta): W[a][k] = sum_c T_t[a][beta][c]*Ee[k][c]; out[beta][k][i] = sum_a W[a][k]*Hx[i][a]
// grid 512; 1024 thr = 16 waves (4/SIMD). LDS 128 KB: slab bf16[256a][256c] swz; WT[128k][256a] aliases low 64 KB.
__global__ __launch_bounds__(1024)
void pair_mfma(const unsigned short* __restrict__ EeB,
               const unsigned short* __restrict__ HeB,
               const unsigned short* __restrict__ TeB,
               const float* __restrict__ T0, const float* __restrict__ T1,
               unsigned short* __restrict__ hepN,   // [256][128][128]
               unsigned short* __restrict__ tepN)
{
    __shared__ __align__(16) char smem[131072];
    const int bid = blockIdx.x;
    const int t = bid >> 8;
    const int b = bid & 255;
    const float* T = t ? T1 : T0;
    const unsigned short* Hx = t ? TeB : HeB;
    unsigned short* outp = t ? tepN : hepN;
    const int tid = threadIdx.x;
    const int w = tid >> 6, l = tid & 63;
    const int lr = l & 15, lg = l >> 4;

    // ---- stage T[:,b,:] fp32 -> slab bf16 swz. thread: row = p*32+(tid>>5), chunk = tid&31 (8 floats).
    // lane-consecutive -> LDS-offset-consecutive: conflict-free; 8 indep float4-pairs/thread.
    {
        const int r0 = tid >> 5;
        const int ch = tid & 31;
        #pragma unroll
        for (int p = 0; p < 8; ++p) {
            int row = p * 32 + r0;
            const float* src = T + ((size_t)row * 256 + b) * 256 + ch * 8;
            float4 v0 = ((const float4*)src)[0];
            float4 v1 = ((const float4*)src)[1];
            bf16x8 hv; unsigned short* hp = (unsigned short*)&hv;
            hp[0]=f2bf(v0.x); hp[1]=f2bf(v0.y); hp[2]=f2bf(v0.z); hp[3]=f2bf(v0.w);
            hp[4]=f2bf(v1.x); hp[5]=f2bf(v1.y); hp[6]=f2bf(v1.z); hp[7]=f2bf(v1.w);
            int bo = (row * 512 + ch * 16) ^ ((row & 7) << 4);
            *(bf16x8*)(smem + bo) = hv;
        }
    }
    __syncthreads();

    // ---- P1: W[a][k]; 16 waves: aw = w&3 (64a), kw = w>>2 (32k)
    f32x4 acc1[4][2];
    {
        const int aw = (w & 3) * 64;
        const int kw = (w >> 2) * 32;
        #pragma unroll
        for (int mt = 0; mt < 4; ++mt)
            #pragma unroll
            for (int nt = 0; nt < 2; ++nt) acc1[mt][nt] = (f32x4){0.f, 0.f, 0.f, 0.f};

        #pragma unroll
        for (int ks = 0; ks < 8; ++ks) {
            bf16x8 af[4], bf[2];
            #pragma unroll
            for (int mt = 0; mt < 4; ++mt) {
                int ar = aw + mt * 16 + lr;
                int bo = (ar * 512 + (ks * 32 + lg * 8) * 2) ^ ((ar & 7) << 4);
                af[mt] = *(const bf16x8*)(smem + bo);
            }
            #pragma unroll
            for (int nt = 0; nt < 2; ++nt)
                bf[nt] = *(const bf16x8*)(EeB + (kw + nt * 16 + lr) * H2 + ks * 32 + lg * 8);
            #pragma unroll
            for (int mt = 0; mt < 4; ++mt)
                #pragma unroll
                for (int nt = 0; nt < 2; ++nt)
                    acc1[mt][nt] = __builtin_amdgcn_mfma_f32_16x16x32_bf16(af[mt], bf[nt], acc1[mt][nt], 0, 0, 0);
        }
    }
    __syncthreads();   // slab fully consumed

    // ---- write WT[k][a] bf16 swz into smem[0:64K]
    {
        const int aw = (w & 3) * 64;
        const int kw = (w >> 2) * 32;
        #pragma unroll
        for (int mt = 0; mt < 4; ++mt)
            #pragma unroll
            for (int nt = 0; nt < 2; ++nt) {
                int k  = kw + nt * 16 + lr;
                int a0 = aw + mt * 16 + lg * 4;
                unsigned short h4[4] = { f2bf(acc1[mt][nt][0]), f2bf(acc1[mt][nt][1]),
                                         f2bf(acc1[mt][nt][2]), f2bf(acc1[mt][nt][3]) };
                int bo = (k * 512 + a0 * 2) ^ ((k & 7) << 4);
                *(uint2*)(smem + bo) = *(uint2*)h4;
            }
    }
    __syncthreads();

    // ---- P2: out[b][k][i]; 16 waves: kw2 = w>>3 (64k), iw = w&7 (16i)
    {
        const int kw2 = (w >> 3) * 64;
        const int iw  = (w & 7) * 16;
        f32x4 acc2[4];
        #pragma unroll
        for (int mt = 0; mt < 4; ++mt) acc2[mt] = (f32x4){0.f, 0.f, 0.f, 0.f};

        #pragma unroll
        for (int ks = 0; ks < 8; ++ks) {
            bf16x8 af[4], bf;
            #pragma unroll
            for (int mt = 0; mt < 4; ++mt) {
                int kr = kw2 + mt * 16 + lr;
                int bo = (kr * 512 + (ks * 32 + lg * 8) * 2) ^ ((kr & 7) << 4);
                af[mt] = *(const bf16x8*)(smem + bo);
            }
            bf = *(const bf16x8*)(Hx + (iw + lr) * H2 + ks * 32 + lg * 8);
            #pragma unroll
            for (int mt = 0; mt < 4; ++mt)
                acc2[mt] = __builtin_amdgcn_mfma_f32_16x16x32_bf16(af[mt], bf, acc2[mt], 0, 0, 0);
        }
        unsigned short* po = outp + (size_t)b * (128 * 128);
        #pragma unroll
        for (int mt = 0; mt < 4; ++mt)
            #pragma unroll
            for (int r = 0; r < 4; ++r) {
                int k = kw2 + mt * 16 + lg * 4 + r;
                int i = iw + lr;
                po[k * 128 + i] = f2bf(acc2[mt][r]);
            }
    }
}

// ---------------- step3: block per (k, j-half); m-loop inside ----------------
__global__ __launch_bounds__(512)
void step3_mfma(const unsigned short* __restrict__ hepN,  // [256 beta][128 k][128 i]
                const unsigned short* __restrict__ tepN,  // [256 b][128 k][128 j]
                const unsigned short* __restrict__ TclsB, // [m][c][b]
                float* __restrict__ predT)
{
    __shared__ unsigned short hepS[128 * 256];  // [i][beta] swz, 64 KB
    __shared__ unsigned short tepS[64 * 256];   // [j][b] swz, 32 KB
    __shared__ unsigned short WS[64 * 256];     // [j][c] swz, 32 KB
    const int lbid = (blockIdx.x & 7) * 32 + (blockIdx.x >> 3);
    const int k  = lbid >> 1;
    const int jh = lbid & 1;
    const int tid = threadIdx.x;
    const int w  = tid >> 6;
    const int l  = tid & 63;
    const int lr = l & 15;
    const int lg = l >> 4;
    const int swz = (lr & 7) << 4;

    #pragma unroll
    for (int q = 0; q < 4; ++q) {
        int bcol = q * 64 + l;
        bf16x8 v = *(const bf16x8*)(tepN + ((size_t)bcol * 128 + k) * 128 + jh * 64 + w * 8);
        #pragma unroll
        for (int r = 0; r < 8; ++r) {
            int j = w * 8 + r;
            int bo = (j * 512 + bcol * 2) ^ (r << 4);
            *(unsigned short*)((char*)tepS + bo) = ((unsigned short*)&v)[r];
        }
    }
    #pragma unroll
    for (int s = 0; s < 2; ++s)
        #pragma unroll
        for (int q = 0; q < 4; ++q) {
            int bcol = q * 64 + l;
            bf16x8 v = *(const bf16x8*)(hepN + ((size_t)bcol * 128 + k) * 128 + w * 16 + s * 8);
            #pragma unroll
            for (int r = 0; r < 8; ++r) {
                int i = w * 16 + s * 8 + r;
                int bo = (i * 512 + bcol * 2) ^ (r << 4);
                *(unsigned short*)((char*)hepS + bo) = ((unsigned short*)&v)[r];
            }
        }
    __syncthreads();

    bf16x8 ha[8];
    #pragma unroll
    for (int ks = 0; ks < 8; ++ks) {
        int ir = w * 16 + lr;
        int bo = (ir * 512 + (ks * 32 + lg * 8) * 2) ^ ((ir & 7) << 4);
        ha[ks] = *(const bf16x8*)((const char*)hepS + bo);
    }

    #pragma unroll 1
    for (int m = 0; m < NCLS; ++m) {
        {
            const unsigned short* tcm = TclsB + (size_t)m * (H2 * H2);
            f32x4 acc1[4][2];
            #pragma unroll
            for (int jt = 0; jt < 4; ++jt)
                #pragma unroll
                for (int ct = 0; ct < 2; ++ct) acc1[jt][ct] = (f32x4){0.f, 0.f, 0.f, 0.f};

            #pragma unroll
            for (int ks = 0; ks < 8; ++ks) {
                bf16x8 a[4], bb[2];
                #pragma unroll
                for (int jt = 0; jt < 4; ++jt) {
                    int byteoff = ((((jt * 16 + lr) << 8) + ks * 32 + lg * 8) << 1) ^ swz;
                    a[jt] = *(const bf16x8*)((const char*)tepS + byteoff);
                }
                #pragma unroll
                for (int ct = 0; ct < 2; ++ct)
                    bb[ct] = *(const bf16x8*)(tcm + (size_t)(w * 32 + ct * 16 + lr) * H2 + ks * 32 + lg * 8);
                #pragma unroll
                for (int jt = 0; jt < 4; ++jt)
                    #pragma unroll
                    for (int ct = 0; ct < 2; ++ct)
                        acc1[jt][ct] = __builtin_amdgcn_mfma_f32_16x16x32_bf16(a[jt], bb[ct], acc1[jt][ct], 0, 0, 0);
            }
            #pragma unroll
            for (int jt = 0; jt < 4; ++jt)
                #pragma unroll
                for (int ct = 0; ct < 2; ++ct)
                    #pragma unroll
                    for (int r = 0; r < 4; ++r) {
                        int j = jt * 16 + lg * 4 + r;
                        int c = w * 32 + ct * 16 + lr;
                        int byteoff = ((((j << 8) + c)) << 1) ^ ((j & 7) << 4);
                        *(unsigned short*)((char*)WS + byteoff) = f2bf(acc1[jt][ct][r]);
                    }
        }
        __syncthreads();

        {
            f32x4 acc2[4];
            #pragma unroll
            for (int jt = 0; jt < 4; ++jt) acc2[jt] = (f32x4){0.f, 0.f, 0.f, 0.f};

            #pragma unroll
            for (int ks = 0; ks < 8; ++ks) {
                #pragma unroll
                for (int jt = 0; jt < 4; ++jt) {
                    int byteoff = ((((jt * 16 + lr) << 8) + ks * 32 + lg * 8) << 1) ^ swz;
                    bf16x8 wb = *(const bf16x8*)((const char*)WS + byteoff);
                    acc2[jt] = __builtin_amdgcn_mfma_f32_16x16x32_bf16(ha[ks], wb, acc2[jt], 0, 0, 0);
                }
            }
            float* po = predT + (size_t)(k * NCLS + m) * (NENT * NENT);
            #pragma unroll
            for (int jt = 0; jt < 4; ++jt)
                #pragma unroll
                for (int r = 0; r < 4; ++r) {
                    int i = w * 16 + lg * 4 + r;
                    int j = jh * 64 + jt * 16 + lr;
                    po[i * NENT + j] = acc2[jt][r];
                }
        }
        __syncthreads();
    }
}

// ---------------- transpose: predT[km][ij] -> out[ij][km] ----------------
__global__ __launch_bounds__(256)
void transpose_out(const float* __restrict__ predT, float* __restrict__ out)
{
    __shared__ float Ls[160][33];
    const int bid = blockIdx.x;
    const int ij0 = (bid >> 2) * 32;
    const int km0 = (bid & 3) * 160;
    const int t = threadIdx.x;

    #pragma unroll
    for (int q = 0; q < 20; ++q) {
        int r = (t >> 5) + q * 8;
        int c = t & 31;
        Ls[r][c] = predT[(size_t)(km0 + r) * 16384 + ij0 + c];
    }
    __syncthreads();
    for (int idx = t; idx < 32 * 160; idx += 256) {
        int r = idx / 160, c = idx % 160;
        out[(size_t)(ij0 + r) * 640 + km0 + c] = Ls[c][r];
    }
}

extern "C" void kernel_launch(void* const* d_in, const int* in_sizes, int n_in,
                              void* d_out, int out_size, void* d_ws, size_t ws_size,
                              hipStream_t stream)
{
    (void)in_sizes; (void)n_in; (void)out_size; (void)ws_size;
    const float* enc  = (const float*)d_in[0];
    const int*   hidx = (const int*)d_in[1];
    const int*   tidx = (const int*)d_in[2];
    const int*   eidx = (const int*)d_in[3];
    const float* Whf = (const float*)d_in[4];
    const float* bhf = (const float*)d_in[5];
    const float* Whb = (const float*)d_in[6];
    const float* bhb = (const float*)d_in[7];
    const float* Wtf = (const float*)d_in[8];
    const float* btf = (const float*)d_in[9];
    const float* Wtb = (const float*)d_in[10];
    const float* btb = (const float*)d_in[11];
    const float* Wef = (const float*)d_in[12];
    const float* bef = (const float*)d_in[13];
    const float* Web = (const float*)d_in[14];
    const float* beb = (const float*)d_in[15];
    const float* T_he  = (const float*)d_in[16];
    const float* T_te  = (const float*)d_in[17];
    const float* T_cls = (const float*)d_in[18];

    float* out = (float*)d_out;
    char*  ws  = (char*)d_ws;
    unsigned short* poolB = (unsigned short*)(ws + POOLB_OFF);
    unsigned short* hepN  = (unsigned short*)(ws + HEPB_OFF);
    unsigned short* tepN  = (unsigned short*)(ws + TEPB_OFF);
    unsigned short* TclsB = (unsigned short*)(ws + TCLSB_OFF);
    unsigned short* WB    = (unsigned short*)(ws + WB_OFF);
    unsigned short* tokB  = (unsigned short*)(ws + TOKB_OFF);
    float*          gates = (float*)(ws + GATES_OFF);
    float*          predT = (float*)(ws + PREDT_OFF);

    unsigned short* HeB = poolB;
    unsigned short* TeB = poolB + 1 * NENT * H2;
    unsigned short* EeB = poolB + 2 * NENT * H2;

    prep_kernel<<<7616, 256, 0, stream>>>(Whf, Whb, Wtf, Wtb, Wef, Web,
                                          T_cls, enc, hidx, tidx, eidx,
                                          WB, TclsB, tokB);

    gates_mfma<<<288, 256, 0, stream>>>(tokB, WB, gates);

    pool_epilogue<<<384, 256, 0, stream>>>(gates, bhf, bhb, btf, btb, bef, beb, poolB);

    pair_mfma<<<512, 1024, 0, stream>>>(EeB, HeB, TeB, T_he, T_te, hepN, tepN);

    step3_mfma<<<256, 512, 0, stream>>>(hepN, tepN, TclsB, predT);

    transpose_out<<<2048, 256, 0, stream>>>(predT, out);
}